// Round 1
// baseline (2401.968 us; speedup 1.0000x reference)
//
#include <hip/hip_runtime.h>
#include <math.h>

// Problem constants
// B=128, H=W=40, C=60, L=1600, NH=10, HD=6, WS=8, N=64, NW=25, NB=4

// ---------------------------------------------------------------- conv_in
// x [B,18,40,40] -> S [B,1600,60]
__global__ __launch_bounds__(256) void conv_in_k(
    const float* __restrict__ x, const float* __restrict__ w,
    const float* __restrict__ bias, float* __restrict__ S)
{
    __shared__ float ins[3][18][40];
    __shared__ float wts[60 * 18 * 9];
    int b = blockIdx.x / 40, y = blockIdx.x % 40;
    int tid = threadIdx.x;
    const float* xb = x + (size_t)b * 18 * 1600;
    for (int idx = tid; idx < 3 * 18 * 40; idx += 256) {
        int ky = idx / (18 * 40); int ci = (idx / 40) % 18; int xx = idx % 40;
        int yy = y + ky - 1;
        ins[ky][ci][xx] = (yy >= 0 && yy < 40) ? xb[ci * 1600 + yy * 40 + xx] : 0.f;
    }
    for (int idx = tid; idx < 60 * 18 * 9; idx += 256) wts[idx] = w[idx];
    __syncthreads();
    if (tid < 240) {
        int c = tid % 60, g = tid / 60;
        int x0 = g * 10;
        float acc[10];
        float bv = bias[c];
        #pragma unroll
        for (int i = 0; i < 10; i++) acc[i] = bv;
        for (int ci = 0; ci < 18; ci++) {
            #pragma unroll
            for (int ky = 0; ky < 3; ky++) {
                const float* wr = &wts[(c * 18 + ci) * 9 + ky * 3];
                float w0 = wr[0], w1 = wr[1], w2 = wr[2];
                float v[12];
                #pragma unroll
                for (int j = 0; j < 12; j++) {
                    int xx = x0 + j - 1;
                    v[j] = (xx >= 0 && xx < 40) ? ins[ky][ci][xx] : 0.f;
                }
                #pragma unroll
                for (int i = 0; i < 10; i++)
                    acc[i] += w0 * v[i] + w1 * v[i + 1] + w2 * v[i + 2];
            }
        }
        float* Sp = S + ((size_t)b * 1600 + y * 40 + x0) * 60 + c;
        #pragma unroll
        for (int i = 0; i < 10; i++) Sp[i * 60] = acc[i];
    }
}

// ---------------------------------------------------------------- attention block
// One workgroup per (image, window). In-place: S[g] += proj(attn(LN(S)))
__global__ __launch_bounds__(256) void attn_k(
    float* __restrict__ S, const float* __restrict__ g1, const float* __restrict__ b1,
    const float* __restrict__ qkvw, const float* __restrict__ qkvb,
    const float* __restrict__ rpb, const float* __restrict__ pw,
    const float* __restrict__ pb, int shift)
{
    __shared__ __align__(16) float xlnT[60][64];   // LN out (transposed); reused as obT
    __shared__ __align__(16) float qkvT[180][64];  // rows 0-59 q*scale, 60-119 k, 120-179 v
    __shared__ int gmap[64];

    int b = blockIdx.x / 25, wnd = blockIdx.x % 25;
    int wh = wnd / 5, wc = wnd % 5;
    int tid = threadIdx.x;

    if (tid < 64) {
        int r = tid / 8, cc = tid % 8;
        int hh = wh * 8 + r + shift; if (hh >= 40) hh -= 40;
        int ww = wc * 8 + cc + shift; if (ww >= 40) ww -= 40;
        gmap[tid] = hh * 40 + ww;
    }
    __syncthreads();

    const float* Sb = S + (size_t)b * 1600 * 60;
    for (int idx = tid; idx < 64 * 60; idx += 256) {
        int n = idx / 60, c = idx % 60;
        xlnT[c][n] = Sb[(size_t)gmap[n] * 60 + c];
    }
    __syncthreads();

    if (tid < 64) {  // LayerNorm per token (column tid)
        float m = 0.f;
        for (int c = 0; c < 60; c++) m += xlnT[c][tid];
        m *= (1.f / 60.f);
        float v = 0.f;
        for (int c = 0; c < 60; c++) { float d = xlnT[c][tid] - m; v += d * d; }
        v *= (1.f / 60.f);
        float rs = rsqrtf(v + 1e-5f);
        for (int c = 0; c < 60; c++)
            xlnT[c][tid] = (xlnT[c][tid] - m) * rs * g1[c] + b1[c];
    }
    __syncthreads();

    // QKV gemm: [64,60] @ [60,180]^T ; thread tile 4 tokens x 12 outputs
    {
        int tg = tid & 15, cs = tid >> 4;
        if (cs < 15) {
            int i0 = tg * 4, o0 = cs * 12;
            float acc[12][4];
            #pragma unroll
            for (int m = 0; m < 12; m++) {
                float bv = qkvb[o0 + m];
                acc[m][0] = bv; acc[m][1] = bv; acc[m][2] = bv; acc[m][3] = bv;
            }
            #pragma unroll 4
            for (int k = 0; k < 60; k++) {
                float4 xv = *(const float4*)&xlnT[k][i0];
                #pragma unroll
                for (int m = 0; m < 12; m++) {
                    float wv = qkvw[(o0 + m) * 60 + k];
                    acc[m][0] += wv * xv.x; acc[m][1] += wv * xv.y;
                    acc[m][2] += wv * xv.z; acc[m][3] += wv * xv.w;
                }
            }
            #pragma unroll
            for (int m = 0; m < 12; m++) {
                int o = o0 + m;
                float sc = (o < 60) ? 0.40824829046386302f : 1.0f;  // q * HD^-0.5
                qkvT[o][i0 + 0] = acc[m][0] * sc;
                qkvT[o][i0 + 1] = acc[m][1] * sc;
                qkvT[o][i0 + 2] = acc[m][2] * sc;
                qkvT[o][i0 + 3] = acc[m][3] * sc;
            }
        }
    }
    __syncthreads();

    // Per-head attention: thread = (row i = tid/4, j-quarter qj = tid%4)
    float (*obT)[64] = xlnT;  // xlnT dead -> reuse as attention output (transposed)
    {
        int i = tid >> 2, qj = tid & 3;
        int ri = i >> 3, ci = i & 7;
        int shp = wh * 8 + ri, swp = wc * 8 + ci;
        int regi = (shp < 32 ? 0 : (shp < 36 ? 1 : 2)) * 3 + (swp < 32 ? 0 : (swp < 36 ? 1 : 2));
        int ridx[16]; float madd[16];
        #pragma unroll
        for (int jj = 0; jj < 16; jj++) {
            int j = qj * 16 + jj;
            int rj = j >> 3, cj = j & 7;
            ridx[jj] = ((ri - rj + 7) * 15 + (ci - cj + 7)) * 10;
            float mv = 0.f;
            if (shift) {
                int shq = wh * 8 + rj, swq = wc * 8 + cj;
                int regj = (shq < 32 ? 0 : (shq < 36 ? 1 : 2)) * 3 + (swq < 32 ? 0 : (swq < 36 ? 1 : 2));
                if (regj != regi) mv = -100.f;
            }
            madd[jj] = mv;
        }
        for (int h = 0; h < 10; h++) {
            float qs[6];
            #pragma unroll
            for (int d = 0; d < 6; d++) qs[d] = qkvT[h * 6 + d][i];
            float sc[16];
            #pragma unroll
            for (int jj = 0; jj < 16; jj++) sc[jj] = rpb[ridx[jj] + h] + madd[jj];
            #pragma unroll
            for (int d = 0; d < 6; d++) {
                float qv = qs[d];
                const float* kr = &qkvT[60 + h * 6 + d][qj * 16];
                #pragma unroll
                for (int jj = 0; jj < 16; jj++) sc[jj] += qv * kr[jj];
            }
            // softmax across full row (4 lanes x 16)
            float mx = sc[0];
            #pragma unroll
            for (int jj = 1; jj < 16; jj++) mx = fmaxf(mx, sc[jj]);
            mx = fmaxf(mx, __shfl_xor(mx, 1));
            mx = fmaxf(mx, __shfl_xor(mx, 2));
            float sum = 0.f;
            #pragma unroll
            for (int jj = 0; jj < 16; jj++) { sc[jj] = __expf(sc[jj] - mx); sum += sc[jj]; }
            sum += __shfl_xor(sum, 1);
            sum += __shfl_xor(sum, 2);
            float inv = 1.f / sum;
            #pragma unroll
            for (int d = 0; d < 6; d++) {
                const float* vr = &qkvT[120 + h * 6 + d][qj * 16];
                float p = 0.f;
                #pragma unroll
                for (int jj = 0; jj < 16; jj++) p += sc[jj] * vr[jj];
                p += __shfl_xor(p, 1);
                p += __shfl_xor(p, 2);
                if (qj == 0) obT[h * 6 + d][i] = p * inv;
            }
        }
    }
    __syncthreads();

    // proj [64,60]@[60,60]^T + residual (in place)
    {
        int tg = tid & 15, cs = tid >> 4;
        if (cs < 15) {
            int i0 = tg * 4, c0 = cs * 4;
            float acc[4][4];
            #pragma unroll
            for (int m = 0; m < 4; m++)
                for (int d = 0; d < 4; d++) acc[m][d] = 0.f;
            #pragma unroll 4
            for (int k = 0; k < 60; k++) {
                float4 ov = *(const float4*)&obT[k][i0];
                #pragma unroll
                for (int m = 0; m < 4; m++) {
                    float wv = pw[(c0 + m) * 60 + k];
                    acc[m][0] += wv * ov.x; acc[m][1] += wv * ov.y;
                    acc[m][2] += wv * ov.z; acc[m][3] += wv * ov.w;
                }
            }
            #pragma unroll
            for (int di = 0; di < 4; di++) {
                int g = gmap[i0 + di];
                float* Sp = S + ((size_t)b * 1600 + g) * 60 + c0;
                #pragma unroll
                for (int m = 0; m < 4; m++)
                    Sp[m] += acc[m][di] + pb[c0 + m];
            }
        }
    }
}

// ---------------------------------------------------------------- MLP block
// S += fc2(gelu(fc1(LN2(S)))), 64 tokens per workgroup
__global__ __launch_bounds__(256) void mlp_k(
    float* __restrict__ S, const float* __restrict__ g2, const float* __restrict__ b2,
    const float* __restrict__ f1w, const float* __restrict__ f1b,
    const float* __restrict__ f2w, const float* __restrict__ f2b)
{
    __shared__ __align__(16) float xlnT[60][64];
    __shared__ __align__(16) float h1T[120][64];
    size_t tb = (size_t)blockIdx.x * 64;
    int tid = threadIdx.x;

    for (int idx = tid; idx < 64 * 60; idx += 256) {
        int n = idx / 60, c = idx % 60;
        xlnT[c][n] = S[(tb + n) * 60 + c];
    }
    __syncthreads();
    if (tid < 64) {
        float m = 0.f;
        for (int c = 0; c < 60; c++) m += xlnT[c][tid];
        m *= (1.f / 60.f);
        float v = 0.f;
        for (int c = 0; c < 60; c++) { float d = xlnT[c][tid] - m; v += d * d; }
        v *= (1.f / 60.f);
        float rs = rsqrtf(v + 1e-5f);
        for (int c = 0; c < 60; c++)
            xlnT[c][tid] = (xlnT[c][tid] - m) * rs * g2[c] + b2[c];
    }
    __syncthreads();

    int tg = tid & 15, cs = tid >> 4;
    int i0 = tg * 4;
    float acc2[4][4];
    #pragma unroll
    for (int m = 0; m < 4; m++)
        for (int d = 0; d < 4; d++) acc2[m][d] = 0.f;

    for (int ph = 0; ph < 2; ph++) {
        if (cs < 15) {  // fc1 half + gelu
            int o0 = ph * 120 + cs * 8;
            float a1[8][4];
            #pragma unroll
            for (int m = 0; m < 8; m++) {
                float bv = f1b[o0 + m];
                a1[m][0] = bv; a1[m][1] = bv; a1[m][2] = bv; a1[m][3] = bv;
            }
            #pragma unroll 4
            for (int k = 0; k < 60; k++) {
                float4 xv = *(const float4*)&xlnT[k][i0];
                #pragma unroll
                for (int m = 0; m < 8; m++) {
                    float wv = f1w[(o0 + m) * 60 + k];
                    a1[m][0] += wv * xv.x; a1[m][1] += wv * xv.y;
                    a1[m][2] += wv * xv.z; a1[m][3] += wv * xv.w;
                }
            }
            #pragma unroll
            for (int m = 0; m < 8; m++) {
                int lr = cs * 8 + m;
                #pragma unroll
                for (int di = 0; di < 4; di++) {
                    float v = a1[m][di];
                    h1T[lr][i0 + di] = 0.5f * v * (1.f + erff(v * 0.70710678118654752f));
                }
            }
        }
        __syncthreads();
        if (cs < 15) {  // fc2 partial over this half's 120 k
            int c0 = cs * 4;
            #pragma unroll 4
            for (int k = 0; k < 120; k++) {
                float4 hv = *(const float4*)&h1T[k][i0];
                #pragma unroll
                for (int m = 0; m < 4; m++) {
                    float wv = f2w[(c0 + m) * 240 + ph * 120 + k];
                    acc2[m][0] += wv * hv.x; acc2[m][1] += wv * hv.y;
                    acc2[m][2] += wv * hv.z; acc2[m][3] += wv * hv.w;
                }
            }
        }
        __syncthreads();
    }
    if (cs < 15) {
        int c0 = cs * 4;
        #pragma unroll
        for (int di = 0; di < 4; di++) {
            float* Sp = S + (tb + i0 + di) * 60 + c0;
            #pragma unroll
            for (int m = 0; m < 4; m++)
                Sp[m] += acc2[m][di] + f2b[c0 + m];
        }
    }
}

// ---------------------------------------------------------------- conv_out
// S [B,1600,60] -> out [B,3,40,40]
__global__ __launch_bounds__(256) void conv_out_k(
    const float* __restrict__ S, const float* __restrict__ w,
    const float* __restrict__ bias, float* __restrict__ out)
{
    __shared__ float Sr[3][40][60];
    __shared__ float wts[3 * 60 * 9];
    __shared__ float part[2][120];
    int b = blockIdx.x / 40, y = blockIdx.x % 40;
    int tid = threadIdx.x;
    for (int idx = tid; idx < 3 * 40 * 60; idx += 256) {
        int ky = idx / 2400; int n = (idx / 60) % 40; int c = idx % 60;
        int yy = y + ky - 1;
        Sr[ky][n][c] = (yy >= 0 && yy < 40) ? S[((size_t)b * 1600 + yy * 40 + n) * 60 + c] : 0.f;
    }
    for (int idx = tid; idx < 3 * 60 * 9; idx += 256) wts[idx] = w[idx];
    __syncthreads();
    if (tid < 240) {
        int p = tid % 120, half = tid / 120;
        int x = p % 40, co = p / 40;
        float acc = 0.f;
        int c0 = half * 30;
        for (int c = c0; c < c0 + 30; c++) {
            #pragma unroll
            for (int ky = 0; ky < 3; ky++) {
                const float* wr = &wts[(co * 60 + c) * 9 + ky * 3];
                float s0 = (x >= 1) ? Sr[ky][x - 1][c] : 0.f;
                float s1 = Sr[ky][x][c];
                float s2 = (x <= 38) ? Sr[ky][x + 1][c] : 0.f;
                acc += wr[0] * s0 + wr[1] * s1 + wr[2] * s2;
            }
        }
        part[half][p] = acc;
    }
    __syncthreads();
    if (tid < 120) {
        int x = tid % 40, co = tid / 40;
        out[((size_t)b * 3 + co) * 1600 + y * 40 + x] = part[0][tid] + part[1][tid] + bias[co];
    }
}

// ---------------------------------------------------------------- launch
extern "C" void kernel_launch(void* const* d_in, const int* in_sizes, int n_in,
                              void* d_out, int out_size, void* d_ws, size_t ws_size,
                              hipStream_t stream)
{
    const float* x   = (const float*)d_in[0];
    const float* ciw = (const float*)d_in[1];
    const float* cib = (const float*)d_in[2];
    const float* n1g = (const float*)d_in[3];
    const float* n1b = (const float*)d_in[4];
    const float* qw  = (const float*)d_in[5];
    const float* qb  = (const float*)d_in[6];
    const float* rpb = (const float*)d_in[7];
    const float* pw  = (const float*)d_in[8];
    const float* pb  = (const float*)d_in[9];
    const float* n2g = (const float*)d_in[10];
    const float* n2b = (const float*)d_in[11];
    const float* f1w = (const float*)d_in[12];
    const float* f1b = (const float*)d_in[13];
    const float* f2w = (const float*)d_in[14];
    const float* f2b = (const float*)d_in[15];
    const float* cow = (const float*)d_in[16];
    const float* cob = (const float*)d_in[17];
    float* out = (float*)d_out;
    float* S = (float*)d_ws;  // [128][1600][60] f32 = 49.15 MB

    conv_in_k<<<128 * 40, 256, 0, stream>>>(x, ciw, cib, S);
    for (int i = 0; i < 4; i++) {
        int shift = (i & 1) ? 4 : 0;
        attn_k<<<128 * 25, 256, 0, stream>>>(S, n1g + i * 60, n1b + i * 60,
            qw + i * 180 * 60, qb + i * 180, rpb + i * 225 * 10,
            pw + i * 3600, pb + i * 60, shift);
        mlp_k<<<128 * 25, 256, 0, stream>>>(S, n2g + i * 60, n2b + i * 60,
            f1w + i * 240 * 60, f1b + i * 240, f2w + i * 60 * 240, f2b + i * 60);
    }
    conv_out_k<<<128 * 40, 256, 0, stream>>>(S, cow, cob, out);
}

// Round 2
// 2098.468 us; speedup vs baseline: 1.1446x; 1.1446x over previous
//
#include <hip/hip_runtime.h>
#include <math.h>

// B=128, H=W=40, C=60, L=1600, NH=10, HD=6, WS=8, N=64, NW=25, NB=4
#define TPAD 72   // token-dim pad for bf16 transposed tiles (144B rows, 16B aligned)
#define XPAD 65   // token-dim pad for fp32 xT

__device__ __forceinline__ float bf2f(unsigned short h) {
    return __uint_as_float(((unsigned)h) << 16);
}
__device__ __forceinline__ unsigned short f2bf(float x) {
    unsigned u = __float_as_uint(x);
    return (unsigned short)((u + 0x7fffu + ((u >> 16) & 1u)) >> 16);
}
__device__ __forceinline__ void unpack2(unsigned w, float& lo, float& hi) {
    lo = __uint_as_float(w << 16);
    hi = __uint_as_float(w & 0xffff0000u);
}
__device__ __forceinline__ float gelu_f(float v) {
    // tanh-form; |err| < 5e-4, far below bf16 noise at these magnitudes
    float t = 0.7978845608028654f * (v + 0.044715f * v * v * v);
    float e = __expf(2.f * t);
    float th = (e - 1.f) / (e + 1.f);
    return 0.5f * v * (1.f + th);
}

// ---------------------------------------------------------------- conv_in
__global__ __launch_bounds__(256) void conv_in_k(
    const float* __restrict__ x, const float* __restrict__ w,
    const float* __restrict__ bias, float* __restrict__ S)
{
    __shared__ float ins[3][18][40];
    __shared__ float wts[60 * 18 * 9];
    int b = blockIdx.x / 40, y = blockIdx.x % 40;
    int tid = threadIdx.x;
    const float* xb = x + (size_t)b * 18 * 1600;
    for (int idx = tid; idx < 3 * 18 * 40; idx += 256) {
        int ky = idx / (18 * 40); int ci = (idx / 40) % 18; int xx = idx % 40;
        int yy = y + ky - 1;
        ins[ky][ci][xx] = (yy >= 0 && yy < 40) ? xb[ci * 1600 + yy * 40 + xx] : 0.f;
    }
    for (int idx = tid; idx < 60 * 18 * 9; idx += 256) wts[idx] = w[idx];
    __syncthreads();
    if (tid < 240) {
        int c = tid % 60, g = tid / 60;
        int x0 = g * 10;
        float acc[10];
        float bv = bias[c];
        #pragma unroll
        for (int i = 0; i < 10; i++) acc[i] = bv;
        for (int ci = 0; ci < 18; ci++) {
            #pragma unroll
            for (int ky = 0; ky < 3; ky++) {
                const float* wr = &wts[(c * 18 + ci) * 9 + ky * 3];
                float w0 = wr[0], w1 = wr[1], w2 = wr[2];
                float v[12];
                #pragma unroll
                for (int j = 0; j < 12; j++) {
                    int xx = x0 + j - 1;
                    v[j] = (xx >= 0 && xx < 40) ? ins[ky][ci][xx] : 0.f;
                }
                #pragma unroll
                for (int i = 0; i < 10; i++)
                    acc[i] += w0 * v[i] + w1 * v[i + 1] + w2 * v[i + 2];
            }
        }
        float* Sp = S + ((size_t)b * 1600 + y * 40 + x0) * 60 + c;
        #pragma unroll
        for (int i = 0; i < 10; i++) Sp[i * 60] = acc[i];
    }
}

// ---------------------------------------------------------------- fused Swin block
// one workgroup per (image, window): LN1 -> QKV -> attn -> proj (+res) -> LN2 -> MLP (+res)
__global__ __launch_bounds__(256) void block_k(
    float* __restrict__ S,
    const float* __restrict__ g1, const float* __restrict__ b1,
    const float* __restrict__ qkvw, const float* __restrict__ qkvb,
    const float* __restrict__ rpb, const float* __restrict__ pw, const float* __restrict__ pb,
    const float* __restrict__ g2, const float* __restrict__ b2,
    const float* __restrict__ f1w, const float* __restrict__ f1b,
    const float* __restrict__ f2w, const float* __restrict__ f2b,
    int shift)
{
    __shared__ float xT[60][XPAD];                         // x (then x1) fp32
    __shared__ __align__(16) unsigned short lnb[60][TPAD]; // LN out / attn-out / LN2 out (bf16)
    __shared__ __align__(16) unsigned short qkv[180][TPAD];// q*scale,k,v (bf16); reused as h1
    __shared__ int gmap[64];

    int b = blockIdx.x / 25, wnd = blockIdx.x % 25;
    int wh = wnd / 5, wc = wnd % 5;
    int tid = threadIdx.x;
    int tg = tid & 15, cs = tid >> 4;

    if (tid < 64) {
        int r = tid / 8, cc = tid % 8;
        int hh = wh * 8 + r + shift; if (hh >= 40) hh -= 40;
        int ww = wc * 8 + cc + shift; if (ww >= 40) ww -= 40;
        gmap[tid] = hh * 40 + ww;
    }
    __syncthreads();

    float* Sb = S + (size_t)b * 1600 * 60;

    // ---- stage x -> xT (fp32, transposed). float4 global reads, conflict-free LDS writes
    {
        int n = tid & 63, w0 = tid >> 6;  // wave-uniform cg base
        #pragma unroll
        for (int it = 0; it < 4; it++) {
            int cg = w0 + it * 4;  // 0..15
            if (cg < 15) {
                const float4 v = *(const float4*)&Sb[(size_t)gmap[n] * 60 + cg * 4];
                xT[cg * 4 + 0][n] = v.x;
                xT[cg * 4 + 1][n] = v.y;
                xT[cg * 4 + 2][n] = v.z;
                xT[cg * 4 + 3][n] = v.w;
            }
        }
    }
    __syncthreads();

    // ---- LN1 (4 lanes per token)
    {
        int n = tid >> 2, p = tid & 3, cb = p * 15;
        float s = 0.f;
        #pragma unroll
        for (int ii = 0; ii < 15; ii++) s += xT[cb + ii][n];
        s += __shfl_xor(s, 1); s += __shfl_xor(s, 2);
        float m = s * (1.f / 60.f);
        float v = 0.f;
        #pragma unroll
        for (int ii = 0; ii < 15; ii++) { float d = xT[cb + ii][n] - m; v += d * d; }
        v += __shfl_xor(v, 1); v += __shfl_xor(v, 2);
        float rs = rsqrtf(v * (1.f / 60.f) + 1e-5f);
        #pragma unroll
        for (int ii = 0; ii < 15; ii++) {
            int c = cb + ii;
            lnb[c][n] = f2bf((xT[c][n] - m) * rs * g1[c] + b1[c]);
        }
    }
    __syncthreads();

    // ---- QKV gemm [64,60]x[60,180]^T -> qkv (bf16), q pre-scaled
    if (cs < 15) {
        int i0 = tg * 4, o0 = cs * 12;
        float acc[12][4];
        #pragma unroll
        for (int m = 0; m < 12; m++) {
            float bv = qkvb[o0 + m];
            acc[m][0] = bv; acc[m][1] = bv; acc[m][2] = bv; acc[m][3] = bv;
        }
        for (int kb = 0; kb < 60; kb += 4) {
            float xv[4][4];
            #pragma unroll
            for (int kk = 0; kk < 4; kk++) {
                ushort4 u = *(const ushort4*)&lnb[kb + kk][i0];
                xv[kk][0] = bf2f(u.x); xv[kk][1] = bf2f(u.y);
                xv[kk][2] = bf2f(u.z); xv[kk][3] = bf2f(u.w);
            }
            #pragma unroll
            for (int m = 0; m < 12; m++) {
                float4 wv = *(const float4*)&qkvw[(o0 + m) * 60 + kb];
                #pragma unroll
                for (int t = 0; t < 4; t++)
                    acc[m][t] += wv.x * xv[0][t] + wv.y * xv[1][t] + wv.z * xv[2][t] + wv.w * xv[3][t];
            }
        }
        #pragma unroll
        for (int m = 0; m < 12; m++) {
            int o = o0 + m;
            float scl = (o < 60) ? 0.40824829046386302f : 1.0f;
            ushort4 st;
            st.x = f2bf(acc[m][0] * scl); st.y = f2bf(acc[m][1] * scl);
            st.z = f2bf(acc[m][2] * scl); st.w = f2bf(acc[m][3] * scl);
            *(ushort4*)&qkv[o][i0] = st;
        }
    }
    __syncthreads();

    // ---- attention: thread = (row i = tid>>2, quarter qj = tid&3); out -> lnb (bf16)
    {
        int i = tid >> 2, qj = tid & 3, qj16 = (tid & 3) * 16;
        int ri = i >> 3, ci = i & 7;
        int shp = wh * 8 + ri, swp = wc * 8 + ci;
        int regi = (shp < 32 ? 0 : (shp < 36 ? 1 : 2)) * 3 + (swp < 32 ? 0 : (swp < 36 ? 1 : 2));
        int ridx[16]; float madd[16];
        #pragma unroll
        for (int jj = 0; jj < 16; jj++) {
            int j = qj16 + jj;
            int rj = j >> 3, cj = j & 7;
            ridx[jj] = ((ri - rj + 7) * 15 + (ci - cj + 7)) * 10;
            float mv = 0.f;
            if (shift) {
                int shq = wh * 8 + rj, swq = wc * 8 + cj;
                int regj = (shq < 32 ? 0 : (shq < 36 ? 1 : 2)) * 3 + (swq < 32 ? 0 : (swq < 36 ? 1 : 2));
                if (regj != regi) mv = -100.f;
            }
            madd[jj] = mv;
        }
        for (int h = 0; h < 10; h++) {
            float qs[6];
            #pragma unroll
            for (int d = 0; d < 6; d++) qs[d] = bf2f(qkv[h * 6 + d][i]);
            float sc[16];
            #pragma unroll
            for (int jj = 0; jj < 16; jj++) sc[jj] = rpb[ridx[jj] + h] + madd[jj];
            #pragma unroll
            for (int d = 0; d < 6; d++) {
                const uint4* kp = (const uint4*)&qkv[60 + h * 6 + d][qj16];
                uint4 ka = kp[0], kb2 = kp[1];
                float kv[16];
                unpack2(ka.x, kv[0], kv[1]);  unpack2(ka.y, kv[2], kv[3]);
                unpack2(ka.z, kv[4], kv[5]);  unpack2(ka.w, kv[6], kv[7]);
                unpack2(kb2.x, kv[8], kv[9]); unpack2(kb2.y, kv[10], kv[11]);
                unpack2(kb2.z, kv[12], kv[13]); unpack2(kb2.w, kv[14], kv[15]);
                float qv = qs[d];
                #pragma unroll
                for (int jj = 0; jj < 16; jj++) sc[jj] += qv * kv[jj];
            }
            float mx = sc[0];
            #pragma unroll
            for (int jj = 1; jj < 16; jj++) mx = fmaxf(mx, sc[jj]);
            mx = fmaxf(mx, __shfl_xor(mx, 1));
            mx = fmaxf(mx, __shfl_xor(mx, 2));
            float sum = 0.f;
            #pragma unroll
            for (int jj = 0; jj < 16; jj++) { sc[jj] = __expf(sc[jj] - mx); sum += sc[jj]; }
            sum += __shfl_xor(sum, 1);
            sum += __shfl_xor(sum, 2);
            float inv = 1.f / sum;
            #pragma unroll
            for (int d = 0; d < 6; d++) {
                const uint4* vp = (const uint4*)&qkv[120 + h * 6 + d][qj16];
                uint4 va = vp[0], vb = vp[1];
                float vv[16];
                unpack2(va.x, vv[0], vv[1]);  unpack2(va.y, vv[2], vv[3]);
                unpack2(va.z, vv[4], vv[5]);  unpack2(va.w, vv[6], vv[7]);
                unpack2(vb.x, vv[8], vv[9]);  unpack2(vb.y, vv[10], vv[11]);
                unpack2(vb.z, vv[12], vv[13]); unpack2(vb.w, vv[14], vv[15]);
                float p = 0.f;
                #pragma unroll
                for (int jj = 0; jj < 16; jj++) p += sc[jj] * vv[jj];
                p += __shfl_xor(p, 1);
                p += __shfl_xor(p, 2);
                if (qj == 0) lnb[h * 6 + d][i] = f2bf(p * inv);
            }
        }
    }
    __syncthreads();

    // ---- proj + residual into xT (x1)
    if (cs < 15) {
        int i0 = tg * 4, c0 = cs * 4;
        float acc[4][4];
        #pragma unroll
        for (int m = 0; m < 4; m++)
            for (int d = 0; d < 4; d++) acc[m][d] = 0.f;
        for (int kb = 0; kb < 60; kb += 4) {
            float xv[4][4];
            #pragma unroll
            for (int kk = 0; kk < 4; kk++) {
                ushort4 u = *(const ushort4*)&lnb[kb + kk][i0];
                xv[kk][0] = bf2f(u.x); xv[kk][1] = bf2f(u.y);
                xv[kk][2] = bf2f(u.z); xv[kk][3] = bf2f(u.w);
            }
            #pragma unroll
            for (int m = 0; m < 4; m++) {
                float4 wv = *(const float4*)&pw[(c0 + m) * 60 + kb];
                #pragma unroll
                for (int t = 0; t < 4; t++)
                    acc[m][t] += wv.x * xv[0][t] + wv.y * xv[1][t] + wv.z * xv[2][t] + wv.w * xv[3][t];
            }
        }
        #pragma unroll
        for (int m = 0; m < 4; m++) {
            float bv = pb[c0 + m];
            #pragma unroll
            for (int di = 0; di < 4; di++)
                xT[c0 + m][i0 + di] += acc[m][di] + bv;
        }
    }
    __syncthreads();

    // ---- LN2 -> lnb (bf16)
    {
        int n = tid >> 2, p = tid & 3, cb = p * 15;
        float s = 0.f;
        #pragma unroll
        for (int ii = 0; ii < 15; ii++) s += xT[cb + ii][n];
        s += __shfl_xor(s, 1); s += __shfl_xor(s, 2);
        float m = s * (1.f / 60.f);
        float v = 0.f;
        #pragma unroll
        for (int ii = 0; ii < 15; ii++) { float d = xT[cb + ii][n] - m; v += d * d; }
        v += __shfl_xor(v, 1); v += __shfl_xor(v, 2);
        float rs = rsqrtf(v * (1.f / 60.f) + 1e-5f);
        #pragma unroll
        for (int ii = 0; ii < 15; ii++) {
            int c = cb + ii;
            lnb[c][n] = f2bf((xT[c][n] - m) * rs * g2[c] + b2[c]);
        }
    }
    __syncthreads();

    // ---- MLP: fc1(+gelu) in 2 halves of 120, fc2 accumulates across halves
    unsigned short (*h1)[TPAD] = qkv;  // reuse
    float acc2[4][4];
    #pragma unroll
    for (int m = 0; m < 4; m++)
        for (int d = 0; d < 4; d++) acc2[m][d] = 0.f;
    int i0 = tg * 4;

    for (int ph = 0; ph < 2; ph++) {
        if (cs < 15) {
            int o0 = ph * 120 + cs * 8;
            float a1[8][4];
            #pragma unroll
            for (int m = 0; m < 8; m++) {
                float bv = f1b[o0 + m];
                a1[m][0] = bv; a1[m][1] = bv; a1[m][2] = bv; a1[m][3] = bv;
            }
            for (int kb = 0; kb < 60; kb += 4) {
                float xv[4][4];
                #pragma unroll
                for (int kk = 0; kk < 4; kk++) {
                    ushort4 u = *(const ushort4*)&lnb[kb + kk][i0];
                    xv[kk][0] = bf2f(u.x); xv[kk][1] = bf2f(u.y);
                    xv[kk][2] = bf2f(u.z); xv[kk][3] = bf2f(u.w);
                }
                #pragma unroll
                for (int m = 0; m < 8; m++) {
                    float4 wv = *(const float4*)&f1w[(o0 + m) * 60 + kb];
                    #pragma unroll
                    for (int t = 0; t < 4; t++)
                        a1[m][t] += wv.x * xv[0][t] + wv.y * xv[1][t] + wv.z * xv[2][t] + wv.w * xv[3][t];
                }
            }
            #pragma unroll
            for (int m = 0; m < 8; m++) {
                ushort4 st;
                st.x = f2bf(gelu_f(a1[m][0])); st.y = f2bf(gelu_f(a1[m][1]));
                st.z = f2bf(gelu_f(a1[m][2])); st.w = f2bf(gelu_f(a1[m][3]));
                *(ushort4*)&h1[cs * 8 + m][i0] = st;
            }
        }
        __syncthreads();
        if (cs < 15) {
            int c0 = cs * 4;
            for (int kb = 0; kb < 120; kb += 4) {
                float hv[4][4];
                #pragma unroll
                for (int kk = 0; kk < 4; kk++) {
                    ushort4 u = *(const ushort4*)&h1[kb + kk][i0];
                    hv[kk][0] = bf2f(u.x); hv[kk][1] = bf2f(u.y);
                    hv[kk][2] = bf2f(u.z); hv[kk][3] = bf2f(u.w);
                }
                #pragma unroll
                for (int m = 0; m < 4; m++) {
                    float4 wv = *(const float4*)&f2w[(c0 + m) * 240 + ph * 120 + kb];
                    #pragma unroll
                    for (int t = 0; t < 4; t++)
                        acc2[m][t] += wv.x * hv[0][t] + wv.y * hv[1][t] + wv.z * hv[2][t] + wv.w * hv[3][t];
                }
            }
        }
        __syncthreads();
    }

    // ---- final: S[g] = x1 + fc2out + bias
    if (cs < 15) {
        int c0 = cs * 4;
        float b0 = f2b[c0], b1v = f2b[c0 + 1], b2v = f2b[c0 + 2], b3 = f2b[c0 + 3];
        #pragma unroll
        for (int di = 0; di < 4; di++) {
            int n = i0 + di;
            int g = gmap[n];
            float4 r;
            r.x = xT[c0 + 0][n] + acc2[0][di] + b0;
            r.y = xT[c0 + 1][n] + acc2[1][di] + b1v;
            r.z = xT[c0 + 2][n] + acc2[2][di] + b2v;
            r.w = xT[c0 + 3][n] + acc2[3][di] + b3;
            *(float4*)&Sb[(size_t)g * 60 + c0] = r;
        }
    }
}

// ---------------------------------------------------------------- conv_out
__global__ __launch_bounds__(256) void conv_out_k(
    const float* __restrict__ S, const float* __restrict__ w,
    const float* __restrict__ bias, float* __restrict__ out)
{
    __shared__ float Sr[3][40][60];
    __shared__ float wts[3 * 60 * 9];
    __shared__ float part[2][120];
    int b = blockIdx.x / 40, y = blockIdx.x % 40;
    int tid = threadIdx.x;
    for (int idx = tid; idx < 3 * 40 * 60; idx += 256) {
        int ky = idx / 2400; int n = (idx / 60) % 40; int c = idx % 60;
        int yy = y + ky - 1;
        Sr[ky][n][c] = (yy >= 0 && yy < 40) ? S[((size_t)b * 1600 + yy * 40 + n) * 60 + c] : 0.f;
    }
    for (int idx = tid; idx < 3 * 60 * 9; idx += 256) wts[idx] = w[idx];
    __syncthreads();
    if (tid < 240) {
        int p = tid % 120, half = tid / 120;
        int x = p % 40, co = p / 40;
        float acc = 0.f;
        int c0 = half * 30;
        for (int c = c0; c < c0 + 30; c++) {
            #pragma unroll
            for (int ky = 0; ky < 3; ky++) {
                const float* wr = &wts[(co * 60 + c) * 9 + ky * 3];
                float s0 = (x >= 1) ? Sr[ky][x - 1][c] : 0.f;
                float s1 = Sr[ky][x][c];
                float s2 = (x <= 38) ? Sr[ky][x + 1][c] : 0.f;
                acc += wr[0] * s0 + wr[1] * s1 + wr[2] * s2;
            }
        }
        part[half][p] = acc;
    }
    __syncthreads();
    if (tid < 120) {
        int x = tid % 40, co = tid / 40;
        out[((size_t)b * 3 + co) * 1600 + y * 40 + x] = part[0][tid] + part[1][tid] + bias[co];
    }
}

// ---------------------------------------------------------------- launch
extern "C" void kernel_launch(void* const* d_in, const int* in_sizes, int n_in,
                              void* d_out, int out_size, void* d_ws, size_t ws_size,
                              hipStream_t stream)
{
    const float* x   = (const float*)d_in[0];
    const float* ciw = (const float*)d_in[1];
    const float* cib = (const float*)d_in[2];
    const float* n1g = (const float*)d_in[3];
    const float* n1b = (const float*)d_in[4];
    const float* qw  = (const float*)d_in[5];
    const float* qb  = (const float*)d_in[6];
    const float* rpb = (const float*)d_in[7];
    const float* pw  = (const float*)d_in[8];
    const float* pb  = (const float*)d_in[9];
    const float* n2g = (const float*)d_in[10];
    const float* n2b = (const float*)d_in[11];
    const float* f1w = (const float*)d_in[12];
    const float* f1b = (const float*)d_in[13];
    const float* f2w = (const float*)d_in[14];
    const float* f2b = (const float*)d_in[15];
    const float* cow = (const float*)d_in[16];
    const float* cob = (const float*)d_in[17];
    float* out = (float*)d_out;
    float* S = (float*)d_ws;  // [128][1600][60] f32

    conv_in_k<<<128 * 40, 256, 0, stream>>>(x, ciw, cib, S);
    for (int i = 0; i < 4; i++) {
        int shift = (i & 1) ? 4 : 0;
        block_k<<<128 * 25, 256, 0, stream>>>(S,
            n1g + i * 60, n1b + i * 60,
            qw + i * 180 * 60, qb + i * 180, rpb + i * 225 * 10,
            pw + i * 3600, pb + i * 60,
            n2g + i * 60, n2b + i * 60,
            f1w + i * 240 * 60, f1b + i * 240, f2w + i * 60 * 240, f2b + i * 60,
            shift);
    }
    conv_out_k<<<128 * 40, 256, 0, stream>>>(S, cow, cob, out);
}

// Round 3
// 1230.952 us; speedup vs baseline: 1.9513x; 1.7048x over previous
//
#include <hip/hip_runtime.h>
#include <hip/hip_bf16.h>
#include <math.h>

// B=128, H=W=40, C=60, L=1600, NH=10, HD=6, WS=8, N=64, NW=25, NB=4

typedef __bf16 bf16x8 __attribute__((ext_vector_type(8)));
typedef float f32x4 __attribute__((ext_vector_type(4)));
typedef unsigned int u32x4 __attribute__((ext_vector_type(4)));
typedef float f4u __attribute__((ext_vector_type(4), aligned(4)));

#define MFMA16(a, b, c) __builtin_amdgcn_mfma_f32_16x16x32_bf16(a, b, c, 0, 0, 0)

__device__ __forceinline__ unsigned short f2bfu(float x) {
    __hip_bfloat16 h = __float2bfloat16(x);
    return __builtin_bit_cast(unsigned short, h);
}
__device__ __forceinline__ float bf2f(unsigned short h) {
    return __uint_as_float(((unsigned)h) << 16);
}
__device__ __forceinline__ unsigned pk2(float a, float b) {
    return (unsigned)f2bfu(a) | ((unsigned)f2bfu(b) << 16);
}
__device__ __forceinline__ float gelu_f(float v) {
    float t = 0.7978845608028654f * (v + 0.044715f * v * v * v);
    float e = __expf(2.f * t);
    float th = (e - 1.f) / (e + 1.f);
    return 0.5f * v * (1.f + th);
}
// build A-fragment (8 bf16 along k) from a fp32 weight row; zero beyond kmax / invalid row
__device__ __forceinline__ bf16x8 loadWfrag(const float* Wrow, int k0, int kmax, bool valid) {
    u32x4 u = {0u, 0u, 0u, 0u};
    if (valid) {
        if (k0 + 8 <= kmax) {
            f4u a = *(const f4u*)(Wrow + k0);
            f4u b = *(const f4u*)(Wrow + k0 + 4);
            u.x = pk2(a[0], a[1]); u.y = pk2(a[2], a[3]);
            u.z = pk2(b[0], b[1]); u.w = pk2(b[2], b[3]);
        } else if (k0 + 4 <= kmax) {
            f4u a = *(const f4u*)(Wrow + k0);
            u.x = pk2(a[0], a[1]); u.y = pk2(a[2], a[3]);
        }
    }
    return __builtin_bit_cast(bf16x8, u);
}

// ---------------------------------------------------------------- conv_in
__global__ __launch_bounds__(256) void conv_in_k(
    const float* __restrict__ x, const float* __restrict__ w,
    const float* __restrict__ bias, float* __restrict__ S)
{
    __shared__ float ins[3][18][40];
    __shared__ float wts[60 * 18 * 9];
    int b = blockIdx.x / 40, y = blockIdx.x % 40;
    int tid = threadIdx.x;
    const float* xb = x + (size_t)b * 18 * 1600;
    for (int idx = tid; idx < 3 * 18 * 40; idx += 256) {
        int ky = idx / (18 * 40); int ci = (idx / 40) % 18; int xx = idx % 40;
        int yy = y + ky - 1;
        ins[ky][ci][xx] = (yy >= 0 && yy < 40) ? xb[ci * 1600 + yy * 40 + xx] : 0.f;
    }
    for (int idx = tid; idx < 60 * 18 * 9; idx += 256) wts[idx] = w[idx];
    __syncthreads();
    if (tid < 240) {
        int c = tid % 60, g = tid / 60;
        int x0 = g * 10;
        float acc[10];
        float bv = bias[c];
        #pragma unroll
        for (int i = 0; i < 10; i++) acc[i] = bv;
        for (int ci = 0; ci < 18; ci++) {
            #pragma unroll
            for (int ky = 0; ky < 3; ky++) {
                const float* wr = &wts[(c * 18 + ci) * 9 + ky * 3];
                float w0 = wr[0], w1 = wr[1], w2 = wr[2];
                float v[12];
                #pragma unroll
                for (int j = 0; j < 12; j++) {
                    int xx = x0 + j - 1;
                    v[j] = (xx >= 0 && xx < 40) ? ins[ky][ci][xx] : 0.f;
                }
                #pragma unroll
                for (int i = 0; i < 10; i++)
                    acc[i] += w0 * v[i] + w1 * v[i + 1] + w2 * v[i + 2];
            }
        }
        float* Sp = S + ((size_t)b * 1600 + y * 40 + x0) * 60 + c;
        #pragma unroll
        for (int i = 0; i < 10; i++) Sp[i * 60] = acc[i];
    }
}

// ---------------------------------------------------------------- fused Swin block (MFMA)
__global__ __launch_bounds__(256) void block_k(
    float* __restrict__ S,
    const float* __restrict__ g1, const float* __restrict__ b1,
    const float* __restrict__ qkvw, const float* __restrict__ qkvb,
    const float* __restrict__ rpb, const float* __restrict__ pw, const float* __restrict__ pb,
    const float* __restrict__ g2, const float* __restrict__ b2,
    const float* __restrict__ f1w, const float* __restrict__ f1b,
    const float* __restrict__ f2w, const float* __restrict__ f2b,
    int shift)
{
    // LDS map (byte offsets, all 16B-aligned, bf16 tiles pitch-72 shorts = 144B):
    //  [0,15600)      rpl bf16[2250] @0 + P bf16[64][72] @4512   -> later x1T f32[60][65]
    //  [15600,24816)  xln bf16[64][72]                           -> later h1 bf16[64][136] (spans to 33008)
    //  [24816,34032)  qn  bf16[64][72] / o_lds (attn out)
    //  [34032,43248)  kn  bf16[64][72]
    //  [43248,53616)  vt  bf16[72][72]                           -> later ln2 bf16[64][72]
    //  [53616,53872)  gmap int[64]
    __shared__ __align__(16) unsigned char LDSA[53872];
    unsigned short* rpl = (unsigned short*)(LDSA + 0);
    unsigned short* Pl  = (unsigned short*)(LDSA + 4512);
    float*          x1t = (float*)(LDSA + 0);
    unsigned short* xln = (unsigned short*)(LDSA + 15600);
    unsigned short* h1  = (unsigned short*)(LDSA + 15600);
    unsigned short* qn  = (unsigned short*)(LDSA + 24816);
    unsigned short* kn  = (unsigned short*)(LDSA + 34032);
    unsigned short* vt  = (unsigned short*)(LDSA + 43248);
    unsigned short* ln2 = (unsigned short*)(LDSA + 43248);
    int* gmap = (int*)(LDSA + 53616);

    const int tid = threadIdx.x;
    const int lane = tid & 63, w = tid >> 6;
    const int l15 = lane & 15, l4 = lane >> 4;
    const int wbase = w * 16;
    const int b = blockIdx.x / 25, wnd = blockIdx.x % 25;
    const int wh = wnd / 5, wc = wnd % 5;
    float* Sb = S + (size_t)b * 96000;
    const f32x4 zf = {0.f, 0.f, 0.f, 0.f};
    u32x4 zu = {0u, 0u, 0u, 0u};
    const bf16x8 zb = __builtin_bit_cast(bf16x8, zu);

    if (tid < 64) {
        int r = tid >> 3, cc = tid & 7;
        int hh = wh * 8 + r + shift; if (hh >= 40) hh -= 40;
        int ww = wc * 8 + cc + shift; if (ww >= 40) ww -= 40;
        gmap[tid] = hh * 40 + ww;
    }
    for (int idx = tid; idx < 2250; idx += 256) rpl[idx] = f2bfu(rpb[idx]);
    __syncthreads();  // B0

    // ---- LN1: global x -> xln (bf16, n-major, cols 60..63 zeroed)
    {
        int n = tid >> 2, p = tid & 3, cb = p * 15;
        const float* xp = Sb + (size_t)gmap[n] * 60 + cb;
        f4u a0 = *(const f4u*)xp, a1 = *(const f4u*)(xp + 4), a2 = *(const f4u*)(xp + 8);
        float xv[15] = {a0[0], a0[1], a0[2], a0[3], a1[0], a1[1], a1[2], a1[3],
                        a2[0], a2[1], a2[2], a2[3], xp[12], xp[13], xp[14]};
        float s = 0.f;
        #pragma unroll
        for (int ii = 0; ii < 15; ii++) s += xv[ii];
        s += __shfl_xor(s, 1); s += __shfl_xor(s, 2);
        float mean = s * (1.f / 60.f);
        float vv = 0.f;
        #pragma unroll
        for (int ii = 0; ii < 15; ii++) { float d = xv[ii] - mean; vv += d * d; }
        vv += __shfl_xor(vv, 1); vv += __shfl_xor(vv, 2);
        float rs = rsqrtf(vv * (1.f / 60.f) + 1e-5f);
        unsigned short* xr = xln + n * 72;
        #pragma unroll
        for (int ii = 0; ii < 15; ii++)
            xr[cb + ii] = f2bfu((xv[ii] - mean) * rs * g1[cb + ii] + b1[cb + ii]);
        if (p == 3) { *(unsigned int*)(xr + 60) = 0u; *(unsigned int*)(xr + 62) = 0u; }
    }
    __syncthreads();  // B1

    // ---- QKV: [64,60]x[60,180]^T via MFMA; q scaled; q,k n-major; v transposed
    {
        bf16x8 bx[4][2];
        #pragma unroll
        for (int nt = 0; nt < 4; nt++)
            #pragma unroll
            for (int ks = 0; ks < 2; ks++)
                bx[nt][ks] = *(const bf16x8*)(xln + (nt * 16 + l15) * 72 + l4 * 8 + ks * 32);
        #pragma unroll
        for (int t = 0; t < 3; t++) {
            int ot = w * 3 + t;
            int orow = ot * 16 + l15;
            f32x4 acc[4];
            #pragma unroll
            for (int nt = 0; nt < 4; nt++) acc[nt] = zf;
            #pragma unroll
            for (int ks = 0; ks < 2; ks++) {
                bf16x8 a = loadWfrag(qkvw + (size_t)orow * 60, l4 * 8 + ks * 32, 60, orow < 180);
                #pragma unroll
                for (int nt = 0; nt < 4; nt++) acc[nt] = MFMA16(a, bx[nt][ks], acc[nt]);
            }
            int o0 = ot * 16 + l4 * 4;
            if (o0 < 180) {
                f4u bias = *(const f4u*)(qkvb + o0);
                #pragma unroll
                for (int nt = 0; nt < 4; nt++) {
                    int n = nt * 16 + l15;
                    float v0 = acc[nt][0] + bias[0], v1 = acc[nt][1] + bias[1];
                    float v2 = acc[nt][2] + bias[2], v3 = acc[nt][3] + bias[3];
                    if (o0 < 60) {
                        const float sc = 0.40824829046386302f;
                        *(ushort4*)(qn + n * 72 + o0) =
                            make_ushort4(f2bfu(v0 * sc), f2bfu(v1 * sc), f2bfu(v2 * sc), f2bfu(v3 * sc));
                    } else if (o0 < 120) {
                        *(ushort4*)(kn + n * 72 + (o0 - 60)) =
                            make_ushort4(f2bfu(v0), f2bfu(v1), f2bfu(v2), f2bfu(v3));
                    } else {
                        int r = o0 - 120;
                        vt[(r + 0) * 72 + n] = f2bfu(v0);
                        vt[(r + 1) * 72 + n] = f2bfu(v1);
                        vt[(r + 2) * 72 + n] = f2bfu(v2);
                        vt[(r + 3) * 72 + n] = f2bfu(v3);
                    }
                }
            }
        }
    }
    __syncthreads();  // B2

    // ---- per-element rel-pos index / shift mask (acc layout: row j, col-tile nt2)
    int rel10[16];
    float madd[16];
    #pragma unroll
    for (int e = 0; e < 16; e++) {
        int nt2 = e >> 2, j = e & 3;
        int n1 = wbase + l4 * 4 + j;
        int n2 = nt2 * 16 + l15;
        int ri = n1 >> 3, ci = n1 & 7, rj = n2 >> 3, cj = n2 & 7;
        rel10[e] = ((ri - rj + 7) * 15 + (ci - cj + 7)) * 10;
        float mv = 0.f;
        if (shift) {
            int shp = wh * 8 + ri, swp = wc * 8 + ci, shq = wh * 8 + rj, swq = wc * 8 + cj;
            int ra = (shp < 32 ? 0 : (shp < 36 ? 1 : 2)) * 3 + (swp < 32 ? 0 : (swp < 36 ? 1 : 2));
            int rb = (shq < 32 ? 0 : (shq < 36 ? 1 : 2)) * 3 + (swq < 32 ? 0 : (swq < 36 ? 1 : 2));
            if (ra != rb) mv = -100.f;
        }
        madd[e] = mv;
    }

    // ---- head loop (barrier-free: wave w owns token-tile w rows of q/P; kn/vt read-only)
    f32x4 oacc[10];
    #pragma unroll
    for (int h = 0; h < 10; h++) oacc[h] = zf;

    #pragma unroll
    for (int h = 0; h < 10; h++) {
        bf16x8 aq = zb, bk0 = zb, bk1 = zb, bk2 = zb, bk3 = zb;
        if (l4 == 0) {
            const unsigned int* qp = (const unsigned int*)(qn + (wbase + l15) * 72 + h * 6);
            u32x4 uq = {qp[0], qp[1], qp[2], 0u};
            aq = __builtin_bit_cast(bf16x8, uq);
            const unsigned int* k0p = (const unsigned int*)(kn + (0 * 16 + l15) * 72 + h * 6);
            const unsigned int* k1p = (const unsigned int*)(kn + (1 * 16 + l15) * 72 + h * 6);
            const unsigned int* k2p = (const unsigned int*)(kn + (2 * 16 + l15) * 72 + h * 6);
            const unsigned int* k3p = (const unsigned int*)(kn + (3 * 16 + l15) * 72 + h * 6);
            u32x4 u0 = {k0p[0], k0p[1], k0p[2], 0u}; bk0 = __builtin_bit_cast(bf16x8, u0);
            u32x4 u1 = {k1p[0], k1p[1], k1p[2], 0u}; bk1 = __builtin_bit_cast(bf16x8, u1);
            u32x4 u2 = {k2p[0], k2p[1], k2p[2], 0u}; bk2 = __builtin_bit_cast(bf16x8, u2);
            u32x4 u3 = {k3p[0], k3p[1], k3p[2], 0u}; bk3 = __builtin_bit_cast(bf16x8, u3);
        }
        f32x4 s0 = MFMA16(aq, bk0, zf);
        f32x4 s1 = MFMA16(aq, bk1, zf);
        f32x4 s2 = MFMA16(aq, bk2, zf);
        f32x4 s3 = MFMA16(aq, bk3, zf);
        float sc[4][4];
        #pragma unroll
        for (int j = 0; j < 4; j++) {
            sc[0][j] = s0[j] + bf2f(rpl[rel10[0 * 4 + j] + h]) + madd[0 * 4 + j];
            sc[1][j] = s1[j] + bf2f(rpl[rel10[1 * 4 + j] + h]) + madd[1 * 4 + j];
            sc[2][j] = s2[j] + bf2f(rpl[rel10[2 * 4 + j] + h]) + madd[2 * 4 + j];
            sc[3][j] = s3[j] + bf2f(rpl[rel10[3 * 4 + j] + h]) + madd[3 * 4 + j];
        }
        #pragma unroll
        for (int j = 0; j < 4; j++) {
            float m = fmaxf(fmaxf(sc[0][j], sc[1][j]), fmaxf(sc[2][j], sc[3][j]));
            m = fmaxf(m, __shfl_xor(m, 1)); m = fmaxf(m, __shfl_xor(m, 2));
            m = fmaxf(m, __shfl_xor(m, 4)); m = fmaxf(m, __shfl_xor(m, 8));
            float e0 = __expf(sc[0][j] - m), e1 = __expf(sc[1][j] - m);
            float e2 = __expf(sc[2][j] - m), e3 = __expf(sc[3][j] - m);
            float t = e0 + e1 + e2 + e3;
            t += __shfl_xor(t, 1); t += __shfl_xor(t, 2);
            t += __shfl_xor(t, 4); t += __shfl_xor(t, 8);
            float inv = __builtin_amdgcn_rcpf(t);
            sc[0][j] = e0 * inv; sc[1][j] = e1 * inv; sc[2][j] = e2 * inv; sc[3][j] = e3 * inv;
        }
        #pragma unroll
        for (int nt2 = 0; nt2 < 4; nt2++)
            #pragma unroll
            for (int j = 0; j < 4; j++)
                Pl[(wbase + l4 * 4 + j) * 72 + nt2 * 16 + l15] = f2bfu(sc[nt2][j]);
        asm volatile("s_waitcnt lgkmcnt(0)" ::: "memory");
        #pragma unroll
        for (int ks = 0; ks < 2; ks++) {
            bf16x8 ap = *(const bf16x8*)(Pl + (wbase + l15) * 72 + l4 * 8 + ks * 32);
            bf16x8 bv = *(const bf16x8*)(vt + (h * 6 + l15) * 72 + l4 * 8 + ks * 32);
            oacc[h] = MFMA16(ap, bv, oacc[h]);
        }
    }

    // ---- write attention output (o_lds = qn slab; own rows only) + zero pad cols
    unsigned short* olds = qn;
    if (l15 < 6) {
        #pragma unroll
        for (int h = 0; h < 10; h++)
            #pragma unroll
            for (int j = 0; j < 4; j++)
                olds[(wbase + l4 * 4 + j) * 72 + h * 6 + l15] = f2bfu(oacc[h][j]);
    } else if (l15 < 10) {
        #pragma unroll
        for (int j = 0; j < 4; j++)
            olds[(wbase + l4 * 4 + j) * 72 + 60 + (l15 - 6)] = 0;
    }
    __syncthreads();  // B2.5 (all waves past P/rpl/vt reads; x1t/ln2 overlays now safe)

    // ---- proj + residual -> x1T (fp32). wave w handles n-tile w, all 4 o-tiles
    {
        f32x4 acc[4];
        #pragma unroll
        for (int ot = 0; ot < 4; ot++) acc[ot] = zf;
        bf16x8 bo[2];
        #pragma unroll
        for (int ks = 0; ks < 2; ks++)
            bo[ks] = *(const bf16x8*)(olds + (wbase + l15) * 72 + l4 * 8 + ks * 32);
        #pragma unroll
        for (int ot = 0; ot < 4; ot++) {
            int orow = ot * 16 + l15;
            #pragma unroll
            for (int ks = 0; ks < 2; ks++) {
                bf16x8 a = loadWfrag(pw + (size_t)orow * 60, l4 * 8 + ks * 32, 60, orow < 60);
                acc[ot] = MFMA16(a, bo[ks], acc[ot]);
            }
        }
        int n = wbase + l15;
        int g = gmap[n];
        #pragma unroll
        for (int ot = 0; ot < 4; ot++) {
            int o0 = ot * 16 + l4 * 4;
            if (o0 < 60) {
                float4 xr = *(const float4*)(Sb + (size_t)g * 60 + o0);
                f4u pbv = *(const f4u*)(pb + o0);
                x1t[(o0 + 0) * 65 + n] = xr.x + acc[ot][0] + pbv[0];
                x1t[(o0 + 1) * 65 + n] = xr.y + acc[ot][1] + pbv[1];
                x1t[(o0 + 2) * 65 + n] = xr.z + acc[ot][2] + pbv[2];
                x1t[(o0 + 3) * 65 + n] = xr.w + acc[ot][3] + pbv[3];
            }
        }
    }
    asm volatile("s_waitcnt lgkmcnt(0)" ::: "memory");

    // ---- LN2 (same-wave cols) -> ln2 bf16 (vt slab; safe after B2.5)
    {
        int n = wbase + (lane >> 2), p = lane & 3, cb = p * 15;
        float xv[15];
        #pragma unroll
        for (int ii = 0; ii < 15; ii++) xv[ii] = x1t[(cb + ii) * 65 + n];
        float s = 0.f;
        #pragma unroll
        for (int ii = 0; ii < 15; ii++) s += xv[ii];
        s += __shfl_xor(s, 1); s += __shfl_xor(s, 2);
        float mean = s * (1.f / 60.f);
        float vv = 0.f;
        #pragma unroll
        for (int ii = 0; ii < 15; ii++) { float d = xv[ii] - mean; vv += d * d; }
        vv += __shfl_xor(vv, 1); vv += __shfl_xor(vv, 2);
        float rs = rsqrtf(vv * (1.f / 60.f) + 1e-5f);
        unsigned short* lr = ln2 + n * 72;
        #pragma unroll
        for (int ii = 0; ii < 15; ii++)
            lr[cb + ii] = f2bfu((xv[ii] - mean) * rs * g2[cb + ii] + b2[cb + ii]);
        if (p == 3) { *(unsigned int*)(lr + 60) = 0u; *(unsigned int*)(lr + 62) = 0u; }
    }
    __syncthreads();  // B3

    // ---- MLP: fc1+gelu in 2 halves of 120 -> h1; fc2 accumulates across halves
    f32x4 acc2[4];
    #pragma unroll
    for (int ot = 0; ot < 4; ot++) acc2[ot] = zf;

    #pragma unroll
    for (int ph = 0; ph < 2; ph++) {
        {   // fc1 half: wave w -> o-tiles {w, w+4}
            bf16x8 bl[4][2];
            #pragma unroll
            for (int nt = 0; nt < 4; nt++)
                #pragma unroll
                for (int ks = 0; ks < 2; ks++)
                    bl[nt][ks] = *(const bf16x8*)(ln2 + (nt * 16 + l15) * 72 + l4 * 8 + ks * 32);
            #pragma unroll
            for (int t = 0; t < 2; t++) {
                int ot = w + t * 4;
                int olocal = ot * 16 + l15;
                f32x4 a1[4];
                #pragma unroll
                for (int nt = 0; nt < 4; nt++) a1[nt] = zf;
                #pragma unroll
                for (int ks = 0; ks < 2; ks++) {
                    bf16x8 a = loadWfrag(f1w + (size_t)(ph * 120 + olocal) * 60,
                                         l4 * 8 + ks * 32, 60, olocal < 120);
                    #pragma unroll
                    for (int nt = 0; nt < 4; nt++) a1[nt] = MFMA16(a, bl[nt][ks], a1[nt]);
                }
                int o0 = ot * 16 + l4 * 4;
                if (o0 < 120) {
                    f4u b4 = *(const f4u*)(f1b + ph * 120 + o0);
                    #pragma unroll
                    for (int nt = 0; nt < 4; nt++) {
                        int n = nt * 16 + l15;
                        *(ushort4*)(h1 + n * 136 + o0) = make_ushort4(
                            f2bfu(gelu_f(a1[nt][0] + b4[0])), f2bfu(gelu_f(a1[nt][1] + b4[1])),
                            f2bfu(gelu_f(a1[nt][2] + b4[2])), f2bfu(gelu_f(a1[nt][3] + b4[3])));
                    }
                }
            }
            if (ph == 0 && tid < 64)
                *(uint4*)(h1 + tid * 136 + 120) = make_uint4(0u, 0u, 0u, 0u);
        }
        __syncthreads();  // h1 ready
        {   // fc2 partial: wave w -> n-tile w, K = 120 (pad 128)
            bf16x8 bh[4];
            #pragma unroll
            for (int ks = 0; ks < 4; ks++)
                bh[ks] = *(const bf16x8*)(h1 + (wbase + l15) * 136 + l4 * 8 + ks * 32);
            #pragma unroll
            for (int ot = 0; ot < 4; ot++) {
                int orow = ot * 16 + l15;
                #pragma unroll
                for (int ks = 0; ks < 4; ks++) {
                    bf16x8 a = loadWfrag(f2w + (size_t)orow * 240 + ph * 120,
                                         l4 * 8 + ks * 32, 120, orow < 60);
                    acc2[ot] = MFMA16(a, bh[ks], acc2[ot]);
                }
            }
        }
        if (ph == 0) __syncthreads();  // h1 consumed before overwrite
    }

    // ---- final: S[g] = x1 + fc2out + bias
    {
        int n = wbase + l15, g = gmap[n];
        #pragma unroll
        for (int ot = 0; ot < 4; ot++) {
            int o0 = ot * 16 + l4 * 4;
            if (o0 < 60) {
                f4u fb = *(const f4u*)(f2b + o0);
                float4 r;
                r.x = x1t[(o0 + 0) * 65 + n] + acc2[ot][0] + fb[0];
                r.y = x1t[(o0 + 1) * 65 + n] + acc2[ot][1] + fb[1];
                r.z = x1t[(o0 + 2) * 65 + n] + acc2[ot][2] + fb[2];
                r.w = x1t[(o0 + 3) * 65 + n] + acc2[ot][3] + fb[3];
                *(float4*)(Sb + (size_t)g * 60 + o0) = r;
            }
        }
    }
}

// ---------------------------------------------------------------- conv_out
__global__ __launch_bounds__(256) void conv_out_k(
    const float* __restrict__ S, const float* __restrict__ w,
    const float* __restrict__ bias, float* __restrict__ out)
{
    __shared__ float Sr[3][40][60];
    __shared__ float wts[3 * 60 * 9];
    __shared__ float part[2][120];
    int b = blockIdx.x / 40, y = blockIdx.x % 40;
    int tid = threadIdx.x;
    for (int idx = tid; idx < 3 * 40 * 60; idx += 256) {
        int ky = idx / 2400; int n = (idx / 60) % 40; int c = idx % 60;
        int yy = y + ky - 1;
        Sr[ky][n][c] = (yy >= 0 && yy < 40) ? S[((size_t)b * 1600 + yy * 40 + n) * 60 + c] : 0.f;
    }
    for (int idx = tid; idx < 3 * 60 * 9; idx += 256) wts[idx] = w[idx];
    __syncthreads();
    if (tid < 240) {
        int p = tid % 120, half = tid / 120;
        int x = p % 40, co = p / 40;
        float acc = 0.f;
        int c0 = half * 30;
        for (int c = c0; c < c0 + 30; c++) {
            #pragma unroll
            for (int ky = 0; ky < 3; ky++) {
                const float* wr = &wts[(co * 60 + c) * 9 + ky * 3];
                float s0 = (x >= 1) ? Sr[ky][x - 1][c] : 0.f;
                float s1 = Sr[ky][x][c];
                float s2 = (x <= 38) ? Sr[ky][x + 1][c] : 0.f;
                acc += wr[0] * s0 + wr[1] * s1 + wr[2] * s2;
            }
        }
        part[half][p] = acc;
    }
    __syncthreads();
    if (tid < 120) {
        int x = tid % 40, co = tid / 40;
        out[((size_t)b * 3 + co) * 1600 + y * 40 + x] = part[0][tid] + part[1][tid] + bias[co];
    }
}

// ---------------------------------------------------------------- launch
extern "C" void kernel_launch(void* const* d_in, const int* in_sizes, int n_in,
                              void* d_out, int out_size, void* d_ws, size_t ws_size,
                              hipStream_t stream)
{
    const float* x   = (const float*)d_in[0];
    const float* ciw = (const float*)d_in[1];
    const float* cib = (const float*)d_in[2];
    const float* n1g = (const float*)d_in[3];
    const float* n1b = (const float*)d_in[4];
    const float* qw  = (const float*)d_in[5];
    const float* qb  = (const float*)d_in[6];
    const float* rpb = (const float*)d_in[7];
    const float* pw  = (const float*)d_in[8];
    const float* pb  = (const float*)d_in[9];
    const float* n2g = (const float*)d_in[10];
    const float* n2b = (const float*)d_in[11];
    const float* f1w = (const float*)d_in[12];
    const float* f1b = (const float*)d_in[13];
    const float* f2w = (const float*)d_in[14];
    const float* f2b = (const float*)d_in[15];
    const float* cow = (const float*)d_in[16];
    const float* cob = (const float*)d_in[17];
    float* out = (float*)d_out;
    float* S = (float*)d_ws;  // [128][1600][60] f32

    conv_in_k<<<128 * 40, 256, 0, stream>>>(x, ciw, cib, S);
    for (int i = 0; i < 4; i++) {
        int shift = (i & 1) ? 4 : 0;
        block_k<<<128 * 25, 256, 0, stream>>>(S,
            n1g + i * 60, n1b + i * 60,
            qw + i * 180 * 60, qb + i * 180, rpb + i * 225 * 10,
            pw + i * 3600, pb + i * 60,
            n2g + i * 60, n2b + i * 60,
            f1w + i * 240 * 60, f1b + i * 240, f2w + i * 60 * 240, f2b + i * 60,
            shift);
    }
    conv_out_k<<<128 * 40, 256, 0, stream>>>(S, cow, cob, out);
}

// Round 4
// 797.538 us; speedup vs baseline: 3.0117x; 1.5434x over previous
//
#include <hip/hip_runtime.h>
#include <math.h>

// B=128, H=W=40, C=60, L=1600, NH=10, HD=6, WS=8, N=64, NW=25, NB=4

typedef __bf16 bf16x8 __attribute__((ext_vector_type(8)));
typedef float f32x4 __attribute__((ext_vector_type(4)));
typedef unsigned int u32x4 __attribute__((ext_vector_type(4)));
typedef float f4u __attribute__((ext_vector_type(4), aligned(4)));

#define MFMA16(a, b, c) __builtin_amdgcn_mfma_f32_16x16x32_bf16(a, b, c, 0, 0, 0)

__device__ __forceinline__ unsigned short f2bf(float x) {
    unsigned u = __float_as_uint(x);
    return (unsigned short)((u + 0x7fffu + ((u >> 16) & 1u)) >> 16);
}
__device__ __forceinline__ float bfsel(unsigned u, int hi) {
    return __uint_as_float(hi ? (u & 0xffff0000u) : (u << 16));
}
__device__ __forceinline__ float gelu_f(float v) {
    float t = 0.7978845608028654f * (v + 0.044715f * v * v * v);
    float e = __expf(2.f * t);
    float th = (e - 1.f) / (e + 1.f);
    return 0.5f * v * (1.f + th);
}
__device__ __forceinline__ int gidx(int n, int wh, int wc, int shift) {
    int hh = wh * 8 + (n >> 3) + shift; if (hh >= 40) hh -= 40;
    int ww = wc * 8 + (n & 7) + shift;  if (ww >= 40) ww -= 40;
    return hh * 40 + ww;
}

// ---------------------------------------------------------------- weight pre-pack
// Wp layout per layer (shorts, 49152 total):
//   qkv tiles (ot 0..11, ks 0..1): (ot*2+ks)*512
//   pw   @12288: (ot*2+ks)*512, ot 0..3
//   f1w  @16384: ((ph*8+ot)*2+ks)*512, ot 0..7
//   f2w  @32768: ((ph*4+ot)*4+ks)*512, ot 0..3, ks 0..3
// rpb bf16 at Wp+196608: [layer][2250]
__global__ __launch_bounds__(256) void prep_k(
    const float* __restrict__ qkvw, const float* __restrict__ pw,
    const float* __restrict__ f1w, const float* __restrict__ f2w,
    const float* __restrict__ rpb, unsigned short* __restrict__ Wp)
{
    int t = blockIdx.x * 256 + threadIdx.x;  // 0..24575
    int lane = t & 63;
    int q6 = t >> 6;
    int layer = q6 / 96, tile = q6 % 96;
    int l15 = lane & 15, l4 = lane >> 4;
    const float* src; int row, stride, rmax, kmax, k0;
    unsigned short* dst = Wp + layer * 49152;
    if (tile < 24) {
        int ot = tile >> 1, ks = tile & 1;
        src = qkvw + layer * 10800; row = ot * 16 + l15; k0 = ks * 32 + l4 * 8;
        rmax = 180; kmax = 60; stride = 60; dst += tile * 512;
    } else if (tile < 32) {
        int tt = tile - 24; int ot = tt >> 1, ks = tt & 1;
        src = pw + layer * 3600; row = ot * 16 + l15; k0 = ks * 32 + l4 * 8;
        rmax = 60; kmax = 60; stride = 60; dst += 12288 + tt * 512;
    } else if (tile < 64) {
        int tt = tile - 32; int ks = tt & 1; int po = tt >> 1; int ot = po & 7; int ph = po >> 3;
        src = f1w + layer * 14400 + ph * 7200; row = ot * 16 + l15; k0 = ks * 32 + l4 * 8;
        rmax = 120; kmax = 60; stride = 60; dst += 16384 + tt * 512;
    } else {
        int tt = tile - 64; int ks = tt & 3; int po = tt >> 2; int ot = po & 3; int ph = po >> 2;
        src = f2w + layer * 14400 + ph * 120; row = ot * 16 + l15; k0 = ks * 32 + l4 * 8;
        rmax = 60; kmax = 120; stride = 240; dst += 32768 + tt * 512;
    }
    unsigned short v[8];
    #pragma unroll
    for (int i = 0; i < 8; i++) {
        int k = k0 + i;
        v[i] = (row < rmax && k < kmax) ? f2bf(src[row * stride + k]) : (unsigned short)0;
    }
    unsigned a0 = (unsigned)v[0] | ((unsigned)v[1] << 16);
    unsigned a1 = (unsigned)v[2] | ((unsigned)v[3] << 16);
    unsigned a2 = (unsigned)v[4] | ((unsigned)v[5] << 16);
    unsigned a3 = (unsigned)v[6] | ((unsigned)v[7] << 16);
    *(uint4*)(dst + lane * 8) = make_uint4(a0, a1, a2, a3);
    // rpb -> bf16
    for (int i = t; i < 9000; i += 24576)
        Wp[196608 + i] = f2bf(rpb[i]);
}

// ---------------------------------------------------------------- conv_in
__global__ __launch_bounds__(256) void conv_in_k(
    const float* __restrict__ x, const float* __restrict__ w,
    const float* __restrict__ bias, float* __restrict__ S)
{
    __shared__ float ins[3][18][40];
    __shared__ float wts[60 * 18 * 9];
    int b = blockIdx.x / 40, y = blockIdx.x % 40;
    int tid = threadIdx.x;
    const float* xb = x + (size_t)b * 18 * 1600;
    for (int idx = tid; idx < 3 * 18 * 40; idx += 256) {
        int ky = idx / (18 * 40); int ci = (idx / 40) % 18; int xx = idx % 40;
        int yy = y + ky - 1;
        ins[ky][ci][xx] = (yy >= 0 && yy < 40) ? xb[ci * 1600 + yy * 40 + xx] : 0.f;
    }
    for (int idx = tid; idx < 60 * 18 * 9; idx += 256) wts[idx] = w[idx];
    __syncthreads();
    if (tid < 240) {
        int c = tid % 60, g = tid / 60;
        int x0 = g * 10;
        float acc[10];
        float bv = bias[c];
        #pragma unroll
        for (int i = 0; i < 10; i++) acc[i] = bv;
        for (int ci = 0; ci < 18; ci++) {
            #pragma unroll
            for (int ky = 0; ky < 3; ky++) {
                const float* wr = &wts[(c * 18 + ci) * 9 + ky * 3];
                float w0 = wr[0], w1 = wr[1], w2 = wr[2];
                float v[12];
                #pragma unroll
                for (int j = 0; j < 12; j++) {
                    int xx = x0 + j - 1;
                    v[j] = (xx >= 0 && xx < 40) ? ins[ky][ci][xx] : 0.f;
                }
                #pragma unroll
                for (int i = 0; i < 10; i++)
                    acc[i] += w0 * v[i] + w1 * v[i + 1] + w2 * v[i + 2];
            }
        }
        float* Sp = S + ((size_t)b * 1600 + y * 40 + x0) * 60 + c;
        #pragma unroll
        for (int i = 0; i < 10; i++) Sp[i * 60] = acc[i];
    }
}

// ---------------------------------------------------------------- fused Swin block (MFMA + packed weights)
__global__ __launch_bounds__(256, 3) void block_k(
    float* __restrict__ S,
    const float* __restrict__ g1, const float* __restrict__ b1,
    const unsigned short* __restrict__ WpL, const unsigned short* __restrict__ rpb16L,
    const float* __restrict__ qkvb, const float* __restrict__ pb,
    const float* __restrict__ g2, const float* __restrict__ b2,
    const float* __restrict__ f1b, const float* __restrict__ f2b,
    int shift)
{
    // LDS map (bytes):
    //  [0,4500)      rpl bf16[2250]      \ both overlaid by x1t f32[60][65] = [0,15600)
    //  [4608,13824)  Pl  bf16[64][72]    /   (x1t live only after B2.5)
    //  [15600,24816) xln bf16[64][72]  -> h1 bf16[64][136] spans [15600,33008)
    //  [24816,34032) qn  bf16[64][72] (o_lds after head loop)
    //  [34032,43248) kn  bf16[64][72]
    //  [43248,53616) vt  bf16[72][72]  -> ln2 bf16[64][72]
    __shared__ __align__(16) unsigned char LDSA[53616];
    unsigned short* rpl = (unsigned short*)(LDSA + 0);
    unsigned short* Pl  = (unsigned short*)(LDSA + 4608);
    float*          x1t = (float*)(LDSA + 0);
    unsigned short* xln = (unsigned short*)(LDSA + 15600);
    unsigned short* h1  = (unsigned short*)(LDSA + 15600);
    unsigned short* qn  = (unsigned short*)(LDSA + 24816);
    unsigned short* kn  = (unsigned short*)(LDSA + 34032);
    unsigned short* vt  = (unsigned short*)(LDSA + 43248);
    unsigned short* ln2 = (unsigned short*)(LDSA + 43248);

    const int tid = threadIdx.x;
    const int lane = tid & 63, w = tid >> 6;
    const int l15 = lane & 15, l4 = lane >> 4;
    const int wbase = w * 16;
    const int b = blockIdx.x / 25, wnd = blockIdx.x % 25;
    const int wh = wnd / 5, wc = wnd % 5;
    float* Sb = S + (size_t)b * 96000;
    const f32x4 zf = {0.f, 0.f, 0.f, 0.f};
    u32x4 zu = {0u, 0u, 0u, 0u};
    const bf16x8 zb = __builtin_bit_cast(bf16x8, zu);

    // ---- stage rpb (bf16 copy, no cvt)
    for (int idx = tid; idx < 1125; idx += 256)
        ((unsigned*)rpl)[idx] = ((const unsigned*)rpb16L)[idx];

    // ---- LN1: global x -> xln (bf16, n-major, cols 60..63 zeroed)
    {
        int n = tid >> 2, p = tid & 3, cb = p * 15;
        int g = gidx(n, wh, wc, shift);
        const float* xp = Sb + (size_t)g * 60 + cb;
        float xv[15];
        #pragma unroll
        for (int ii = 0; ii < 15; ii++) xv[ii] = xp[ii];
        float s = 0.f;
        #pragma unroll
        for (int ii = 0; ii < 15; ii++) s += xv[ii];
        s += __shfl_xor(s, 1); s += __shfl_xor(s, 2);
        float mean = s * (1.f / 60.f);
        float vv = 0.f;
        #pragma unroll
        for (int ii = 0; ii < 15; ii++) { float d = xv[ii] - mean; vv += d * d; }
        vv += __shfl_xor(vv, 1); vv += __shfl_xor(vv, 2);
        float rs = rsqrtf(vv * (1.f / 60.f) + 1e-5f);
        unsigned short* xr = xln + n * 72;
        #pragma unroll
        for (int ii = 0; ii < 15; ii++)
            xr[cb + ii] = f2bf((xv[ii] - mean) * rs * g1[cb + ii] + b1[cb + ii]);
        if (p == 3) { *(unsigned int*)(xr + 60) = 0u; *(unsigned int*)(xr + 62) = 0u; }
    }
    __syncthreads();  // B1

    // ---- QKV: packed-weight MFMA; q scaled; q,k n-major; v transposed
    {
        bf16x8 bx[4][2];
        #pragma unroll
        for (int nt = 0; nt < 4; nt++)
            #pragma unroll
            for (int ks = 0; ks < 2; ks++)
                bx[nt][ks] = *(const bf16x8*)(xln + (nt * 16 + l15) * 72 + l4 * 8 + ks * 32);
        #pragma unroll
        for (int t = 0; t < 3; t++) {
            int ot = w * 3 + t;
            f32x4 acc[4];
            #pragma unroll
            for (int nt = 0; nt < 4; nt++) acc[nt] = zf;
            #pragma unroll
            for (int ks = 0; ks < 2; ks++) {
                bf16x8 a = *(const bf16x8*)(WpL + (ot * 2 + ks) * 512 + lane * 8);
                #pragma unroll
                for (int nt = 0; nt < 4; nt++) acc[nt] = MFMA16(a, bx[nt][ks], acc[nt]);
            }
            int o0 = ot * 16 + l4 * 4;
            if (o0 < 180) {
                f4u bias = *(const f4u*)(qkvb + o0);
                #pragma unroll
                for (int nt = 0; nt < 4; nt++) {
                    int n = nt * 16 + l15;
                    float v0 = acc[nt][0] + bias[0], v1 = acc[nt][1] + bias[1];
                    float v2 = acc[nt][2] + bias[2], v3 = acc[nt][3] + bias[3];
                    if (o0 < 60) {
                        const float sc = 0.40824829046386302f;
                        *(ushort4*)(qn + n * 72 + o0) =
                            make_ushort4(f2bf(v0 * sc), f2bf(v1 * sc), f2bf(v2 * sc), f2bf(v3 * sc));
                    } else if (o0 < 120) {
                        *(ushort4*)(kn + n * 72 + (o0 - 60)) =
                            make_ushort4(f2bf(v0), f2bf(v1), f2bf(v2), f2bf(v3));
                    } else {
                        int r = o0 - 120;
                        vt[(r + 0) * 72 + n] = f2bf(v0);
                        vt[(r + 1) * 72 + n] = f2bf(v1);
                        vt[(r + 2) * 72 + n] = f2bf(v2);
                        vt[(r + 3) * 72 + n] = f2bf(v3);
                    }
                }
            }
        }
    }
    __syncthreads();  // B2

    // ---- rel-pos byte offsets + shift mask bits (once per block)
    unsigned maskbits = 0u;
    int rel20[16];
    #pragma unroll
    for (int e = 0; e < 16; e++) {
        int nt2 = e >> 2, j = e & 3;
        int n1 = wbase + l4 * 4 + j;
        int n2 = nt2 * 16 + l15;
        int ri = n1 >> 3, ci = n1 & 7, rj = n2 >> 3, cj = n2 & 7;
        rel20[e] = ((ri - rj + 7) * 15 + (ci - cj + 7)) * 20;
        if (shift) {
            int shp = wh * 8 + ri, swp = wc * 8 + ci, shq = wh * 8 + rj, swq = wc * 8 + cj;
            int ra = (shp < 32 ? 0 : (shp < 36 ? 1 : 2)) * 3 + (swp < 32 ? 0 : (swp < 36 ? 1 : 2));
            int rb = (shq < 32 ? 0 : (shq < 36 ? 1 : 2)) * 3 + (swq < 32 ? 0 : (swq < 36 ? 1 : 2));
            if (ra != rb) maskbits |= (1u << e);
        }
    }

    // ---- head loop (barrier-free; head pairs share rpb dwords)
    f32x4 oacc[10];
    #pragma unroll
    for (int h = 0; h < 10; h++) oacc[h] = zf;
    const unsigned char* rplb = (const unsigned char*)rpl;

    #pragma unroll
    for (int hp = 0; hp < 5; hp++) {
        unsigned rp[16];
        #pragma unroll
        for (int e = 0; e < 16; e++)
            rp[e] = *(const unsigned*)(rplb + rel20[e] + hp * 4);
        #pragma unroll
        for (int hh2 = 0; hh2 < 2; hh2++) {
            const int h = hp * 2 + hh2;
            bf16x8 aq = zb, bk0 = zb, bk1 = zb, bk2 = zb, bk3 = zb;
            if (l4 == 0) {
                const unsigned* qp = (const unsigned*)(qn + (wbase + l15) * 72 + h * 6);
                u32x4 uq = {qp[0], qp[1], qp[2], 0u};
                aq = __builtin_bit_cast(bf16x8, uq);
                const unsigned* k0p = (const unsigned*)(kn + (0 * 16 + l15) * 72 + h * 6);
                const unsigned* k1p = (const unsigned*)(kn + (1 * 16 + l15) * 72 + h * 6);
                const unsigned* k2p = (const unsigned*)(kn + (2 * 16 + l15) * 72 + h * 6);
                const unsigned* k3p = (const unsigned*)(kn + (3 * 16 + l15) * 72 + h * 6);
                u32x4 u0 = {k0p[0], k0p[1], k0p[2], 0u}; bk0 = __builtin_bit_cast(bf16x8, u0);
                u32x4 u1 = {k1p[0], k1p[1], k1p[2], 0u}; bk1 = __builtin_bit_cast(bf16x8, u1);
                u32x4 u2 = {k2p[0], k2p[1], k2p[2], 0u}; bk2 = __builtin_bit_cast(bf16x8, u2);
                u32x4 u3 = {k3p[0], k3p[1], k3p[2], 0u}; bk3 = __builtin_bit_cast(bf16x8, u3);
            }
            f32x4 s0 = MFMA16(aq, bk0, zf);
            f32x4 s1 = MFMA16(aq, bk1, zf);
            f32x4 s2 = MFMA16(aq, bk2, zf);
            f32x4 s3 = MFMA16(aq, bk3, zf);
            float p[16];
            #pragma unroll
            for (int j = 0; j < 4; j++) {
                float e0 = __expf(s0[j] + bfsel(rp[j], hh2));
                float e1 = __expf(s1[j] + bfsel(rp[4 + j], hh2));
                float e2 = __expf(s2[j] + bfsel(rp[8 + j], hh2));
                float e3 = __expf(s3[j] + bfsel(rp[12 + j], hh2));
                if (maskbits & (1u << (0 + j)))  e0 = 0.f;
                if (maskbits & (1u << (4 + j)))  e1 = 0.f;
                if (maskbits & (1u << (8 + j)))  e2 = 0.f;
                if (maskbits & (1u << (12 + j))) e3 = 0.f;
                float tsum = e0 + e1 + e2 + e3;
                tsum += __shfl_xor(tsum, 1); tsum += __shfl_xor(tsum, 2);
                tsum += __shfl_xor(tsum, 4); tsum += __shfl_xor(tsum, 8);
                float ri_ = __builtin_amdgcn_rcpf(tsum);
                p[0 + j] = e0 * ri_; p[4 + j] = e1 * ri_;
                p[8 + j] = e2 * ri_; p[12 + j] = e3 * ri_;
            }
            #pragma unroll
            for (int e = 0; e < 16; e++) {
                int nt2 = e >> 2, j = e & 3;
                Pl[(wbase + l4 * 4 + j) * 72 + nt2 * 16 + l15] = f2bf(p[e]);
            }
            asm volatile("s_waitcnt lgkmcnt(0)" ::: "memory");
            #pragma unroll
            for (int ks = 0; ks < 2; ks++) {
                bf16x8 ap = *(const bf16x8*)(Pl + (wbase + l15) * 72 + l4 * 8 + ks * 32);
                bf16x8 bv = *(const bf16x8*)(vt + (h * 6 + l15) * 72 + l4 * 8 + ks * 32);
                oacc[h] = MFMA16(ap, bv, oacc[h]);
            }
        }
    }

    // ---- attention output -> olds (= qn slab), zero pad cols 60..63
    unsigned short* olds = qn;
    if (l15 < 6) {
        #pragma unroll
        for (int h = 0; h < 10; h++)
            #pragma unroll
            for (int j = 0; j < 4; j++)
                olds[(wbase + l4 * 4 + j) * 72 + h * 6 + l15] = f2bf(oacc[h][j]);
    } else if (l15 < 10) {
        #pragma unroll
        for (int j = 0; j < 4; j++)
            olds[(wbase + l4 * 4 + j) * 72 + 60 + (l15 - 6)] = 0;
    }
    __syncthreads();  // B2.5: all waves past Pl/vt/kn reads; x1t & ln2 overlays safe

    // ---- proj + residual -> x1t (fp32)
    {
        bf16x8 bo[2];
        #pragma unroll
        for (int ks = 0; ks < 2; ks++)
            bo[ks] = *(const bf16x8*)(olds + (wbase + l15) * 72 + l4 * 8 + ks * 32);
        f32x4 acc[4];
        #pragma unroll
        for (int ot = 0; ot < 4; ot++) acc[ot] = zf;
        #pragma unroll
        for (int ot = 0; ot < 4; ot++)
            #pragma unroll
            for (int ks = 0; ks < 2; ks++) {
                bf16x8 a = *(const bf16x8*)(WpL + 12288 + (ot * 2 + ks) * 512 + lane * 8);
                acc[ot] = MFMA16(a, bo[ks], acc[ot]);
            }
        int n = wbase + l15;
        int g = gidx(n, wh, wc, shift);
        #pragma unroll
        for (int ot = 0; ot < 4; ot++) {
            int o0 = ot * 16 + l4 * 4;
            if (o0 < 60) {
                float4 xr = *(const float4*)(Sb + (size_t)g * 60 + o0);
                f4u pbv = *(const f4u*)(pb + o0);
                x1t[(o0 + 0) * 65 + n] = xr.x + acc[ot][0] + pbv[0];
                x1t[(o0 + 1) * 65 + n] = xr.y + acc[ot][1] + pbv[1];
                x1t[(o0 + 2) * 65 + n] = xr.z + acc[ot][2] + pbv[2];
                x1t[(o0 + 3) * 65 + n] = xr.w + acc[ot][3] + pbv[3];
            }
        }
    }
    asm volatile("s_waitcnt lgkmcnt(0)" ::: "memory");

    // ---- LN2 (wave-local tokens) -> ln2
    {
        int n = wbase + (lane >> 2), p = lane & 3, cb = p * 15;
        float xv[15];
        #pragma unroll
        for (int ii = 0; ii < 15; ii++) xv[ii] = x1t[(cb + ii) * 65 + n];
        float s = 0.f;
        #pragma unroll
        for (int ii = 0; ii < 15; ii++) s += xv[ii];
        s += __shfl_xor(s, 1); s += __shfl_xor(s, 2);
        float mean = s * (1.f / 60.f);
        float vv = 0.f;
        #pragma unroll
        for (int ii = 0; ii < 15; ii++) { float d = xv[ii] - mean; vv += d * d; }
        vv += __shfl_xor(vv, 1); vv += __shfl_xor(vv, 2);
        float rs = rsqrtf(vv * (1.f / 60.f) + 1e-5f);
        unsigned short* lr = ln2 + n * 72;
        #pragma unroll
        for (int ii = 0; ii < 15; ii++)
            lr[cb + ii] = f2bf((xv[ii] - mean) * rs * g2[cb + ii] + b2[cb + ii]);
        if (p == 3) { *(unsigned int*)(lr + 60) = 0u; *(unsigned int*)(lr + 62) = 0u; }
    }
    __syncthreads();  // B3

    // ---- MLP: fc1+gelu (2 halves of 120) -> h1; fc2 accumulates
    f32x4 acc2[4];
    #pragma unroll
    for (int ot = 0; ot < 4; ot++) acc2[ot] = zf;

    #pragma unroll
    for (int ph = 0; ph < 2; ph++) {
        {
            bf16x8 bl[4][2];
            #pragma unroll
            for (int nt = 0; nt < 4; nt++)
                #pragma unroll
                for (int ks = 0; ks < 2; ks++)
                    bl[nt][ks] = *(const bf16x8*)(ln2 + (nt * 16 + l15) * 72 + l4 * 8 + ks * 32);
            #pragma unroll
            for (int t = 0; t < 2; t++) {
                int ot = w + t * 4;
                f32x4 a1[4];
                #pragma unroll
                for (int nt = 0; nt < 4; nt++) a1[nt] = zf;
                #pragma unroll
                for (int ks = 0; ks < 2; ks++) {
                    bf16x8 a = *(const bf16x8*)(WpL + 16384 + ((ph * 8 + ot) * 2 + ks) * 512 + lane * 8);
                    #pragma unroll
                    for (int nt = 0; nt < 4; nt++) a1[nt] = MFMA16(a, bl[nt][ks], a1[nt]);
                }
                int o0 = ot * 16 + l4 * 4;
                if (o0 < 120) {
                    f4u b4 = *(const f4u*)(f1b + ph * 120 + o0);
                    #pragma unroll
                    for (int nt = 0; nt < 4; nt++) {
                        int n = nt * 16 + l15;
                        *(ushort4*)(h1 + n * 136 + o0) = make_ushort4(
                            f2bf(gelu_f(a1[nt][0] + b4[0])), f2bf(gelu_f(a1[nt][1] + b4[1])),
                            f2bf(gelu_f(a1[nt][2] + b4[2])), f2bf(gelu_f(a1[nt][3] + b4[3])));
                    }
                }
            }
            if (ph == 0 && tid < 64)
                *(uint4*)(h1 + tid * 136 + 120) = make_uint4(0u, 0u, 0u, 0u);
        }
        __syncthreads();
        {
            bf16x8 bh[4];
            #pragma unroll
            for (int ks = 0; ks < 4; ks++)
                bh[ks] = *(const bf16x8*)(h1 + (wbase + l15) * 136 + l4 * 8 + ks * 32);
            #pragma unroll
            for (int ot = 0; ot < 4; ot++)
                #pragma unroll
                for (int ks = 0; ks < 4; ks++) {
                    bf16x8 a = *(const bf16x8*)(WpL + 32768 + ((ph * 4 + ot) * 4 + ks) * 512 + lane * 8);
                    acc2[ot] = MFMA16(a, bh[ks], acc2[ot]);
                }
        }
        if (ph == 0) __syncthreads();
    }

    // ---- final: S[g] = x1 + fc2out + bias
    {
        int n = wbase + l15;
        int g = gidx(n, wh, wc, shift);
        #pragma unroll
        for (int ot = 0; ot < 4; ot++) {
            int o0 = ot * 16 + l4 * 4;
            if (o0 < 60) {
                f4u fb = *(const f4u*)(f2b + o0);
                float4 r;
                r.x = x1t[(o0 + 0) * 65 + n] + acc2[ot][0] + fb[0];
                r.y = x1t[(o0 + 1) * 65 + n] + acc2[ot][1] + fb[1];
                r.z = x1t[(o0 + 2) * 65 + n] + acc2[ot][2] + fb[2];
                r.w = x1t[(o0 + 3) * 65 + n] + acc2[ot][3] + fb[3];
                *(float4*)(Sb + (size_t)g * 60 + o0) = r;
            }
        }
    }
}

// ---------------------------------------------------------------- conv_out
__global__ __launch_bounds__(256) void conv_out_k(
    const float* __restrict__ S, const float* __restrict__ w,
    const float* __restrict__ bias, float* __restrict__ out)
{
    __shared__ float Sr[3][40][60];
    __shared__ float wts[3 * 60 * 9];
    __shared__ float part[2][120];
    int b = blockIdx.x / 40, y = blockIdx.x % 40;
    int tid = threadIdx.x;
    for (int idx = tid; idx < 3 * 40 * 60; idx += 256) {
        int ky = idx / 2400; int n = (idx / 60) % 40; int c = idx % 60;
        int yy = y + ky - 1;
        Sr[ky][n][c] = (yy >= 0 && yy < 40) ? S[((size_t)b * 1600 + yy * 40 + n) * 60 + c] : 0.f;
    }
    for (int idx = tid; idx < 3 * 60 * 9; idx += 256) wts[idx] = w[idx];
    __syncthreads();
    if (tid < 240) {
        int p = tid % 120, half = tid / 120;
        int x = p % 40, co = p / 40;
        float acc = 0.f;
        int c0 = half * 30;
        for (int c = c0; c < c0 + 30; c++) {
            #pragma unroll
            for (int ky = 0; ky < 3; ky++) {
                const float* wr = &wts[(co * 60 + c) * 9 + ky * 3];
                float s0 = (x >= 1) ? Sr[ky][x - 1][c] : 0.f;
                float s1 = Sr[ky][x][c];
                float s2 = (x <= 38) ? Sr[ky][x + 1][c] : 0.f;
                acc += wr[0] * s0 + wr[1] * s1 + wr[2] * s2;
            }
        }
        part[half][p] = acc;
    }
    __syncthreads();
    if (tid < 120) {
        int x = tid % 40, co = tid / 40;
        out[((size_t)b * 3 + co) * 1600 + y * 40 + x] = part[0][tid] + part[1][tid] + bias[co];
    }
}

// ---------------------------------------------------------------- launch
extern "C" void kernel_launch(void* const* d_in, const int* in_sizes, int n_in,
                              void* d_out, int out_size, void* d_ws, size_t ws_size,
                              hipStream_t stream)
{
    const float* x   = (const float*)d_in[0];
    const float* ciw = (const float*)d_in[1];
    const float* cib = (const float*)d_in[2];
    const float* n1g = (const float*)d_in[3];
    const float* n1b = (const float*)d_in[4];
    const float* qw  = (const float*)d_in[5];
    const float* qb  = (const float*)d_in[6];
    const float* rpb = (const float*)d_in[7];
    const float* pw  = (const float*)d_in[8];
    const float* pb  = (const float*)d_in[9];
    const float* n2g = (const float*)d_in[10];
    const float* n2b = (const float*)d_in[11];
    const float* f1w = (const float*)d_in[12];
    const float* f1b = (const float*)d_in[13];
    const float* f2w = (const float*)d_in[14];
    const float* f2b = (const float*)d_in[15];
    const float* cow = (const float*)d_in[16];
    const float* cob = (const float*)d_in[17];
    float* out = (float*)d_out;
    float* S = (float*)d_ws;                                      // 49,152,000 B
    unsigned short* Wp = (unsigned short*)((char*)d_ws + 49152000); // 411,216 B packed weights + rpb16

    prep_k<<<96, 256, 0, stream>>>(qw, pw, f1w, f2w, rpb, Wp);
    conv_in_k<<<128 * 40, 256, 0, stream>>>(x, ciw, cib, S);
    for (int i = 0; i < 4; i++) {
        int shift = (i & 1) ? 4 : 0;
        block_k<<<128 * 25, 256, 0, stream>>>(S,
            n1g + i * 60, n1b + i * 60,
            Wp + i * 49152, Wp + 196608 + i * 2250,
            qb + i * 180, pb + i * 60,
            n2g + i * 60, n2b + i * 60,
            f1b + i * 240, f2b + i * 60,
            shift);
    }
    conv_out_k<<<128 * 40, 256, 0, stream>>>(S, cow, cob, out);
}

// Round 5
// 665.412 us; speedup vs baseline: 3.6097x; 1.1986x over previous
//
#include <hip/hip_runtime.h>
#include <math.h>

// B=128, H=W=40, C=60, L=1600, NH=10, HD=6, WS=8, N=64, NW=25, NB=4

typedef __bf16 bf16x8 __attribute__((ext_vector_type(8)));
typedef float f32x4 __attribute__((ext_vector_type(4)));
typedef unsigned int u32x4 __attribute__((ext_vector_type(4)));
typedef float f4u __attribute__((ext_vector_type(4), aligned(4)));

#define MFMA16(a, b, c) __builtin_amdgcn_mfma_f32_16x16x32_bf16(a, b, c, 0, 0, 0)

__device__ __forceinline__ unsigned short f2bf(float x) {  // RNE (prep only)
    unsigned u = __float_as_uint(x);
    return (unsigned short)((u + 0x7fffu + ((u >> 16) & 1u)) >> 16);
}
__device__ __forceinline__ unsigned short bfrn(float x) {  // round-nearest (ties up), 2 ops
    return (unsigned short)((__float_as_uint(x) + 0x8000u) >> 16);
}
__device__ __forceinline__ unsigned pk2rn(float a, float b) {  // pack 2 bf16, 3 ops
    unsigned ua = __float_as_uint(a) + 0x8000u;
    unsigned ub = __float_as_uint(b) + 0x8000u;
    return __builtin_amdgcn_perm(ub, ua, 0x07060302u);
}
__device__ __forceinline__ float bfsel(unsigned u, int hi) {
    return __uint_as_float(hi ? (u & 0xffff0000u) : (u << 16));
}
__device__ __forceinline__ float gelu_f(float v) {
    float t = v * (0.7978845608f + 0.0356774081f * v * v);
    float e = exp2f(t * 2.885390082f);
    float th = (e - 1.f) * __builtin_amdgcn_rcpf(e + 1.f);
    return 0.5f * v * (1.f + th);
}
__device__ __forceinline__ int gidx(int n, int wh, int wc, int shift) {
    int hh = wh * 8 + (n >> 3) + shift; if (hh >= 40) hh -= 40;
    int ww = wc * 8 + (n & 7) + shift;  if (ww >= 40) ww -= 40;
    return hh * 40 + ww;
}

// ---------------------------------------------------------------- weight pre-pack
// Per-layer (49152 shorts): qkv tiles (ot0..11,ks0..1)@0, pw@12288, f1w@16384, f2w@32768.
// K-padded fragments carry: LN-gamma folded into W cols, bias (+LN-beta dot) at k==kmax,
// q rows pre-scaled by 6^-0.5*log2e. rpb(*log2e) bf16 at Wp+196608.
__global__ __launch_bounds__(256) void prep_k(
    const float* __restrict__ qkvw, const float* __restrict__ pw,
    const float* __restrict__ f1w, const float* __restrict__ f2w,
    const float* __restrict__ rpb,
    const float* __restrict__ qkvb, const float* __restrict__ pb,
    const float* __restrict__ f1b, const float* __restrict__ f2b,
    const float* __restrict__ g1v, const float* __restrict__ b1v,
    const float* __restrict__ g2v, const float* __restrict__ b2v,
    unsigned short* __restrict__ Wp)
{
    int t = blockIdx.x * 256 + threadIdx.x;  // 0..24575
    int lane = t & 63;
    int q6 = t >> 6;
    int layer = q6 / 96, tile = q6 % 96;
    int l15 = lane & 15, l4 = lane >> 4;
    const float* src; const float* gam = 0; const float* bet = 0;
    float bias = 0.f, rowscale = 1.f;
    int row, stride, rmax, kmax, k0;
    unsigned short* dst = Wp + layer * 49152;
    if (tile < 24) {
        int ot = tile >> 1, ks = tile & 1;
        src = qkvw + layer * 10800; row = ot * 16 + l15; k0 = ks * 32 + l4 * 8;
        rmax = 180; kmax = 60; stride = 60; dst += tile * 512;
        gam = g1v + layer * 60; bet = b1v + layer * 60;
        if (row < 180) bias = qkvb[layer * 180 + row];
        if (row < 60) rowscale = 0.58897780f;  // 6^-0.5 * log2(e)
    } else if (tile < 32) {
        int tt = tile - 24;
        src = pw + layer * 3600; row = (tt >> 1) * 16 + l15; k0 = (tt & 1) * 32 + l4 * 8;
        rmax = 60; kmax = 60; stride = 60; dst += 12288 + tt * 512;
        if (row < 60) bias = pb[layer * 60 + row];
    } else if (tile < 64) {
        int tt = tile - 32; int ks = tt & 1; int po = tt >> 1; int ot = po & 7; int ph = po >> 3;
        src = f1w + layer * 14400 + ph * 7200; row = ot * 16 + l15; k0 = ks * 32 + l4 * 8;
        rmax = 120; kmax = 60; stride = 60; dst += 16384 + tt * 512;
        gam = g2v + layer * 60; bet = b2v + layer * 60;
        if (row < 120) bias = f1b[layer * 240 + ph * 120 + row];
    } else {
        int tt = tile - 64; int ks = tt & 3; int po = tt >> 2; int ot = po & 3; int ph = po >> 2;
        src = f2w + layer * 14400 + ph * 120; row = ot * 16 + l15; k0 = ks * 32 + l4 * 8;
        rmax = 60; kmax = 120; stride = 240; dst += 32768 + tt * 512;
        if (ph == 0 && row < 60) bias = f2b[layer * 60 + row];  // bias only once (ph0)
    }
    unsigned short v[8];
    #pragma unroll
    for (int i = 0; i < 8; i++) {
        int k = k0 + i;
        float f = 0.f;
        if (row < rmax) {
            if (k < kmax) {
                f = src[row * stride + k];
                if (gam) f *= gam[k];
            } else if (k == kmax) {
                f = bias;
                if (bet) for (int kk = 0; kk < kmax; kk++) f += src[row * stride + kk] * bet[kk];
            }
        }
        v[i] = f2bf(f * rowscale);
    }
    unsigned a0 = (unsigned)v[0] | ((unsigned)v[1] << 16);
    unsigned a1 = (unsigned)v[2] | ((unsigned)v[3] << 16);
    unsigned a2 = (unsigned)v[4] | ((unsigned)v[5] << 16);
    unsigned a3 = (unsigned)v[6] | ((unsigned)v[7] << 16);
    *(uint4*)(dst + lane * 8) = make_uint4(a0, a1, a2, a3);
    for (int i = t; i < 9000; i += 24576)
        Wp[196608 + i] = f2bf(rpb[i] * 1.4426950409f);
}

// ---------------------------------------------------------------- conv_in
__global__ __launch_bounds__(256) void conv_in_k(
    const float* __restrict__ x, const float* __restrict__ w,
    const float* __restrict__ bias, float* __restrict__ S)
{
    __shared__ float ins[3][18][40];
    __shared__ float wts[60 * 18 * 9];
    int b = blockIdx.x / 40, y = blockIdx.x % 40;
    int tid = threadIdx.x;
    const float* xb = x + (size_t)b * 18 * 1600;
    for (int idx = tid; idx < 3 * 18 * 40; idx += 256) {
        int ky = idx / (18 * 40); int ci = (idx / 40) % 18; int xx = idx % 40;
        int yy = y + ky - 1;
        ins[ky][ci][xx] = (yy >= 0 && yy < 40) ? xb[ci * 1600 + yy * 40 + xx] : 0.f;
    }
    for (int idx = tid; idx < 60 * 18 * 9; idx += 256) wts[idx] = w[idx];
    __syncthreads();
    if (tid < 240) {
        int c = tid % 60, g = tid / 60;
        int x0 = g * 10;
        float acc[10];
        float bv = bias[c];
        #pragma unroll
        for (int i = 0; i < 10; i++) acc[i] = bv;
        for (int ci = 0; ci < 18; ci++) {
            #pragma unroll
            for (int ky = 0; ky < 3; ky++) {
                const float* wr = &wts[(c * 18 + ci) * 9 + ky * 3];
                float w0 = wr[0], w1 = wr[1], w2 = wr[2];
                float v[12];
                #pragma unroll
                for (int j = 0; j < 12; j++) {
                    int xx = x0 + j - 1;
                    v[j] = (xx >= 0 && xx < 40) ? ins[ky][ci][xx] : 0.f;
                }
                #pragma unroll
                for (int i = 0; i < 10; i++)
                    acc[i] += w0 * v[i] + w1 * v[i + 1] + w2 * v[i + 2];
            }
        }
        float* Sp = S + ((size_t)b * 1600 + y * 40 + x0) * 60 + c;
        #pragma unroll
        for (int i = 0; i < 10; i++) Sp[i * 60] = acc[i];
    }
}

// ---------------------------------------------------------------- fused Swin block
template<int SHIFT>
__global__ __launch_bounds__(256, 3) void block_k(
    float* __restrict__ S,
    const unsigned short* __restrict__ WpL,
    const unsigned short* __restrict__ rpb16L)
{
    // LDS map (bytes):
    //  [0,4500)      rpl bf16[2250]     \ overlaid by x1t f32[60][65] = [0,15600) after B2.5
    //  [4608,13824)  Pl  bf16[64][72]   /
    //  [15600,24816) xln bf16[64][72] -> h1 bf16[64][136] spans [15600,33008)
    //  [24816,34032) qn  bf16[64][72] (olds after head loop)
    //  [34032,43248) kn  bf16[64][72]
    //  [43248,53616) vt  bf16[72][72] -> ln2 bf16[64][72]
    __shared__ __align__(16) unsigned char LDSA[53616];
    unsigned short* rpl = (unsigned short*)(LDSA + 0);
    unsigned short* Pl  = (unsigned short*)(LDSA + 4608);
    float*          x1t = (float*)(LDSA + 0);
    unsigned short* xln = (unsigned short*)(LDSA + 15600);
    unsigned short* h1  = (unsigned short*)(LDSA + 15600);
    unsigned short* qn  = (unsigned short*)(LDSA + 24816);
    unsigned short* kn  = (unsigned short*)(LDSA + 34032);
    unsigned short* vt  = (unsigned short*)(LDSA + 43248);
    unsigned short* ln2 = (unsigned short*)(LDSA + 43248);

    const int tid = threadIdx.x;
    const int lane = tid & 63, w = tid >> 6;
    const int l15 = lane & 15, l4 = lane >> 4;
    const int wbase = w * 16;
    const int b = blockIdx.x / 25, wnd = blockIdx.x % 25;
    const int wh = wnd / 5, wc = wnd % 5;
    float* Sb = S + (size_t)b * 96000;
    const f32x4 zf = {0.f, 0.f, 0.f, 0.f};
    u32x4 zu = {0u, 0u, 0u, 0u};
    const bf16x8 zb = __builtin_bit_cast(bf16x8, zu);
    u32x4 ou = {0x3F803F80u, 0x3F803F80u, 0x3F803F80u, 0x3F803F80u};
    const bf16x8 ones = __builtin_bit_cast(bf16x8, ou);

    // ---- stage rpb (already *log2e, bf16)
    for (int idx = tid; idx < 1125; idx += 256)
        ((unsigned*)rpl)[idx] = ((const unsigned*)rpb16L)[idx];

    // ---- LN1 (pure normalize; col60=1 bias slot) -> xln
    {
        int n = tid >> 2, p = tid & 3, cb = p * 16;
        int g = gidx(n, wh, wc, SHIFT);
        const float* xp = Sb + (size_t)g * 60 + cb;
        float xv[16];
        {
            float4 v0 = *(const float4*)xp;
            float4 v1 = *(const float4*)(xp + 4);
            float4 v2 = *(const float4*)(xp + 8);
            xv[0] = v0.x; xv[1] = v0.y; xv[2] = v0.z; xv[3] = v0.w;
            xv[4] = v1.x; xv[5] = v1.y; xv[6] = v1.z; xv[7] = v1.w;
            xv[8] = v2.x; xv[9] = v2.y; xv[10] = v2.z; xv[11] = v2.w;
            if (p < 3) {
                float4 v3 = *(const float4*)(xp + 12);
                xv[12] = v3.x; xv[13] = v3.y; xv[14] = v3.z; xv[15] = v3.w;
            } else { xv[12] = xv[13] = xv[14] = xv[15] = 0.f; }
        }
        float s = 0.f;
        #pragma unroll
        for (int ii = 0; ii < 16; ii++) s += xv[ii];
        s += __shfl_xor(s, 1); s += __shfl_xor(s, 2);
        float mean = s * (1.f / 60.f);
        float vv = 0.f;
        #pragma unroll
        for (int ii = 0; ii < 12; ii++) { float d = xv[ii] - mean; vv += d * d; }
        #pragma unroll
        for (int ii = 12; ii < 16; ii++) { float d = xv[ii] - mean; vv += (p < 3) ? d * d : 0.f; }
        vv += __shfl_xor(vv, 1); vv += __shfl_xor(vv, 2);
        float rs = rsqrtf(vv * (1.f / 60.f) + 1e-5f);
        float ov[16];
        #pragma unroll
        for (int ii = 0; ii < 12; ii++) ov[ii] = (xv[ii] - mean) * rs;
        #pragma unroll
        for (int ii = 12; ii < 16; ii++)
            ov[ii] = (p < 3) ? (xv[ii] - mean) * rs : ((ii == 12) ? 1.f : 0.f);
        unsigned short* xr = xln + n * 72 + cb;
        *(uint4*)xr = make_uint4(pk2rn(ov[0], ov[1]), pk2rn(ov[2], ov[3]),
                                 pk2rn(ov[4], ov[5]), pk2rn(ov[6], ov[7]));
        *(uint4*)(xr + 8) = make_uint4(pk2rn(ov[8], ov[9]), pk2rn(ov[10], ov[11]),
                                       pk2rn(ov[12], ov[13]), pk2rn(ov[14], ov[15]));
    }
    __syncthreads();  // B1

    // ---- QKV (bias in k=60 slot; q pre-scaled in weights)
    {
        bf16x8 bx[4][2];
        #pragma unroll
        for (int nt = 0; nt < 4; nt++)
            #pragma unroll
            for (int ks = 0; ks < 2; ks++)
                bx[nt][ks] = *(const bf16x8*)(xln + (nt * 16 + l15) * 72 + l4 * 8 + ks * 32);
        #pragma unroll
        for (int t = 0; t < 3; t++) {
            int ot = w * 3 + t;
            f32x4 acc[4];
            #pragma unroll
            for (int nt = 0; nt < 4; nt++) acc[nt] = zf;
            #pragma unroll
            for (int ks = 0; ks < 2; ks++) {
                bf16x8 a = *(const bf16x8*)(WpL + (ot * 2 + ks) * 512 + lane * 8);
                #pragma unroll
                for (int nt = 0; nt < 4; nt++) acc[nt] = MFMA16(a, bx[nt][ks], acc[nt]);
            }
            int o0 = ot * 16 + l4 * 4;
            #pragma unroll
            for (int nt = 0; nt < 4; nt++) {
                int n = nt * 16 + l15;
                if (o0 < 60) {
                    *(uint2*)(qn + n * 72 + o0) =
                        make_uint2(pk2rn(acc[nt][0], acc[nt][1]), pk2rn(acc[nt][2], acc[nt][3]));
                } else if (o0 < 120) {
                    *(uint2*)(kn + n * 72 + (o0 - 60)) =
                        make_uint2(pk2rn(acc[nt][0], acc[nt][1]), pk2rn(acc[nt][2], acc[nt][3]));
                } else {
                    int r = o0 - 120;
                    vt[(r + 0) * 72 + n] = bfrn(acc[nt][0]);
                    vt[(r + 1) * 72 + n] = bfrn(acc[nt][1]);
                    vt[(r + 2) * 72 + n] = bfrn(acc[nt][2]);
                    vt[(r + 3) * 72 + n] = bfrn(acc[nt][3]);
                }
            }
        }
    }
    __syncthreads();  // B2

    // ---- rel-pos byte offsets + mask bits (swapped layout: q=col=wbase+l15, j=row)
    int rel20[16];
    unsigned maskbits = 0u;
    {
        int qtok = wbase + l15;
        int qr = qtok >> 3, qc = qtok & 7;
        int qreg = 0;
        if (SHIFT) {
            int shp = wh * 8 + qr, swp = wc * 8 + qc;
            qreg = (shp < 32 ? 0 : (shp < 36 ? 1 : 2)) * 3 + (swp < 32 ? 0 : (swp < 36 ? 1 : 2));
        }
        #pragma unroll
        for (int e = 0; e < 16; e++) {
            int jt = e >> 2, r = e & 3;
            int j = jt * 16 + l4 * 4 + r;
            int jr = j >> 3, jc = j & 7;
            rel20[e] = ((qr - jr + 7) * 15 + (qc - jc + 7)) * 20;
            if (SHIFT) {
                int shq = wh * 8 + jr, swq = wc * 8 + jc;
                int jreg = (shq < 32 ? 0 : (shq < 36 ? 1 : 2)) * 3 + (swq < 32 ? 0 : (swq < 36 ? 1 : 2));
                if (jreg != qreg) maskbits |= (1u << e);
            }
        }
    }

    // ---- head loop (swapped QK^T; exp2; sum via MFMA(P,ones); deferred normalize)
    f32x4 oacc[10];
    #pragma unroll
    for (int h = 0; h < 10; h++) oacc[h] = zf;
    const unsigned char* rplb = (const unsigned char*)rpl;
    unsigned short* prow = Pl + (wbase + l15) * 72;

    #pragma unroll
    for (int hp = 0; hp < 5; hp++) {
        unsigned rp[16];
        #pragma unroll
        for (int e = 0; e < 16; e++)
            rp[e] = *(const unsigned*)(rplb + rel20[e] + hp * 4);
        #pragma unroll
        for (int hh2 = 0; hh2 < 2; hh2++) {
            const int h = hp * 2 + hh2;
            bf16x8 bq = zb, ak0 = zb, ak1 = zb, ak2 = zb, ak3 = zb;
            if (l4 == 0) {
                const unsigned* qp = (const unsigned*)(qn + (wbase + l15) * 72 + h * 6);
                u32x4 uq = {qp[0], qp[1], qp[2], 0u};
                bq = __builtin_bit_cast(bf16x8, uq);
                const unsigned* k0p = (const unsigned*)(kn + (0 * 16 + l15) * 72 + h * 6);
                const unsigned* k1p = (const unsigned*)(kn + (1 * 16 + l15) * 72 + h * 6);
                const unsigned* k2p = (const unsigned*)(kn + (2 * 16 + l15) * 72 + h * 6);
                const unsigned* k3p = (const unsigned*)(kn + (3 * 16 + l15) * 72 + h * 6);
                u32x4 u0 = {k0p[0], k0p[1], k0p[2], 0u}; ak0 = __builtin_bit_cast(bf16x8, u0);
                u32x4 u1 = {k1p[0], k1p[1], k1p[2], 0u}; ak1 = __builtin_bit_cast(bf16x8, u1);
                u32x4 u2 = {k2p[0], k2p[1], k2p[2], 0u}; ak2 = __builtin_bit_cast(bf16x8, u2);
                u32x4 u3 = {k3p[0], k3p[1], k3p[2], 0u}; ak3 = __builtin_bit_cast(bf16x8, u3);
            }
            f32x4 s0 = MFMA16(ak0, bq, zf);   // D[j-row][q-col]
            f32x4 s1 = MFMA16(ak1, bq, zf);
            f32x4 s2 = MFMA16(ak2, bq, zf);
            f32x4 s3 = MFMA16(ak3, bq, zf);
            float ee[16];
            #pragma unroll
            for (int r = 0; r < 4; r++) {
                ee[0 + r]  = exp2f(s0[r] + bfsel(rp[0 + r], hh2));
                ee[4 + r]  = exp2f(s1[r] + bfsel(rp[4 + r], hh2));
                ee[8 + r]  = exp2f(s2[r] + bfsel(rp[8 + r], hh2));
                ee[12 + r] = exp2f(s3[r] + bfsel(rp[12 + r], hh2));
            }
            if (SHIFT) {
                #pragma unroll
                for (int e = 0; e < 16; e++)
                    if (maskbits & (1u << e)) ee[e] = 0.f;
            }
            #pragma unroll
            for (int jt = 0; jt < 4; jt++)
                *(uint2*)(prow + jt * 16 + l4 * 4) =
                    make_uint2(pk2rn(ee[jt * 4 + 0], ee[jt * 4 + 1]),
                               pk2rn(ee[jt * 4 + 2], ee[jt * 4 + 3]));
            asm volatile("s_waitcnt lgkmcnt(0)" ::: "memory");
            bf16x8 ap0 = *(const bf16x8*)(prow + l4 * 8);
            bf16x8 ap1 = *(const bf16x8*)(prow + 32 + l4 * 8);
            bf16x8 bv0 = *(const bf16x8*)(vt + (h * 6 + l15) * 72 + l4 * 8);
            bf16x8 bv1 = *(const bf16x8*)(vt + (h * 6 + l15) * 72 + 32 + l4 * 8);
            f32x4 sm = MFMA16(ap0, ones, zf);
            sm = MFMA16(ap1, ones, sm);
            f32x4 pv = MFMA16(ap0, bv0, zf);
            pv = MFMA16(ap1, bv1, pv);
            #pragma unroll
            for (int r = 0; r < 4; r++)
                oacc[h][r] = pv[r] * __builtin_amdgcn_rcpf(sm[r]);
        }
    }

    // ---- attention out -> olds (=qn slab); col60=1 bias slot, 61-63 zero
    unsigned short* olds = qn;
    if (l15 < 6) {
        #pragma unroll
        for (int h = 0; h < 10; h++)
            #pragma unroll
            for (int j = 0; j < 4; j++)
                olds[(wbase + l4 * 4 + j) * 72 + h * 6 + l15] = bfrn(oacc[h][j]);
    } else if (l15 < 10) {
        unsigned short pv16 = (l15 == 6) ? (unsigned short)0x3F80 : (unsigned short)0;
        #pragma unroll
        for (int j = 0; j < 4; j++)
            olds[(wbase + l4 * 4 + j) * 72 + 60 + (l15 - 6)] = pv16;
    }
    __syncthreads();  // B2.5: Pl/vt/kn dead -> x1t & ln2 overlays safe

    // ---- proj + residual -> x1t (fp32)
    {
        bf16x8 bo0 = *(const bf16x8*)(olds + (wbase + l15) * 72 + l4 * 8);
        bf16x8 bo1 = *(const bf16x8*)(olds + (wbase + l15) * 72 + 32 + l4 * 8);
        f32x4 acc[4];
        #pragma unroll
        for (int ot = 0; ot < 4; ot++) acc[ot] = zf;
        #pragma unroll
        for (int ot = 0; ot < 4; ot++) {
            bf16x8 a0 = *(const bf16x8*)(WpL + 12288 + (ot * 2 + 0) * 512 + lane * 8);
            bf16x8 a1 = *(const bf16x8*)(WpL + 12288 + (ot * 2 + 1) * 512 + lane * 8);
            acc[ot] = MFMA16(a0, bo0, acc[ot]);
            acc[ot] = MFMA16(a1, bo1, acc[ot]);
        }
        int n = wbase + l15;
        int g = gidx(n, wh, wc, SHIFT);
        #pragma unroll
        for (int ot = 0; ot < 4; ot++) {
            int o0 = ot * 16 + l4 * 4;
            if (o0 < 60) {
                float4 xr = *(const float4*)(Sb + (size_t)g * 60 + o0);
                x1t[(o0 + 0) * 65 + n] = xr.x + acc[ot][0];
                x1t[(o0 + 1) * 65 + n] = xr.y + acc[ot][1];
                x1t[(o0 + 2) * 65 + n] = xr.z + acc[ot][2];
                x1t[(o0 + 3) * 65 + n] = xr.w + acc[ot][3];
            }
        }
    }
    asm volatile("s_waitcnt lgkmcnt(0)" ::: "memory");

    // ---- LN2 -> ln2 (pure normalize; col60=1)
    {
        int n = wbase + (lane >> 2), p = lane & 3, cb = p * 16;
        float xv[16];
        #pragma unroll
        for (int ii = 0; ii < 12; ii++) xv[ii] = x1t[(cb + ii) * 65 + n];
        #pragma unroll
        for (int ii = 12; ii < 16; ii++) xv[ii] = (p < 3) ? x1t[(cb + ii) * 65 + n] : 0.f;
        float s = 0.f;
        #pragma unroll
        for (int ii = 0; ii < 16; ii++) s += xv[ii];
        s += __shfl_xor(s, 1); s += __shfl_xor(s, 2);
        float mean = s * (1.f / 60.f);
        float vv = 0.f;
        #pragma unroll
        for (int ii = 0; ii < 12; ii++) { float d = xv[ii] - mean; vv += d * d; }
        #pragma unroll
        for (int ii = 12; ii < 16; ii++) { float d = xv[ii] - mean; vv += (p < 3) ? d * d : 0.f; }
        vv += __shfl_xor(vv, 1); vv += __shfl_xor(vv, 2);
        float rs = rsqrtf(vv * (1.f / 60.f) + 1e-5f);
        float ov[16];
        #pragma unroll
        for (int ii = 0; ii < 12; ii++) ov[ii] = (xv[ii] - mean) * rs;
        #pragma unroll
        for (int ii = 12; ii < 16; ii++)
            ov[ii] = (p < 3) ? (xv[ii] - mean) * rs : ((ii == 12) ? 1.f : 0.f);
        unsigned short* lr = ln2 + n * 72 + cb;
        *(uint4*)lr = make_uint4(pk2rn(ov[0], ov[1]), pk2rn(ov[2], ov[3]),
                                 pk2rn(ov[4], ov[5]), pk2rn(ov[6], ov[7]));
        *(uint4*)(lr + 8) = make_uint4(pk2rn(ov[8], ov[9]), pk2rn(ov[10], ov[11]),
                                       pk2rn(ov[12], ov[13]), pk2rn(ov[14], ov[15]));
    }
    __syncthreads();  // B3

    // ---- MLP: fc1+gelu (2 output-halves) -> h1; fc2 accumulates (bias via h1 col120=1)
    f32x4 acc2[4];
    #pragma unroll
    for (int ot = 0; ot < 4; ot++) acc2[ot] = zf;

    #pragma unroll
    for (int ph = 0; ph < 2; ph++) {
        {
            bf16x8 bl[4][2];
            #pragma unroll
            for (int nt = 0; nt < 4; nt++)
                #pragma unroll
                for (int ks = 0; ks < 2; ks++)
                    bl[nt][ks] = *(const bf16x8*)(ln2 + (nt * 16 + l15) * 72 + l4 * 8 + ks * 32);
            #pragma unroll
            for (int t = 0; t < 2; t++) {
                int ot = w + t * 4;
                f32x4 a1[4];
                #pragma unroll
                for (int nt = 0; nt < 4; nt++) a1[nt] = zf;
                #pragma unroll
                for (int ks = 0; ks < 2; ks++) {
                    bf16x8 a = *(const bf16x8*)(WpL + 16384 + ((ph * 8 + ot) * 2 + ks) * 512 + lane * 8);
                    #pragma unroll
                    for (int nt = 0; nt < 4; nt++) a1[nt] = MFMA16(a, bl[nt][ks], a1[nt]);
                }
                int o0 = ot * 16 + l4 * 4;
                if (o0 < 120) {
                    #pragma unroll
                    for (int nt = 0; nt < 4; nt++) {
                        int n = nt * 16 + l15;
                        *(uint2*)(h1 + n * 136 + o0) =
                            make_uint2(pk2rn(gelu_f(a1[nt][0]), gelu_f(a1[nt][1])),
                                       pk2rn(gelu_f(a1[nt][2]), gelu_f(a1[nt][3])));
                    }
                }
            }
            if (ph == 0 && tid < 64)
                *(uint4*)(h1 + tid * 136 + 120) = make_uint4(0x3F80u, 0u, 0u, 0u);
        }
        __syncthreads();
        {
            bf16x8 bh[4];
            #pragma unroll
            for (int ks = 0; ks < 4; ks++)
                bh[ks] = *(const bf16x8*)(h1 + (wbase + l15) * 136 + l4 * 8 + ks * 32);
            #pragma unroll
            for (int ot = 0; ot < 4; ot++)
                #pragma unroll
                for (int ks = 0; ks < 4; ks++) {
                    bf16x8 a = *(const bf16x8*)(WpL + 32768 + ((ph * 4 + ot) * 4 + ks) * 512 + lane * 8);
                    acc2[ot] = MFMA16(a, bh[ks], acc2[ot]);
                }
        }
        if (ph == 0) __syncthreads();
    }

    // ---- final: S[g] = x1 + fc2out
    {
        int n = wbase + l15;
        int g = gidx(n, wh, wc, SHIFT);
        #pragma unroll
        for (int ot = 0; ot < 4; ot++) {
            int o0 = ot * 16 + l4 * 4;
            if (o0 < 60) {
                float4 r;
                r.x = x1t[(o0 + 0) * 65 + n] + acc2[ot][0];
                r.y = x1t[(o0 + 1) * 65 + n] + acc2[ot][1];
                r.z = x1t[(o0 + 2) * 65 + n] + acc2[ot][2];
                r.w = x1t[(o0 + 3) * 65 + n] + acc2[ot][3];
                *(float4*)(Sb + (size_t)g * 60 + o0) = r;
            }
        }
    }
}

// ---------------------------------------------------------------- conv_out
__global__ __launch_bounds__(256) void conv_out_k(
    const float* __restrict__ S, const float* __restrict__ w,
    const float* __restrict__ bias, float* __restrict__ out)
{
    __shared__ float Sr[3][40][60];
    __shared__ float wts[3 * 60 * 9];
    __shared__ float part[2][120];
    int b = blockIdx.x / 40, y = blockIdx.x % 40;
    int tid = threadIdx.x;
    for (int idx = tid; idx < 3 * 40 * 60; idx += 256) {
        int ky = idx / 2400; int n = (idx / 60) % 40; int c = idx % 60;
        int yy = y + ky - 1;
        Sr[ky][n][c] = (yy >= 0 && yy < 40) ? S[((size_t)b * 1600 + yy * 40 + n) * 60 + c] : 0.f;
    }
    for (int idx = tid; idx < 3 * 60 * 9; idx += 256) wts[idx] = w[idx];
    __syncthreads();
    if (tid < 240) {
        int p = tid % 120, half = tid / 120;
        int x = p % 40, co = p / 40;
        float acc = 0.f;
        int c0 = half * 30;
        for (int c = c0; c < c0 + 30; c++) {
            #pragma unroll
            for (int ky = 0; ky < 3; ky++) {
                const float* wr = &wts[(co * 60 + c) * 9 + ky * 3];
                float s0 = (x >= 1) ? Sr[ky][x - 1][c] : 0.f;
                float s1 = Sr[ky][x][c];
                float s2 = (x <= 38) ? Sr[ky][x + 1][c] : 0.f;
                acc += wr[0] * s0 + wr[1] * s1 + wr[2] * s2;
            }
        }
        part[half][p] = acc;
    }
    __syncthreads();
    if (tid < 120) {
        int x = tid % 40, co = tid / 40;
        out[((size_t)b * 3 + co) * 1600 + y * 40 + x] = part[0][tid] + part[1][tid] + bias[co];
    }
}

// ---------------------------------------------------------------- launch
extern "C" void kernel_launch(void* const* d_in, const int* in_sizes, int n_in,
                              void* d_out, int out_size, void* d_ws, size_t ws_size,
                              hipStream_t stream)
{
    const float* x   = (const float*)d_in[0];
    const float* ciw = (const float*)d_in[1];
    const float* cib = (const float*)d_in[2];
    const float* n1g = (const float*)d_in[3];
    const float* n1b = (const float*)d_in[4];
    const float* qw  = (const float*)d_in[5];
    const float* qb  = (const float*)d_in[6];
    const float* rpb = (const float*)d_in[7];
    const float* pw  = (const float*)d_in[8];
    const float* pb  = (const float*)d_in[9];
    const float* n2g = (const float*)d_in[10];
    const float* n2b = (const float*)d_in[11];
    const float* f1w = (const float*)d_in[12];
    const float* f1b = (const float*)d_in[13];
    const float* f2w = (const float*)d_in[14];
    const float* f2b = (const float*)d_in[15];
    const float* cow = (const float*)d_in[16];
    const float* cob = (const float*)d_in[17];
    float* out = (float*)d_out;
    float* S = (float*)d_ws;                                        // 49,152,000 B
    unsigned short* Wp = (unsigned short*)((char*)d_ws + 49152000); // packed W + rpb16

    prep_k<<<96, 256, 0, stream>>>(qw, pw, f1w, f2w, rpb, qb, pb, f1b, f2b,
                                   n1g, n1b, n2g, n2b, Wp);
    conv_in_k<<<128 * 40, 256, 0, stream>>>(x, ciw, cib, S);
    for (int i = 0; i < 4; i++) {
        const unsigned short* WpL = Wp + i * 49152;
        const unsigned short* rpbL = Wp + 196608 + i * 2250;
        if (i & 1) block_k<4><<<128 * 25, 256, 0, stream>>>(S, WpL, rpbL);
        else       block_k<0><<<128 * 25, 256, 0, stream>>>(S, WpL, rpbL);
    }
    conv_out_k<<<128 * 40, 256, 0, stream>>>(S, cow, cob, out);
}

// Round 6
// 592.416 us; speedup vs baseline: 4.0545x; 1.1232x over previous
//
#include <hip/hip_runtime.h>
#include <math.h>

// B=128, H=W=40, C=60, L=1600, NH=10, HD=6, WS=8, N=64, NW=25, NB=4

typedef __bf16 bf16x8 __attribute__((ext_vector_type(8)));
typedef float f32x4 __attribute__((ext_vector_type(4)));
typedef unsigned int u32x4 __attribute__((ext_vector_type(4)));
typedef float f4u __attribute__((ext_vector_type(4), aligned(4)));

#define MFMA16(a, b, c) __builtin_amdgcn_mfma_f32_16x16x32_bf16(a, b, c, 0, 0, 0)

__device__ __forceinline__ unsigned short f2bf(float x) {  // RNE (prep only)
    unsigned u = __float_as_uint(x);
    return (unsigned short)((u + 0x7fffu + ((u >> 16) & 1u)) >> 16);
}
__device__ __forceinline__ unsigned short bfrn(float x) {  // 2 ops
    return (unsigned short)((__float_as_uint(x) + 0x8000u) >> 16);
}
__device__ __forceinline__ unsigned pk2rn(float a, float b) {  // 1 op: lo=bf16(a), hi=bf16(b)
    unsigned r;
    asm("v_cvt_pk_bf16_f32 %0, %1, %2" : "=v"(r) : "v"(a), "v"(b));
    return r;
}
__device__ __forceinline__ float bfsel(unsigned u, int hi) {
    return __uint_as_float(hi ? (u & 0xffff0000u) : (u << 16));
}
__device__ __forceinline__ float gelu_f(float v) {
    // gelu = v - v*rcp(exp2(v*(c1+c2*v^2))+1); c1=2*0.79788456*log2e, c2=c1*0.044715
    float t2 = v * v;
    float e = __builtin_amdgcn_exp2f(v * fmaf(0.102943225f, t2, 2.302207877f));
    float r = __builtin_amdgcn_rcpf(e + 1.f);
    return fmaf(-v, r, v);
}
__device__ __forceinline__ int gidx(int n, int wh, int wc, int shift) {
    int hh = wh * 8 + (n >> 3) + shift; if (hh >= 40) hh -= 40;
    int ww = wc * 8 + (n & 7) + shift;  if (ww >= 40) ww -= 40;
    return hh * 40 + ww;
}

// ---------------------------------------------------------------- weight pre-pack
// Per-layer (49152 shorts): qkv tiles (ot0..11,ks0..1)@0, pw@12288, f1w@16384, f2w@32768.
// LN-gamma folded into W cols, bias (+LN-beta dot) at k==kmax, q rows *6^-0.5*log2e.
__global__ __launch_bounds__(256) void prep_k(
    const float* __restrict__ qkvw, const float* __restrict__ pw,
    const float* __restrict__ f1w, const float* __restrict__ f2w,
    const float* __restrict__ qkvb, const float* __restrict__ pb,
    const float* __restrict__ f1b, const float* __restrict__ f2b,
    const float* __restrict__ g1v, const float* __restrict__ b1v,
    const float* __restrict__ g2v, const float* __restrict__ b2v,
    unsigned short* __restrict__ Wp)
{
    int t = blockIdx.x * 256 + threadIdx.x;  // 0..24575
    int lane = t & 63;
    int q6 = t >> 6;
    int layer = q6 / 96, tile = q6 % 96;
    int l15 = lane & 15, l4 = lane >> 4;
    const float* src; const float* gam = 0; const float* bet = 0;
    float bias = 0.f, rowscale = 1.f;
    int row, stride, rmax, kmax, k0;
    unsigned short* dst = Wp + layer * 49152;
    if (tile < 24) {
        int ot = tile >> 1, ks = tile & 1;
        src = qkvw + layer * 10800; row = ot * 16 + l15; k0 = ks * 32 + l4 * 8;
        rmax = 180; kmax = 60; stride = 60; dst += tile * 512;
        gam = g1v + layer * 60; bet = b1v + layer * 60;
        if (row < 180) bias = qkvb[layer * 180 + row];
        if (row < 60) rowscale = 0.58897780f;  // 6^-0.5 * log2(e)
    } else if (tile < 32) {
        int tt = tile - 24;
        src = pw + layer * 3600; row = (tt >> 1) * 16 + l15; k0 = (tt & 1) * 32 + l4 * 8;
        rmax = 60; kmax = 60; stride = 60; dst += 12288 + tt * 512;
        if (row < 60) bias = pb[layer * 60 + row];
    } else if (tile < 64) {
        int tt = tile - 32; int ks = tt & 1; int po = tt >> 1; int ot = po & 7; int ph = po >> 3;
        src = f1w + layer * 14400 + ph * 7200; row = ot * 16 + l15; k0 = ks * 32 + l4 * 8;
        rmax = 120; kmax = 60; stride = 60; dst += 16384 + tt * 512;
        gam = g2v + layer * 60; bet = b2v + layer * 60;
        if (row < 120) bias = f1b[layer * 240 + ph * 120 + row];
    } else {
        int tt = tile - 64; int ks = tt & 3; int po = tt >> 2; int ot = po & 3; int ph = po >> 2;
        src = f2w + layer * 14400 + ph * 120; row = ot * 16 + l15; k0 = ks * 32 + l4 * 8;
        rmax = 60; kmax = 120; stride = 240; dst += 32768 + tt * 512;
        if (ph == 0 && row < 60) bias = f2b[layer * 60 + row];  // bias only once (ph0)
    }
    unsigned short v[8];
    #pragma unroll
    for (int i = 0; i < 8; i++) {
        int k = k0 + i;
        float f = 0.f;
        if (row < rmax) {
            if (k < kmax) {
                f = src[row * stride + k];
                if (gam) f *= gam[k];
            } else if (k == kmax) {
                f = bias;
                if (bet) for (int kk = 0; kk < kmax; kk++) f += src[row * stride + kk] * bet[kk];
            }
        }
        v[i] = f2bf(f * rowscale);
    }
    unsigned a0 = (unsigned)v[0] | ((unsigned)v[1] << 16);
    unsigned a1 = (unsigned)v[2] | ((unsigned)v[3] << 16);
    unsigned a2 = (unsigned)v[4] | ((unsigned)v[5] << 16);
    unsigned a3 = (unsigned)v[6] | ((unsigned)v[7] << 16);
    *(uint4*)(dst + lane * 8) = make_uint4(a0, a1, a2, a3);
}

// ---------------------------------------------------------------- rpb pre-expansion
// rpbE[(layer*5+hp)][q][j] : dword = {lo: rpb[h=2hp][RPI(q,j)]*log2e, hi: h=2hp+1}
__global__ __launch_bounds__(256) void rpbexp_k(
    const float* __restrict__ rpb, unsigned* __restrict__ rpbE)
{
    int layer = blockIdx.x / 5, hp = blockIdx.x % 5;
    int tid = threadIdx.x;
    int q = tid >> 2, j0 = (tid & 3) * 16;
    const float* rsrc = rpb + layer * 2250 + hp * 2;
    unsigned* dst = rpbE + ((layer * 5 + hp) * 64 + q) * 64 + j0;
    int qr = q >> 3, qc = q & 7;
    #pragma unroll
    for (int jj = 0; jj < 16; jj++) {
        int j = j0 + jj;
        int jr = j >> 3, jc = j & 7;
        int ridx = ((qr - jr + 7) * 15 + (qc - jc + 7)) * 10;
        unsigned short lo = f2bf(rsrc[ridx] * 1.4426950409f);
        unsigned short hi = f2bf(rsrc[ridx + 1] * 1.4426950409f);
        dst[jj] = (unsigned)lo | ((unsigned)hi << 16);
    }
}

// ---------------------------------------------------------------- conv_in (4 rows/block, halo tile)
__global__ __launch_bounds__(256) void conv_in_k(
    const float* __restrict__ x, const float* __restrict__ w,
    const float* __restrict__ bias, float* __restrict__ S)
{
    __shared__ float ins[6][18][42];
    __shared__ float wts[60 * 18 * 9];
    int b = blockIdx.x / 10, y0 = (blockIdx.x % 10) * 4;
    int tid = threadIdx.x;
    const float* xb = x + (size_t)b * 18 * 1600;
    for (int idx = tid; idx < 6 * 18 * 42; idx += 256) {
        int ry = idx / (18 * 42); int ci = (idx / 42) % 18; int xx = idx % 42;
        int yy = y0 + ry - 1; int xs = xx - 1;
        ins[ry][ci][xx] = (yy >= 0 && yy < 40 && xs >= 0 && xs < 40)
                          ? xb[ci * 1600 + yy * 40 + xs] : 0.f;
    }
    for (int idx = tid; idx < 60 * 18 * 9; idx += 256) wts[idx] = w[idx];
    __syncthreads();
    if (tid < 240) {
        int c = tid % 60, g = tid / 60;
        int x0 = g * 10;
        float bv = bias[c];
        for (int ry = 0; ry < 4; ry++) {
            float acc[10];
            #pragma unroll
            for (int i = 0; i < 10; i++) acc[i] = bv;
            for (int ci = 0; ci < 18; ci++) {
                #pragma unroll
                for (int ky = 0; ky < 3; ky++) {
                    const float* wr = &wts[(c * 18 + ci) * 9 + ky * 3];
                    const float* ir = &ins[ry + ky][ci][x0];
                    float w0 = wr[0], w1 = wr[1], w2 = wr[2];
                    #pragma unroll
                    for (int i = 0; i < 10; i++)
                        acc[i] += w0 * ir[i] + w1 * ir[i + 1] + w2 * ir[i + 2];
                }
            }
            float* Sp = S + ((size_t)b * 1600 + (y0 + ry) * 40 + x0) * 60 + c;
            #pragma unroll
            for (int i = 0; i < 10; i++) Sp[i * 60] = acc[i];
        }
    }
}

// ---------------------------------------------------------------- fused Swin block
template<int SHIFT>
__global__ __launch_bounds__(256, 3) void block_k(
    float* __restrict__ S,
    const unsigned short* __restrict__ WpL,
    const unsigned* __restrict__ rpE)
{
    // LDS map (bytes):
    //  [4608,13824)  Pl  bf16[64][72]   (overlaid by x1t f32[60][65] = [0,15600) after B2.5)
    //  [15600,24816) xln bf16[64][72] -> h1 bf16[64][136] spans [15600,33008)
    //  [24816,34032) qn  bf16[64][72] (olds after head loop)
    //  [34032,43248) kn  bf16[64][72]
    //  [43248,53616) vt  bf16[72][72] -> ln2 bf16[64][72]
    __shared__ __align__(16) unsigned char LDSA[53616];
    unsigned short* Pl  = (unsigned short*)(LDSA + 4608);
    float*          x1t = (float*)(LDSA + 0);
    unsigned short* xln = (unsigned short*)(LDSA + 15600);
    unsigned short* h1  = (unsigned short*)(LDSA + 15600);
    unsigned short* qn  = (unsigned short*)(LDSA + 24816);
    unsigned short* kn  = (unsigned short*)(LDSA + 34032);
    unsigned short* vt  = (unsigned short*)(LDSA + 43248);
    unsigned short* ln2 = (unsigned short*)(LDSA + 43248);

    const int tid = threadIdx.x;
    const int lane = tid & 63, w = tid >> 6;
    const int l15 = lane & 15, l4 = lane >> 4;
    const int wbase = w * 16;
    const int b = blockIdx.x / 25, wnd = blockIdx.x % 25;
    const int wh = wnd / 5, wc = wnd % 5;
    float* Sb = S + (size_t)b * 96000;
    const f32x4 zf = {0.f, 0.f, 0.f, 0.f};
    u32x4 zu = {0u, 0u, 0u, 0u};
    const bf16x8 zb = __builtin_bit_cast(bf16x8, zu);
    u32x4 ou = {0x3F803F80u, 0x3F803F80u, 0x3F803F80u, 0x3F803F80u};
    const bf16x8 ones = __builtin_bit_cast(bf16x8, ou);

    // ---- LN1 (pure normalize; col60=1 bias slot) -> xln
    {
        int n = tid >> 2, p = tid & 3, cb = p * 16;
        int g = gidx(n, wh, wc, SHIFT);
        const float* xp = Sb + (size_t)g * 60 + cb;
        float xv[16];
        {
            float4 v0 = *(const float4*)xp;
            float4 v1 = *(const float4*)(xp + 4);
            float4 v2 = *(const float4*)(xp + 8);
            xv[0] = v0.x; xv[1] = v0.y; xv[2] = v0.z; xv[3] = v0.w;
            xv[4] = v1.x; xv[5] = v1.y; xv[6] = v1.z; xv[7] = v1.w;
            xv[8] = v2.x; xv[9] = v2.y; xv[10] = v2.z; xv[11] = v2.w;
            if (p < 3) {
                float4 v3 = *(const float4*)(xp + 12);
                xv[12] = v3.x; xv[13] = v3.y; xv[14] = v3.z; xv[15] = v3.w;
            } else { xv[12] = xv[13] = xv[14] = xv[15] = 0.f; }
        }
        float s = 0.f;
        #pragma unroll
        for (int ii = 0; ii < 16; ii++) s += xv[ii];
        s += __shfl_xor(s, 1); s += __shfl_xor(s, 2);
        float mean = s * (1.f / 60.f);
        float vv = 0.f;
        #pragma unroll
        for (int ii = 0; ii < 12; ii++) { float d = xv[ii] - mean; vv += d * d; }
        #pragma unroll
        for (int ii = 12; ii < 16; ii++) { float d = xv[ii] - mean; vv += (p < 3) ? d * d : 0.f; }
        vv += __shfl_xor(vv, 1); vv += __shfl_xor(vv, 2);
        float rs = rsqrtf(vv * (1.f / 60.f) + 1e-5f);
        float ov[16];
        #pragma unroll
        for (int ii = 0; ii < 12; ii++) ov[ii] = (xv[ii] - mean) * rs;
        #pragma unroll
        for (int ii = 12; ii < 16; ii++)
            ov[ii] = (p < 3) ? (xv[ii] - mean) * rs : ((ii == 12) ? 1.f : 0.f);
        unsigned short* xr = xln + n * 72 + cb;
        *(uint4*)xr = make_uint4(pk2rn(ov[0], ov[1]), pk2rn(ov[2], ov[3]),
                                 pk2rn(ov[4], ov[5]), pk2rn(ov[6], ov[7]));
        *(uint4*)(xr + 8) = make_uint4(pk2rn(ov[8], ov[9]), pk2rn(ov[10], ov[11]),
                                       pk2rn(ov[12], ov[13]), pk2rn(ov[14], ov[15]));
    }
    __syncthreads();  // B1

    // ---- QKV (bias in k=60 slot; q pre-scaled in weights)
    {
        bf16x8 bx[4][2];
        #pragma unroll
        for (int nt = 0; nt < 4; nt++)
            #pragma unroll
            for (int ks = 0; ks < 2; ks++)
                bx[nt][ks] = *(const bf16x8*)(xln + (nt * 16 + l15) * 72 + l4 * 8 + ks * 32);
        #pragma unroll
        for (int t = 0; t < 3; t++) {
            int ot = w * 3 + t;
            f32x4 acc[4];
            #pragma unroll
            for (int nt = 0; nt < 4; nt++) acc[nt] = zf;
            #pragma unroll
            for (int ks = 0; ks < 2; ks++) {
                bf16x8 a = *(const bf16x8*)(WpL + (ot * 2 + ks) * 512 + lane * 8);
                #pragma unroll
                for (int nt = 0; nt < 4; nt++) acc[nt] = MFMA16(a, bx[nt][ks], acc[nt]);
            }
            int o0 = ot * 16 + l4 * 4;
            #pragma unroll
            for (int nt = 0; nt < 4; nt++) {
                int n = nt * 16 + l15;
                if (o0 < 60) {
                    *(uint2*)(qn + n * 72 + o0) =
                        make_uint2(pk2rn(acc[nt][0], acc[nt][1]), pk2rn(acc[nt][2], acc[nt][3]));
                } else if (o0 < 120) {
                    *(uint2*)(kn + n * 72 + (o0 - 60)) =
                        make_uint2(pk2rn(acc[nt][0], acc[nt][1]), pk2rn(acc[nt][2], acc[nt][3]));
                } else {
                    int r = o0 - 120;
                    vt[(r + 0) * 72 + n] = bfrn(acc[nt][0]);
                    vt[(r + 1) * 72 + n] = bfrn(acc[nt][1]);
                    vt[(r + 2) * 72 + n] = bfrn(acc[nt][2]);
                    vt[(r + 3) * 72 + n] = bfrn(acc[nt][3]);
                }
            }
        }
    }
    __syncthreads();  // B2

    // ---- shift-mask bits (swapped layout: q=col=wbase+l15, j=row)
    unsigned maskbits = 0u;
    if (SHIFT) {
        int qtok = wbase + l15;
        int qr = qtok >> 3, qc = qtok & 7;
        int shp = wh * 8 + qr, swp = wc * 8 + qc;
        int qreg = (shp < 32 ? 0 : (shp < 36 ? 1 : 2)) * 3 + (swp < 32 ? 0 : (swp < 36 ? 1 : 2));
        #pragma unroll
        for (int e = 0; e < 16; e++) {
            int jt = e >> 2, r = e & 3;
            int j = jt * 16 + l4 * 4 + r;
            int jr = j >> 3, jc = j & 7;
            int shq = wh * 8 + jr, swq = wc * 8 + jc;
            int jreg = (shq < 32 ? 0 : (shq < 36 ? 1 : 2)) * 3 + (swq < 32 ? 0 : (swq < 36 ? 1 : 2));
            if (jreg != qreg) maskbits |= (1u << e);
        }
    }

    // ---- head loop (swapped QK^T; exp2; sum via MFMA(P,ones); rp from global, sw-pipelined)
    f32x4 oacc[10];
    #pragma unroll
    for (int h = 0; h < 10; h++) oacc[h] = zf;
    unsigned short* prow = Pl + (wbase + l15) * 72;
    const unsigned* rpq = rpE + ((wbase + l15) << 6) + (l4 << 2);

    u32x4 rpc[4];
    #pragma unroll
    for (int jt = 0; jt < 4; jt++) rpc[jt] = *(const u32x4*)(rpq + jt * 16);

    #pragma unroll
    for (int hp = 0; hp < 5; hp++) {
        u32x4 rpn[4];
        if (hp < 4) {
            const unsigned* rq = rpq + (hp + 1) * 4096;
            #pragma unroll
            for (int jt = 0; jt < 4; jt++) rpn[jt] = *(const u32x4*)(rq + jt * 16);
        }
        #pragma unroll
        for (int hh2 = 0; hh2 < 2; hh2++) {
            const int h = hp * 2 + hh2;
            bf16x8 bq = zb, ak0 = zb, ak1 = zb, ak2 = zb, ak3 = zb;
            if (l4 == 0) {
                const unsigned* qp = (const unsigned*)(qn + (wbase + l15) * 72 + h * 6);
                u32x4 uq = {qp[0], qp[1], qp[2], 0u};
                bq = __builtin_bit_cast(bf16x8, uq);
                const unsigned* k0p = (const unsigned*)(kn + (0 * 16 + l15) * 72 + h * 6);
                const unsigned* k1p = (const unsigned*)(kn + (1 * 16 + l15) * 72 + h * 6);
                const unsigned* k2p = (const unsigned*)(kn + (2 * 16 + l15) * 72 + h * 6);
                const unsigned* k3p = (const unsigned*)(kn + (3 * 16 + l15) * 72 + h * 6);
                u32x4 u0 = {k0p[0], k0p[1], k0p[2], 0u}; ak0 = __builtin_bit_cast(bf16x8, u0);
                u32x4 u1 = {k1p[0], k1p[1], k1p[2], 0u}; ak1 = __builtin_bit_cast(bf16x8, u1);
                u32x4 u2 = {k2p[0], k2p[1], k2p[2], 0u}; ak2 = __builtin_bit_cast(bf16x8, u2);
                u32x4 u3 = {k3p[0], k3p[1], k3p[2], 0u}; ak3 = __builtin_bit_cast(bf16x8, u3);
            }
            f32x4 s0 = MFMA16(ak0, bq, zf);   // D[j-row][q-col]
            f32x4 s1 = MFMA16(ak1, bq, zf);
            f32x4 s2 = MFMA16(ak2, bq, zf);
            f32x4 s3 = MFMA16(ak3, bq, zf);
            float ee[16];
            #pragma unroll
            for (int r = 0; r < 4; r++) {
                ee[0 + r]  = __builtin_amdgcn_exp2f(s0[r] + bfsel(rpc[0][r], hh2));
                ee[4 + r]  = __builtin_amdgcn_exp2f(s1[r] + bfsel(rpc[1][r], hh2));
                ee[8 + r]  = __builtin_amdgcn_exp2f(s2[r] + bfsel(rpc[2][r], hh2));
                ee[12 + r] = __builtin_amdgcn_exp2f(s3[r] + bfsel(rpc[3][r], hh2));
            }
            if (SHIFT) {
                #pragma unroll
                for (int e = 0; e < 16; e++)
                    if (maskbits & (1u << e)) ee[e] = 0.f;
            }
            #pragma unroll
            for (int jt = 0; jt < 4; jt++)
                *(uint2*)(prow + jt * 16 + l4 * 4) =
                    make_uint2(pk2rn(ee[jt * 4 + 0], ee[jt * 4 + 1]),
                               pk2rn(ee[jt * 4 + 2], ee[jt * 4 + 3]));
            asm volatile("s_waitcnt lgkmcnt(0)" ::: "memory");
            bf16x8 ap0 = *(const bf16x8*)(prow + l4 * 8);
            bf16x8 ap1 = *(const bf16x8*)(prow + 32 + l4 * 8);
            bf16x8 bv0 = *(const bf16x8*)(vt + (h * 6 + l15) * 72 + l4 * 8);
            bf16x8 bv1 = *(const bf16x8*)(vt + (h * 6 + l15) * 72 + 32 + l4 * 8);
            f32x4 sm = MFMA16(ap0, ones, zf);
            sm = MFMA16(ap1, ones, sm);
            f32x4 pv = MFMA16(ap0, bv0, zf);
            pv = MFMA16(ap1, bv1, pv);
            #pragma unroll
            for (int r = 0; r < 4; r++)
                oacc[h][r] = pv[r] * __builtin_amdgcn_rcpf(sm[r]);
        }
        #pragma unroll
        for (int jt = 0; jt < 4; jt++) rpc[jt] = rpn[jt];
    }

    // ---- attention out -> olds (=qn slab); col60=1 bias slot, 61-63 zero
    unsigned short* olds = qn;
    if (l15 < 6) {
        #pragma unroll
        for (int h = 0; h < 10; h++)
            #pragma unroll
            for (int j = 0; j < 4; j++)
                olds[(wbase + l4 * 4 + j) * 72 + h * 6 + l15] = bfrn(oacc[h][j]);
    } else if (l15 < 10) {
        unsigned short pv16 = (l15 == 6) ? (unsigned short)0x3F80 : (unsigned short)0;
        #pragma unroll
        for (int j = 0; j < 4; j++)
            olds[(wbase + l4 * 4 + j) * 72 + 60 + (l15 - 6)] = pv16;
    }
    __syncthreads();  // B2.5: Pl/vt/kn dead -> x1t & ln2 overlays safe

    // ---- proj + residual -> x1t (fp32)
    {
        bf16x8 bo0 = *(const bf16x8*)(olds + (wbase + l15) * 72 + l4 * 8);
        bf16x8 bo1 = *(const bf16x8*)(olds + (wbase + l15) * 72 + 32 + l4 * 8);
        f32x4 acc[4];
        #pragma unroll
        for (int ot = 0; ot < 4; ot++) acc[ot] = zf;
        #pragma unroll
        for (int ot = 0; ot < 4; ot++) {
            bf16x8 a0 = *(const bf16x8*)(WpL + 12288 + (ot * 2 + 0) * 512 + lane * 8);
            bf16x8 a1 = *(const bf16x8*)(WpL + 12288 + (ot * 2 + 1) * 512 + lane * 8);
            acc[ot] = MFMA16(a0, bo0, acc[ot]);
            acc[ot] = MFMA16(a1, bo1, acc[ot]);
        }
        int n = wbase + l15;
        int g = gidx(n, wh, wc, SHIFT);
        #pragma unroll
        for (int ot = 0; ot < 4; ot++) {
            int o0 = ot * 16 + l4 * 4;
            if (o0 < 60) {
                float4 xr = *(const float4*)(Sb + (size_t)g * 60 + o0);
                x1t[(o0 + 0) * 65 + n] = xr.x + acc[ot][0];
                x1t[(o0 + 1) * 65 + n] = xr.y + acc[ot][1];
                x1t[(o0 + 2) * 65 + n] = xr.z + acc[ot][2];
                x1t[(o0 + 3) * 65 + n] = xr.w + acc[ot][3];
            }
        }
    }
    asm volatile("s_waitcnt lgkmcnt(0)" ::: "memory");

    // ---- LN2 -> ln2 (pure normalize; col60=1)
    {
        int n = wbase + (lane >> 2), p = lane & 3, cb = p * 16;
        float xv[16];
        #pragma unroll
        for (int ii = 0; ii < 12; ii++) xv[ii] = x1t[(cb + ii) * 65 + n];
        #pragma unroll
        for (int ii = 12; ii < 16; ii++) xv[ii] = (p < 3) ? x1t[(cb + ii) * 65 + n] : 0.f;
        float s = 0.f;
        #pragma unroll
        for (int ii = 0; ii < 16; ii++) s += xv[ii];
        s += __shfl_xor(s, 1); s += __shfl_xor(s, 2);
        float mean = s * (1.f / 60.f);
        float vv = 0.f;
        #pragma unroll
        for (int ii = 0; ii < 12; ii++) { float d = xv[ii] - mean; vv += d * d; }
        #pragma unroll
        for (int ii = 12; ii < 16; ii++) { float d = xv[ii] - mean; vv += (p < 3) ? d * d : 0.f; }
        vv += __shfl_xor(vv, 1); vv += __shfl_xor(vv, 2);
        float rs = rsqrtf(vv * (1.f / 60.f) + 1e-5f);
        float ov[16];
        #pragma unroll
        for (int ii = 0; ii < 12; ii++) ov[ii] = (xv[ii] - mean) * rs;
        #pragma unroll
        for (int ii = 12; ii < 16; ii++)
            ov[ii] = (p < 3) ? (xv[ii] - mean) * rs : ((ii == 12) ? 1.f : 0.f);
        unsigned short* lr = ln2 + n * 72 + cb;
        *(uint4*)lr = make_uint4(pk2rn(ov[0], ov[1]), pk2rn(ov[2], ov[3]),
                                 pk2rn(ov[4], ov[5]), pk2rn(ov[6], ov[7]));
        *(uint4*)(lr + 8) = make_uint4(pk2rn(ov[8], ov[9]), pk2rn(ov[10], ov[11]),
                                       pk2rn(ov[12], ov[13]), pk2rn(ov[14], ov[15]));
    }
    __syncthreads();  // B3

    // ---- MLP: fc1+gelu (2 output-halves) -> h1; fc2 accumulates (bias via h1 col120=1)
    f32x4 acc2[4];
    #pragma unroll
    for (int ot = 0; ot < 4; ot++) acc2[ot] = zf;

    #pragma unroll
    for (int ph = 0; ph < 2; ph++) {
        {
            bf16x8 bl[4][2];
            #pragma unroll
            for (int nt = 0; nt < 4; nt++)
                #pragma unroll
                for (int ks = 0; ks < 2; ks++)
                    bl[nt][ks] = *(const bf16x8*)(ln2 + (nt * 16 + l15) * 72 + l4 * 8 + ks * 32);
            #pragma unroll
            for (int t = 0; t < 2; t++) {
                int ot = w + t * 4;
                f32x4 a1[4];
                #pragma unroll
                for (int nt = 0; nt < 4; nt++) a1[nt] = zf;
                #pragma unroll
                for (int ks = 0; ks < 2; ks++) {
                    bf16x8 a = *(const bf16x8*)(WpL + 16384 + ((ph * 8 + ot) * 2 + ks) * 512 + lane * 8);
                    #pragma unroll
                    for (int nt = 0; nt < 4; nt++) a1[nt] = MFMA16(a, bl[nt][ks], a1[nt]);
                }
                int o0 = ot * 16 + l4 * 4;
                if (o0 < 120) {
                    #pragma unroll
                    for (int nt = 0; nt < 4; nt++) {
                        int n = nt * 16 + l15;
                        *(uint2*)(h1 + n * 136 + o0) =
                            make_uint2(pk2rn(gelu_f(a1[nt][0]), gelu_f(a1[nt][1])),
                                       pk2rn(gelu_f(a1[nt][2]), gelu_f(a1[nt][3])));
                    }
                }
            }
            if (ph == 0 && tid < 64)
                *(uint4*)(h1 + tid * 136 + 120) = make_uint4(0x3F80u, 0u, 0u, 0u);
        }
        __syncthreads();
        {
            bf16x8 bh[4];
            #pragma unroll
            for (int ks = 0; ks < 4; ks++)
                bh[ks] = *(const bf16x8*)(h1 + (wbase + l15) * 136 + l4 * 8 + ks * 32);
            #pragma unroll
            for (int ot = 0; ot < 4; ot++)
                #pragma unroll
                for (int ks = 0; ks < 4; ks++) {
                    bf16x8 a = *(const bf16x8*)(WpL + 32768 + ((ph * 4 + ot) * 4 + ks) * 512 + lane * 8);
                    acc2[ot] = MFMA16(a, bh[ks], acc2[ot]);
                }
        }
        if (ph == 0) __syncthreads();
    }

    // ---- final: S[g] = x1 + fc2out
    {
        int n = wbase + l15;
        int g = gidx(n, wh, wc, SHIFT);
        #pragma unroll
        for (int ot = 0; ot < 4; ot++) {
            int o0 = ot * 16 + l4 * 4;
            if (o0 < 60) {
                float4 r;
                r.x = x1t[(o0 + 0) * 65 + n] + acc2[ot][0];
                r.y = x1t[(o0 + 1) * 65 + n] + acc2[ot][1];
                r.z = x1t[(o0 + 2) * 65 + n] + acc2[ot][2];
                r.w = x1t[(o0 + 3) * 65 + n] + acc2[ot][3];
                *(float4*)(Sb + (size_t)g * 60 + o0) = r;
            }
        }
    }
}

// ---------------------------------------------------------------- conv_out
__global__ __launch_bounds__(256) void conv_out_k(
    const float* __restrict__ S, const float* __restrict__ w,
    const float* __restrict__ bias, float* __restrict__ out)
{
    __shared__ float Sr[3][40][60];
    __shared__ float wts[3 * 60 * 9];
    __shared__ float part[2][120];
    int b = blockIdx.x / 40, y = blockIdx.x % 40;
    int tid = threadIdx.x;
    for (int idx = tid; idx < 3 * 40 * 60; idx += 256) {
        int ky = idx / 2400; int n = (idx / 60) % 40; int c = idx % 60;
        int yy = y + ky - 1;
        Sr[ky][n][c] = (yy >= 0 && yy < 40) ? S[((size_t)b * 1600 + yy * 40 + n) * 60 + c] : 0.f;
    }
    for (int idx = tid; idx < 3 * 60 * 9; idx += 256) wts[idx] = w[idx];
    __syncthreads();
    if (tid < 240) {
        int p = tid % 120, half = tid / 120;
        int x = p % 40, co = p / 40;
        float acc = 0.f;
        int c0 = half * 30;
        for (int c = c0; c < c0 + 30; c++) {
            #pragma unroll
            for (int ky = 0; ky < 3; ky++) {
                const float* wr = &wts[(co * 60 + c) * 9 + ky * 3];
                float s0 = (x >= 1) ? Sr[ky][x - 1][c] : 0.f;
                float s1 = Sr[ky][x][c];
                float s2 = (x <= 38) ? Sr[ky][x + 1][c] : 0.f;
                acc += wr[0] * s0 + wr[1] * s1 + wr[2] * s2;
            }
        }
        part[half][p] = acc;
    }
    __syncthreads();
    if (tid < 120) {
        int x = tid % 40, co = tid / 40;
        out[((size_t)b * 3 + co) * 1600 + y * 40 + x] = part[0][tid] + part[1][tid] + bias[co];
    }
}

// ---------------------------------------------------------------- launch
extern "C" void kernel_launch(void* const* d_in, const int* in_sizes, int n_in,
                              void* d_out, int out_size, void* d_ws, size_t ws_size,
                              hipStream_t stream)
{
    const float* x   = (const float*)d_in[0];
    const float* ciw = (const float*)d_in[1];
    const float* cib = (const float*)d_in[2];
    const float* n1g = (const float*)d_in[3];
    const float* n1b = (const float*)d_in[4];
    const float* qw  = (const float*)d_in[5];
    const float* qb  = (const float*)d_in[6];
    const float* rpb = (const float*)d_in[7];
    const float* pw  = (const float*)d_in[8];
    const float* pb  = (const float*)d_in[9];
    const float* n2g = (const float*)d_in[10];
    const float* n2b = (const float*)d_in[11];
    const float* f1w = (const float*)d_in[12];
    const float* f1b = (const float*)d_in[13];
    const float* f2w = (const float*)d_in[14];
    const float* f2b = (const float*)d_in[15];
    const float* cow = (const float*)d_in[16];
    const float* cob = (const float*)d_in[17];
    float* out = (float*)d_out;
    float* S = (float*)d_ws;                                        // 49,152,000 B
    unsigned short* Wp = (unsigned short*)((char*)d_ws + 49152000); // 393,216 B packed weights
    unsigned* rpbE = (unsigned*)((char*)d_ws + 49545216);           // 327,680 B expanded rpb

    prep_k<<<96, 256, 0, stream>>>(qw, pw, f1w, f2w, qb, pb, f1b, f2b,
                                   n1g, n1b, n2g, n2b, Wp);
    rpbexp_k<<<20, 256, 0, stream>>>(rpb, rpbE);
    conv_in_k<<<128 * 10, 256, 0, stream>>>(x, ciw, cib, S);
    for (int i = 0; i < 4; i++) {
        const unsigned short* WpL = Wp + i * 49152;
        const unsigned* rpEL = rpbE + i * 5 * 4096;
        if (i & 1) block_k<4><<<128 * 25, 256, 0, stream>>>(S, WpL, rpEL);
        else       block_k<0><<<128 * 25, 256, 0, stream>>>(S, WpL, rpEL);
    }
    conv_out_k<<<128 * 40, 256, 0, stream>>>(S, cow, cob, out);
}

// Round 7
// 512.550 us; speedup vs baseline: 4.6863x; 1.1558x over previous
//
#include <hip/hip_runtime.h>
#include <math.h>

// B=128, H=W=40, C=60, L=1600, NH=10, HD=6, WS=8, N=64, NW=25, NB=4

typedef __bf16 bf16x8 __attribute__((ext_vector_type(8)));
typedef float f32x4 __attribute__((ext_vector_type(4)));
typedef unsigned int u32x4 __attribute__((ext_vector_type(4)));
typedef float f4u __attribute__((ext_vector_type(4), aligned(4)));

#define MFMA16(a, b, c) __builtin_amdgcn_mfma_f32_16x16x32_bf16(a, b, c, 0, 0, 0)

__device__ __forceinline__ unsigned short f2bf(float x) {  // RNE (prep only)
    unsigned u = __float_as_uint(x);
    return (unsigned short)((u + 0x7fffu + ((u >> 16) & 1u)) >> 16);
}
__device__ __forceinline__ unsigned short bfrn(float x) {  // 2 ops
    return (unsigned short)((__float_as_uint(x) + 0x8000u) >> 16);
}
__device__ __forceinline__ unsigned pk2rn(float a, float b) {  // 1 op: lo=bf16(a), hi=bf16(b)
    unsigned r;
    asm("v_cvt_pk_bf16_f32 %0, %1, %2" : "=v"(r) : "v"(a), "v"(b));
    return r;
}
__device__ __forceinline__ float bfsel(unsigned u, int hi) {
    return __uint_as_float(hi ? (u & 0xffff0000u) : (u << 16));
}
__device__ __forceinline__ float gelu_f(float v) {
    float t2 = v * v;
    float e = __builtin_amdgcn_exp2f(v * fmaf(0.102943225f, t2, 2.302207877f));
    float r = __builtin_amdgcn_rcpf(e + 1.f);
    return fmaf(-v, r, v);
}
__device__ __forceinline__ int gidx(int n, int wh, int wc, int shift) {
    int hh = wh * 8 + (n >> 3) + shift; if (hh >= 40) hh -= 40;
    int ww = wc * 8 + (n & 7) + shift;  if (ww >= 40) ww -= 40;
    return hh * 40 + ww;
}

// ---------------------------------------------------------------- weight pre-pack (blocks)
__global__ __launch_bounds__(256) void prep_k(
    const float* __restrict__ qkvw, const float* __restrict__ pw,
    const float* __restrict__ f1w, const float* __restrict__ f2w,
    const float* __restrict__ qkvb, const float* __restrict__ pb,
    const float* __restrict__ f1b, const float* __restrict__ f2b,
    const float* __restrict__ g1v, const float* __restrict__ b1v,
    const float* __restrict__ g2v, const float* __restrict__ b2v,
    unsigned short* __restrict__ Wp)
{
    int t = blockIdx.x * 256 + threadIdx.x;  // 0..24575
    int lane = t & 63;
    int q6 = t >> 6;
    int layer = q6 / 96, tile = q6 % 96;
    int l15 = lane & 15, l4 = lane >> 4;
    const float* src; const float* gam = 0; const float* bet = 0;
    float bias = 0.f, rowscale = 1.f;
    int row, stride, rmax, kmax, k0;
    unsigned short* dst = Wp + layer * 49152;
    if (tile < 24) {
        int ot = tile >> 1, ks = tile & 1;
        src = qkvw + layer * 10800; row = ot * 16 + l15; k0 = ks * 32 + l4 * 8;
        rmax = 180; kmax = 60; stride = 60; dst += tile * 512;
        gam = g1v + layer * 60; bet = b1v + layer * 60;
        if (row < 180) bias = qkvb[layer * 180 + row];
        if (row < 60) rowscale = 0.58897780f;  // 6^-0.5 * log2(e)
    } else if (tile < 32) {
        int tt = tile - 24;
        src = pw + layer * 3600; row = (tt >> 1) * 16 + l15; k0 = (tt & 1) * 32 + l4 * 8;
        rmax = 60; kmax = 60; stride = 60; dst += 12288 + tt * 512;
        if (row < 60) bias = pb[layer * 60 + row];
    } else if (tile < 64) {
        int tt = tile - 32; int ks = tt & 1; int po = tt >> 1; int ot = po & 7; int ph = po >> 3;
        src = f1w + layer * 14400 + ph * 7200; row = ot * 16 + l15; k0 = ks * 32 + l4 * 8;
        rmax = 120; kmax = 60; stride = 60; dst += 16384 + tt * 512;
        gam = g2v + layer * 60; bet = b2v + layer * 60;
        if (row < 120) bias = f1b[layer * 240 + ph * 120 + row];
    } else {
        int tt = tile - 64; int ks = tt & 3; int po = tt >> 2; int ot = po & 3; int ph = po >> 2;
        src = f2w + layer * 14400 + ph * 120; row = ot * 16 + l15; k0 = ks * 32 + l4 * 8;
        rmax = 60; kmax = 120; stride = 240; dst += 32768 + tt * 512;
        if (ph == 0 && row < 60) bias = f2b[layer * 60 + row];
    }
    unsigned short v[8];
    #pragma unroll
    for (int i = 0; i < 8; i++) {
        int k = k0 + i;
        float f = 0.f;
        if (row < rmax) {
            if (k < kmax) {
                f = src[row * stride + k];
                if (gam) f *= gam[k];
            } else if (k == kmax) {
                f = bias;
                if (bet) for (int kk = 0; kk < kmax; kk++) f += src[row * stride + kk] * bet[kk];
            }
        }
        v[i] = f2bf(f * rowscale);
    }
    unsigned a0 = (unsigned)v[0] | ((unsigned)v[1] << 16);
    unsigned a1 = (unsigned)v[2] | ((unsigned)v[3] << 16);
    unsigned a2 = (unsigned)v[4] | ((unsigned)v[5] << 16);
    unsigned a3 = (unsigned)v[6] | ((unsigned)v[7] << 16);
    *(uint4*)(dst + lane * 8) = make_uint4(a0, a1, a2, a3);
}

// ---------------------------------------------------------------- conv_in weight pre-pack
// A-frag tiles (mt 0..3, g 0..8): row=c_out(mt*16+l15), k=g*32 + ci(l4*8+i); ci>=18 zero.
__global__ __launch_bounds__(256) void prepc_k(
    const float* __restrict__ ciw, unsigned short* __restrict__ Wc)
{
    int t = blockIdx.x * 256 + threadIdx.x;  // 0..2303
    if (t >= 2304) return;
    int lane = t & 63, tile = t >> 6;        // tile 0..35
    int mt = tile / 9, g = tile % 9;
    int ky = g / 3, kx = g % 3;
    int row = mt * 16 + (lane & 15);
    int ci0 = (lane >> 4) * 8;
    unsigned short v[8];
    #pragma unroll
    for (int i = 0; i < 8; i++) {
        int ci = ci0 + i;
        float f = (row < 60 && ci < 18) ? ciw[(row * 18 + ci) * 9 + ky * 3 + kx] : 0.f;
        v[i] = f2bf(f);
    }
    unsigned a0 = (unsigned)v[0] | ((unsigned)v[1] << 16);
    unsigned a1 = (unsigned)v[2] | ((unsigned)v[3] << 16);
    unsigned a2 = (unsigned)v[4] | ((unsigned)v[5] << 16);
    unsigned a3 = (unsigned)v[6] | ((unsigned)v[7] << 16);
    *(uint4*)(Wc + tile * 512 + lane * 8) = make_uint4(a0, a1, a2, a3);
}

// ---------------------------------------------------------------- rpb pre-expansion
__global__ __launch_bounds__(256) void rpbexp_k(
    const float* __restrict__ rpb, unsigned* __restrict__ rpbE)
{
    int layer = blockIdx.x / 5, hp = blockIdx.x % 5;
    int tid = threadIdx.x;
    int q = tid >> 2, j0 = (tid & 3) * 16;
    const float* rsrc = rpb + layer * 2250 + hp * 2;
    unsigned* dst = rpbE + ((layer * 5 + hp) * 64 + q) * 64 + j0;
    int qr = q >> 3, qc = q & 7;
    #pragma unroll
    for (int jj = 0; jj < 16; jj++) {
        int j = j0 + jj;
        int jr = j >> 3, jc = j & 7;
        int ridx = ((qr - jr + 7) * 15 + (qc - jc + 7)) * 10;
        unsigned short lo = f2bf(rsrc[ridx] * 1.4426950409f);
        unsigned short hi = f2bf(rsrc[ridx + 1] * 1.4426950409f);
        dst[jj] = (unsigned)lo | ((unsigned)hi << 16);
    }
}

// ---------------------------------------------------------------- conv_in (implicit-GEMM MFMA)
// block = (image, 8-row band); LDS tile [10 ry][42 x][32 ci] bf16, XOR-swizzled slots.
__global__ __launch_bounds__(256) void conv_in_k(
    const float* __restrict__ x, const unsigned short* __restrict__ Wc,
    const float* __restrict__ bias, float* __restrict__ S)
{
    __shared__ __align__(16) unsigned short xt[10 * 42 * 32];  // 26880 B
    int b = blockIdx.x / 5, y0 = (blockIdx.x % 5) * 8;
    int tid = threadIdx.x;
    int lane = tid & 63, w = tid >> 6;
    int l15 = lane & 15, l4 = lane >> 4;

    uint4* xt4 = (uint4*)xt;
    for (int i = tid; i < 1680; i += 256) xt4[i] = make_uint4(0u, 0u, 0u, 0u);
    __syncthreads();

    const float* xb = x + (size_t)b * 28800;
    for (int idx = tid; idx < 10 * 18 * 40; idx += 256) {
        int xx = idx % 40;
        int rem = idx / 40;
        int ci = rem % 18;
        int ry = rem / 18;
        int yy = y0 + ry - 1;
        if (yy >= 0 && yy < 40) {
            float v = xb[ci * 1600 + yy * 40 + xx];
            int xs = xx + 1;
            int bo = (((ry * 42 + xs) * 32 + ci) * 2) ^ ((xs & 3) << 4);
            *(unsigned short*)((char*)xt + bo) = bfrn(v);
        }
    }
    __syncthreads();

    // A-frags for this wave's output-channel tile (mt = w)
    bf16x8 afr[9];
    #pragma unroll
    for (int g = 0; g < 9; g++)
        afr[g] = *(const bf16x8*)(Wc + (w * 9 + g) * 512 + lane * 8);

    int c0 = w * 16 + l4 * 4;
    bool valid = (c0 < 60);
    f4u bv = {0.f, 0.f, 0.f, 0.f};
    if (valid) bv = *(const f4u*)(bias + c0);
    const f32x4 zf = {0.f, 0.f, 0.f, 0.f};
    const char* xtb = (const char*)xt;

    for (int nt = 0; nt < 20; nt++) {
        int tok = nt * 16 + l15;
        int yl = tok / 40, xl = tok % 40;
        f32x4 acc = zf;
        #pragma unroll
        for (int g = 0; g < 9; g++) {
            int ky = g / 3, kx = g % 3;
            int xs = xl + kx;
            int ba = ((yl + ky) * 42 + xs) * 64 + ((l4 ^ (xs & 3)) << 4);
            bf16x8 bfrag = *(const bf16x8*)(xtb + ba);
            acc = MFMA16(afr[g], bfrag, acc);
        }
        if (valid) {
            float4 r;
            r.x = acc[0] + bv[0]; r.y = acc[1] + bv[1];
            r.z = acc[2] + bv[2]; r.w = acc[3] + bv[3];
            *(float4*)(S + ((size_t)b * 1600 + y0 * 40 + tok) * 60 + c0) = r;
        }
    }
}

// ---------------------------------------------------------------- fused Swin block
template<int SHIFT>
__global__ __launch_bounds__(256, 3) void block_k(
    float* __restrict__ S,
    const unsigned short* __restrict__ WpL,
    const unsigned* __restrict__ rpE)
{
    __shared__ __align__(16) unsigned char LDSA[53616];
    unsigned short* Pl  = (unsigned short*)(LDSA + 4608);
    float*          x1t = (float*)(LDSA + 0);
    unsigned short* xln = (unsigned short*)(LDSA + 15600);
    unsigned short* h1  = (unsigned short*)(LDSA + 15600);
    unsigned short* qn  = (unsigned short*)(LDSA + 24816);
    unsigned short* kn  = (unsigned short*)(LDSA + 34032);
    unsigned short* vt  = (unsigned short*)(LDSA + 43248);
    unsigned short* ln2 = (unsigned short*)(LDSA + 43248);

    const int tid = threadIdx.x;
    const int lane = tid & 63, w = tid >> 6;
    const int l15 = lane & 15, l4 = lane >> 4;
    const int wbase = w * 16;
    const int b = blockIdx.x / 25, wnd = blockIdx.x % 25;
    const int wh = wnd / 5, wc = wnd % 5;
    float* Sb = S + (size_t)b * 96000;
    const f32x4 zf = {0.f, 0.f, 0.f, 0.f};
    u32x4 zu = {0u, 0u, 0u, 0u};
    const bf16x8 zb = __builtin_bit_cast(bf16x8, zu);
    u32x4 ou = {0x3F803F80u, 0x3F803F80u, 0x3F803F80u, 0x3F803F80u};
    const bf16x8 ones = __builtin_bit_cast(bf16x8, ou);

    // ---- LN1 (pure normalize; col60=1 bias slot) -> xln
    {
        int n = tid >> 2, p = tid & 3, cb = p * 16;
        int g = gidx(n, wh, wc, SHIFT);
        const float* xp = Sb + (size_t)g * 60 + cb;
        float xv[16];
        {
            float4 v0 = *(const float4*)xp;
            float4 v1 = *(const float4*)(xp + 4);
            float4 v2 = *(const float4*)(xp + 8);
            xv[0] = v0.x; xv[1] = v0.y; xv[2] = v0.z; xv[3] = v0.w;
            xv[4] = v1.x; xv[5] = v1.y; xv[6] = v1.z; xv[7] = v1.w;
            xv[8] = v2.x; xv[9] = v2.y; xv[10] = v2.z; xv[11] = v2.w;
            if (p < 3) {
                float4 v3 = *(const float4*)(xp + 12);
                xv[12] = v3.x; xv[13] = v3.y; xv[14] = v3.z; xv[15] = v3.w;
            } else { xv[12] = xv[13] = xv[14] = xv[15] = 0.f; }
        }
        float s = 0.f;
        #pragma unroll
        for (int ii = 0; ii < 16; ii++) s += xv[ii];
        s += __shfl_xor(s, 1); s += __shfl_xor(s, 2);
        float mean = s * (1.f / 60.f);
        float vv = 0.f;
        #pragma unroll
        for (int ii = 0; ii < 12; ii++) { float d = xv[ii] - mean; vv += d * d; }
        #pragma unroll
        for (int ii = 12; ii < 16; ii++) { float d = xv[ii] - mean; vv += (p < 3) ? d * d : 0.f; }
        vv += __shfl_xor(vv, 1); vv += __shfl_xor(vv, 2);
        float rs = rsqrtf(vv * (1.f / 60.f) + 1e-5f);
        float ov[16];
        #pragma unroll
        for (int ii = 0; ii < 12; ii++) ov[ii] = (xv[ii] - mean) * rs;
        #pragma unroll
        for (int ii = 12; ii < 16; ii++)
            ov[ii] = (p < 3) ? (xv[ii] - mean) * rs : ((ii == 12) ? 1.f : 0.f);
        unsigned short* xr = xln + n * 72 + cb;
        *(uint4*)xr = make_uint4(pk2rn(ov[0], ov[1]), pk2rn(ov[2], ov[3]),
                                 pk2rn(ov[4], ov[5]), pk2rn(ov[6], ov[7]));
        *(uint4*)(xr + 8) = make_uint4(pk2rn(ov[8], ov[9]), pk2rn(ov[10], ov[11]),
                                       pk2rn(ov[12], ov[13]), pk2rn(ov[14], ov[15]));
    }
    __syncthreads();  // B1

    // ---- QKV
    {
        bf16x8 bx[4][2];
        #pragma unroll
        for (int nt = 0; nt < 4; nt++)
            #pragma unroll
            for (int ks = 0; ks < 2; ks++)
                bx[nt][ks] = *(const bf16x8*)(xln + (nt * 16 + l15) * 72 + l4 * 8 + ks * 32);
        #pragma unroll
        for (int t = 0; t < 3; t++) {
            int ot = w * 3 + t;
            f32x4 acc[4];
            #pragma unroll
            for (int nt = 0; nt < 4; nt++) acc[nt] = zf;
            #pragma unroll
            for (int ks = 0; ks < 2; ks++) {
                bf16x8 a = *(const bf16x8*)(WpL + (ot * 2 + ks) * 512 + lane * 8);
                #pragma unroll
                for (int nt = 0; nt < 4; nt++) acc[nt] = MFMA16(a, bx[nt][ks], acc[nt]);
            }
            int o0 = ot * 16 + l4 * 4;
            #pragma unroll
            for (int nt = 0; nt < 4; nt++) {
                int n = nt * 16 + l15;
                if (o0 < 60) {
                    *(uint2*)(qn + n * 72 + o0) =
                        make_uint2(pk2rn(acc[nt][0], acc[nt][1]), pk2rn(acc[nt][2], acc[nt][3]));
                } else if (o0 < 120) {
                    *(uint2*)(kn + n * 72 + (o0 - 60)) =
                        make_uint2(pk2rn(acc[nt][0], acc[nt][1]), pk2rn(acc[nt][2], acc[nt][3]));
                } else {
                    int r = o0 - 120;
                    vt[(r + 0) * 72 + n] = bfrn(acc[nt][0]);
                    vt[(r + 1) * 72 + n] = bfrn(acc[nt][1]);
                    vt[(r + 2) * 72 + n] = bfrn(acc[nt][2]);
                    vt[(r + 3) * 72 + n] = bfrn(acc[nt][3]);
                }
            }
        }
    }
    __syncthreads();  // B2

    // ---- shift-mask bits
    unsigned maskbits = 0u;
    if (SHIFT) {
        int qtok = wbase + l15;
        int qr = qtok >> 3, qc = qtok & 7;
        int shp = wh * 8 + qr, swp = wc * 8 + qc;
        int qreg = (shp < 32 ? 0 : (shp < 36 ? 1 : 2)) * 3 + (swp < 32 ? 0 : (swp < 36 ? 1 : 2));
        #pragma unroll
        for (int e = 0; e < 16; e++) {
            int jt = e >> 2, r = e & 3;
            int j = jt * 16 + l4 * 4 + r;
            int jr = j >> 3, jc = j & 7;
            int shq = wh * 8 + jr, swq = wc * 8 + jc;
            int jreg = (shq < 32 ? 0 : (shq < 36 ? 1 : 2)) * 3 + (swq < 32 ? 0 : (swq < 36 ? 1 : 2));
            if (jreg != qreg) maskbits |= (1u << e);
        }
    }

    // ---- head loop
    f32x4 oacc[10];
    #pragma unroll
    for (int h = 0; h < 10; h++) oacc[h] = zf;
    unsigned short* prow = Pl + (wbase + l15) * 72;
    const unsigned* rpq = rpE + ((wbase + l15) << 6) + (l4 << 2);

    u32x4 rpc[4];
    #pragma unroll
    for (int jt = 0; jt < 4; jt++) rpc[jt] = *(const u32x4*)(rpq + jt * 16);

    #pragma unroll
    for (int hp = 0; hp < 5; hp++) {
        u32x4 rpn[4];
        if (hp < 4) {
            const unsigned* rq = rpq + (hp + 1) * 4096;
            #pragma unroll
            for (int jt = 0; jt < 4; jt++) rpn[jt] = *(const u32x4*)(rq + jt * 16);
        }
        #pragma unroll
        for (int hh2 = 0; hh2 < 2; hh2++) {
            const int h = hp * 2 + hh2;
            bf16x8 bq = zb, ak0 = zb, ak1 = zb, ak2 = zb, ak3 = zb;
            if (l4 == 0) {
                const unsigned* qp = (const unsigned*)(qn + (wbase + l15) * 72 + h * 6);
                u32x4 uq = {qp[0], qp[1], qp[2], 0u};
                bq = __builtin_bit_cast(bf16x8, uq);
                const unsigned* k0p = (const unsigned*)(kn + (0 * 16 + l15) * 72 + h * 6);
                const unsigned* k1p = (const unsigned*)(kn + (1 * 16 + l15) * 72 + h * 6);
                const unsigned* k2p = (const unsigned*)(kn + (2 * 16 + l15) * 72 + h * 6);
                const unsigned* k3p = (const unsigned*)(kn + (3 * 16 + l15) * 72 + h * 6);
                u32x4 u0 = {k0p[0], k0p[1], k0p[2], 0u}; ak0 = __builtin_bit_cast(bf16x8, u0);
                u32x4 u1 = {k1p[0], k1p[1], k1p[2], 0u}; ak1 = __builtin_bit_cast(bf16x8, u1);
                u32x4 u2 = {k2p[0], k2p[1], k2p[2], 0u}; ak2 = __builtin_bit_cast(bf16x8, u2);
                u32x4 u3 = {k3p[0], k3p[1], k3p[2], 0u}; ak3 = __builtin_bit_cast(bf16x8, u3);
            }
            f32x4 s0 = MFMA16(ak0, bq, zf);
            f32x4 s1 = MFMA16(ak1, bq, zf);
            f32x4 s2 = MFMA16(ak2, bq, zf);
            f32x4 s3 = MFMA16(ak3, bq, zf);
            float ee[16];
            #pragma unroll
            for (int r = 0; r < 4; r++) {
                ee[0 + r]  = __builtin_amdgcn_exp2f(s0[r] + bfsel(rpc[0][r], hh2));
                ee[4 + r]  = __builtin_amdgcn_exp2f(s1[r] + bfsel(rpc[1][r], hh2));
                ee[8 + r]  = __builtin_amdgcn_exp2f(s2[r] + bfsel(rpc[2][r], hh2));
                ee[12 + r] = __builtin_amdgcn_exp2f(s3[r] + bfsel(rpc[3][r], hh2));
            }
            if (SHIFT) {
                #pragma unroll
                for (int e = 0; e < 16; e++)
                    if (maskbits & (1u << e)) ee[e] = 0.f;
            }
            #pragma unroll
            for (int jt = 0; jt < 4; jt++)
                *(uint2*)(prow + jt * 16 + l4 * 4) =
                    make_uint2(pk2rn(ee[jt * 4 + 0], ee[jt * 4 + 1]),
                               pk2rn(ee[jt * 4 + 2], ee[jt * 4 + 3]));
            asm volatile("s_waitcnt lgkmcnt(0)" ::: "memory");
            bf16x8 ap0 = *(const bf16x8*)(prow + l4 * 8);
            bf16x8 ap1 = *(const bf16x8*)(prow + 32 + l4 * 8);
            bf16x8 bv0 = *(const bf16x8*)(vt + (h * 6 + l15) * 72 + l4 * 8);
            bf16x8 bv1 = *(const bf16x8*)(vt + (h * 6 + l15) * 72 + 32 + l4 * 8);
            f32x4 sm = MFMA16(ap0, ones, zf);
            sm = MFMA16(ap1, ones, sm);
            f32x4 pv = MFMA16(ap0, bv0, zf);
            pv = MFMA16(ap1, bv1, pv);
            #pragma unroll
            for (int r = 0; r < 4; r++)
                oacc[h][r] = pv[r] * __builtin_amdgcn_rcpf(sm[r]);
        }
        #pragma unroll
        for (int jt = 0; jt < 4; jt++) rpc[jt] = rpn[jt];
    }

    // ---- attention out -> olds (=qn slab)
    unsigned short* olds = qn;
    if (l15 < 6) {
        #pragma unroll
        for (int h = 0; h < 10; h++)
            #pragma unroll
            for (int j = 0; j < 4; j++)
                olds[(wbase + l4 * 4 + j) * 72 + h * 6 + l15] = bfrn(oacc[h][j]);
    } else if (l15 < 10) {
        unsigned short pv16 = (l15 == 6) ? (unsigned short)0x3F80 : (unsigned short)0;
        #pragma unroll
        for (int j = 0; j < 4; j++)
            olds[(wbase + l4 * 4 + j) * 72 + 60 + (l15 - 6)] = pv16;
    }
    __syncthreads();  // B2.5

    // ---- proj + residual -> x1t
    {
        bf16x8 bo0 = *(const bf16x8*)(olds + (wbase + l15) * 72 + l4 * 8);
        bf16x8 bo1 = *(const bf16x8*)(olds + (wbase + l15) * 72 + 32 + l4 * 8);
        f32x4 acc[4];
        #pragma unroll
        for (int ot = 0; ot < 4; ot++) acc[ot] = zf;
        #pragma unroll
        for (int ot = 0; ot < 4; ot++) {
            bf16x8 a0 = *(const bf16x8*)(WpL + 12288 + (ot * 2 + 0) * 512 + lane * 8);
            bf16x8 a1 = *(const bf16x8*)(WpL + 12288 + (ot * 2 + 1) * 512 + lane * 8);
            acc[ot] = MFMA16(a0, bo0, acc[ot]);
            acc[ot] = MFMA16(a1, bo1, acc[ot]);
        }
        int n = wbase + l15;
        int g = gidx(n, wh, wc, SHIFT);
        #pragma unroll
        for (int ot = 0; ot < 4; ot++) {
            int o0 = ot * 16 + l4 * 4;
            if (o0 < 60) {
                float4 xr = *(const float4*)(Sb + (size_t)g * 60 + o0);
                x1t[(o0 + 0) * 65 + n] = xr.x + acc[ot][0];
                x1t[(o0 + 1) * 65 + n] = xr.y + acc[ot][1];
                x1t[(o0 + 2) * 65 + n] = xr.z + acc[ot][2];
                x1t[(o0 + 3) * 65 + n] = xr.w + acc[ot][3];
            }
        }
    }
    asm volatile("s_waitcnt lgkmcnt(0)" ::: "memory");

    // ---- LN2 -> ln2
    {
        int n = wbase + (lane >> 2), p = lane & 3, cb = p * 16;
        float xv[16];
        #pragma unroll
        for (int ii = 0; ii < 12; ii++) xv[ii] = x1t[(cb + ii) * 65 + n];
        #pragma unroll
        for (int ii = 12; ii < 16; ii++) xv[ii] = (p < 3) ? x1t[(cb + ii) * 65 + n] : 0.f;
        float s = 0.f;
        #pragma unroll
        for (int ii = 0; ii < 16; ii++) s += xv[ii];
        s += __shfl_xor(s, 1); s += __shfl_xor(s, 2);
        float mean = s * (1.f / 60.f);
        float vv = 0.f;
        #pragma unroll
        for (int ii = 0; ii < 12; ii++) { float d = xv[ii] - mean; vv += d * d; }
        #pragma unroll
        for (int ii = 12; ii < 16; ii++) { float d = xv[ii] - mean; vv += (p < 3) ? d * d : 0.f; }
        vv += __shfl_xor(vv, 1); vv += __shfl_xor(vv, 2);
        float rs = rsqrtf(vv * (1.f / 60.f) + 1e-5f);
        float ov[16];
        #pragma unroll
        for (int ii = 0; ii < 12; ii++) ov[ii] = (xv[ii] - mean) * rs;
        #pragma unroll
        for (int ii = 12; ii < 16; ii++)
            ov[ii] = (p < 3) ? (xv[ii] - mean) * rs : ((ii == 12) ? 1.f : 0.f);
        unsigned short* lr = ln2 + n * 72 + cb;
        *(uint4*)lr = make_uint4(pk2rn(ov[0], ov[1]), pk2rn(ov[2], ov[3]),
                                 pk2rn(ov[4], ov[5]), pk2rn(ov[6], ov[7]));
        *(uint4*)(lr + 8) = make_uint4(pk2rn(ov[8], ov[9]), pk2rn(ov[10], ov[11]),
                                       pk2rn(ov[12], ov[13]), pk2rn(ov[14], ov[15]));
    }
    __syncthreads();  // B3

    // ---- MLP
    f32x4 acc2[4];
    #pragma unroll
    for (int ot = 0; ot < 4; ot++) acc2[ot] = zf;

    #pragma unroll
    for (int ph = 0; ph < 2; ph++) {
        {
            bf16x8 bl[4][2];
            #pragma unroll
            for (int nt = 0; nt < 4; nt++)
                #pragma unroll
                for (int ks = 0; ks < 2; ks++)
                    bl[nt][ks] = *(const bf16x8*)(ln2 + (nt * 16 + l15) * 72 + l4 * 8 + ks * 32);
            #pragma unroll
            for (int t = 0; t < 2; t++) {
                int ot = w + t * 4;
                f32x4 a1[4];
                #pragma unroll
                for (int nt = 0; nt < 4; nt++) a1[nt] = zf;
                #pragma unroll
                for (int ks = 0; ks < 2; ks++) {
                    bf16x8 a = *(const bf16x8*)(WpL + 16384 + ((ph * 8 + ot) * 2 + ks) * 512 + lane * 8);
                    #pragma unroll
                    for (int nt = 0; nt < 4; nt++) a1[nt] = MFMA16(a, bl[nt][ks], a1[nt]);
                }
                int o0 = ot * 16 + l4 * 4;
                if (o0 < 120) {
                    #pragma unroll
                    for (int nt = 0; nt < 4; nt++) {
                        int n = nt * 16 + l15;
                        *(uint2*)(h1 + n * 136 + o0) =
                            make_uint2(pk2rn(gelu_f(a1[nt][0]), gelu_f(a1[nt][1])),
                                       pk2rn(gelu_f(a1[nt][2]), gelu_f(a1[nt][3])));
                    }
                }
            }
            if (ph == 0 && tid < 64)
                *(uint4*)(h1 + tid * 136 + 120) = make_uint4(0x3F80u, 0u, 0u, 0u);
        }
        __syncthreads();
        {
            bf16x8 bh[4];
            #pragma unroll
            for (int ks = 0; ks < 4; ks++)
                bh[ks] = *(const bf16x8*)(h1 + (wbase + l15) * 136 + l4 * 8 + ks * 32);
            #pragma unroll
            for (int ot = 0; ot < 4; ot++)
                #pragma unroll
                for (int ks = 0; ks < 4; ks++) {
                    bf16x8 a = *(const bf16x8*)(WpL + 32768 + ((ph * 4 + ot) * 4 + ks) * 512 + lane * 8);
                    acc2[ot] = MFMA16(a, bh[ks], acc2[ot]);
                }
        }
        if (ph == 0) __syncthreads();
    }

    // ---- final: S[g] = x1 + fc2out
    {
        int n = wbase + l15;
        int g = gidx(n, wh, wc, SHIFT);
        #pragma unroll
        for (int ot = 0; ot < 4; ot++) {
            int o0 = ot * 16 + l4 * 4;
            if (o0 < 60) {
                float4 r;
                r.x = x1t[(o0 + 0) * 65 + n] + acc2[ot][0];
                r.y = x1t[(o0 + 1) * 65 + n] + acc2[ot][1];
                r.z = x1t[(o0 + 2) * 65 + n] + acc2[ot][2];
                r.w = x1t[(o0 + 3) * 65 + n] + acc2[ot][3];
                *(float4*)(Sb + (size_t)g * 60 + o0) = r;
            }
        }
    }
}

// ---------------------------------------------------------------- conv_out
__global__ __launch_bounds__(256) void conv_out_k(
    const float* __restrict__ S, const float* __restrict__ w,
    const float* __restrict__ bias, float* __restrict__ out)
{
    __shared__ float Sr[3][40][60];
    __shared__ float wts[3 * 60 * 9];
    __shared__ float part[2][120];
    int b = blockIdx.x / 40, y = blockIdx.x % 40;
    int tid = threadIdx.x;
    for (int idx = tid; idx < 3 * 40 * 60; idx += 256) {
        int ky = idx / 2400; int n = (idx / 60) % 40; int c = idx % 60;
        int yy = y + ky - 1;
        Sr[ky][n][c] = (yy >= 0 && yy < 40) ? S[((size_t)b * 1600 + yy * 40 + n) * 60 + c] : 0.f;
    }
    for (int idx = tid; idx < 3 * 60 * 9; idx += 256) wts[idx] = w[idx];
    __syncthreads();
    if (tid < 240) {
        int p = tid % 120, half = tid / 120;
        int x = p % 40, co = p / 40;
        float acc = 0.f;
        int c0 = half * 30;
        for (int c = c0; c < c0 + 30; c++) {
            #pragma unroll
            for (int ky = 0; ky < 3; ky++) {
                const float* wr = &wts[(co * 60 + c) * 9 + ky * 3];
                float s0 = (x >= 1) ? Sr[ky][x - 1][c] : 0.f;
                float s1 = Sr[ky][x][c];
                float s2 = (x <= 38) ? Sr[ky][x + 1][c] : 0.f;
                acc += wr[0] * s0 + wr[1] * s1 + wr[2] * s2;
            }
        }
        part[half][p] = acc;
    }
    __syncthreads();
    if (tid < 120) {
        int x = tid % 40, co = tid / 40;
        out[((size_t)b * 3 + co) * 1600 + y * 40 + x] = part[0][tid] + part[1][tid] + bias[co];
    }
}

// ---------------------------------------------------------------- launch
extern "C" void kernel_launch(void* const* d_in, const int* in_sizes, int n_in,
                              void* d_out, int out_size, void* d_ws, size_t ws_size,
                              hipStream_t stream)
{
    const float* x   = (const float*)d_in[0];
    const float* ciw = (const float*)d_in[1];
    const float* cib = (const float*)d_in[2];
    const float* n1g = (const float*)d_in[3];
    const float* n1b = (const float*)d_in[4];
    const float* qw  = (const float*)d_in[5];
    const float* qb  = (const float*)d_in[6];
    const float* rpb = (const float*)d_in[7];
    const float* pw  = (const float*)d_in[8];
    const float* pb  = (const float*)d_in[9];
    const float* n2g = (const float*)d_in[10];
    const float* n2b = (const float*)d_in[11];
    const float* f1w = (const float*)d_in[12];
    const float* f1b = (const float*)d_in[13];
    const float* f2w = (const float*)d_in[14];
    const float* f2b = (const float*)d_in[15];
    const float* cow = (const float*)d_in[16];
    const float* cob = (const float*)d_in[17];
    float* out = (float*)d_out;
    float* S = (float*)d_ws;                                        // 49,152,000 B
    unsigned short* Wp = (unsigned short*)((char*)d_ws + 49152000); // 393,216 B packed weights
    unsigned* rpbE = (unsigned*)((char*)d_ws + 49545216);           // 327,680 B expanded rpb
    unsigned short* Wc = (unsigned short*)((char*)d_ws + 49872896); // 36,864 B conv_in A-frags

    prep_k<<<96, 256, 0, stream>>>(qw, pw, f1w, f2w, qb, pb, f1b, f2b,
                                   n1g, n1b, n2g, n2b, Wp);
    prepc_k<<<9, 256, 0, stream>>>(ciw, Wc);
    rpbexp_k<<<20, 256, 0, stream>>>(rpb, rpbE);
    conv_in_k<<<128 * 5, 256, 0, stream>>>(x, Wc, cib, S);
    for (int i = 0; i < 4; i++) {
        const unsigned short* WpL = Wp + i * 49152;
        const unsigned* rpEL = rpbE + i * 5 * 4096;
        if (i & 1) block_k<4><<<128 * 25, 256, 0, stream>>>(S, WpL, rpEL);
        else       block_k<0><<<128 * 25, 256, 0, stream>>>(S, WpL, rpEL);
    }
    conv_out_k<<<128 * 40, 256, 0, stream>>>(S, cow, cob, out);
}

// Round 8
// 417.593 us; speedup vs baseline: 5.7519x; 1.2274x over previous
//
#include <hip/hip_runtime.h>
#include <math.h>

// B=128, H=W=40, C=60, L=1600, NH=10, HD=6, WS=8, N=64, NW=25, NB=4

typedef __bf16 bf16x8 __attribute__((ext_vector_type(8)));
typedef float f32x4 __attribute__((ext_vector_type(4)));
typedef unsigned int u32x4 __attribute__((ext_vector_type(4)));
typedef float f4u __attribute__((ext_vector_type(4), aligned(4)));

#define MFMA16(a, b, c) __builtin_amdgcn_mfma_f32_16x16x32_bf16(a, b, c, 0, 0, 0)

__device__ __forceinline__ unsigned short f2bf(float x) {  // RNE (prep only)
    unsigned u = __float_as_uint(x);
    return (unsigned short)((u + 0x7fffu + ((u >> 16) & 1u)) >> 16);
}
__device__ __forceinline__ unsigned short bfrn(float x) {  // 2 ops
    return (unsigned short)((__float_as_uint(x) + 0x8000u) >> 16);
}
__device__ __forceinline__ unsigned pk2rn(float a, float b) {  // 1 op: lo=bf16(a), hi=bf16(b)
    unsigned r;
    asm("v_cvt_pk_bf16_f32 %0, %1, %2" : "=v"(r) : "v"(a), "v"(b));
    return r;
}
__device__ __forceinline__ float bfsel(unsigned u, int hi) {
    return __uint_as_float(hi ? (u & 0xffff0000u) : (u << 16));
}
__device__ __forceinline__ float gelu_f(float v) {
    float t2 = v * v;
    float e = __builtin_amdgcn_exp2f(v * fmaf(0.102943225f, t2, 2.302207877f));
    float r = __builtin_amdgcn_rcpf(e + 1.f);
    return fmaf(-v, r, v);
}
__device__ __forceinline__ int gidx(int n, int wh, int wc, int shift) {
    int hh = wh * 8 + (n >> 3) + shift; if (hh >= 40) hh -= 40;
    int ww = wc * 8 + (n & 7) + shift;  if (ww >= 40) ww -= 40;
    return hh * 40 + ww;
}

// ---------------------------------------------------------------- weight pre-pack (blocks)
__global__ __launch_bounds__(256) void prep_k(
    const float* __restrict__ qkvw, const float* __restrict__ pw,
    const float* __restrict__ f1w, const float* __restrict__ f2w,
    const float* __restrict__ qkvb, const float* __restrict__ pb,
    const float* __restrict__ f1b, const float* __restrict__ f2b,
    const float* __restrict__ g1v, const float* __restrict__ b1v,
    const float* __restrict__ g2v, const float* __restrict__ b2v,
    unsigned short* __restrict__ Wp)
{
    int t = blockIdx.x * 256 + threadIdx.x;  // 0..24575
    int lane = t & 63;
    int q6 = t >> 6;
    int layer = q6 / 96, tile = q6 % 96;
    int l15 = lane & 15, l4 = lane >> 4;
    const float* src; const float* gam = 0; const float* bet = 0;
    float bias = 0.f, rowscale = 1.f;
    int row, stride, rmax, kmax, k0;
    unsigned short* dst = Wp + layer * 49152;
    if (tile < 24) {
        int ot = tile >> 1, ks = tile & 1;
        src = qkvw + layer * 10800; row = ot * 16 + l15; k0 = ks * 32 + l4 * 8;
        rmax = 180; kmax = 60; stride = 60; dst += tile * 512;
        gam = g1v + layer * 60; bet = b1v + layer * 60;
        if (row < 180) bias = qkvb[layer * 180 + row];
        if (row < 60) rowscale = 0.58897780f;  // 6^-0.5 * log2(e)
    } else if (tile < 32) {
        int tt = tile - 24;
        src = pw + layer * 3600; row = (tt >> 1) * 16 + l15; k0 = (tt & 1) * 32 + l4 * 8;
        rmax = 60; kmax = 60; stride = 60; dst += 12288 + tt * 512;
        if (row < 60) bias = pb[layer * 60 + row];
    } else if (tile < 64) {
        int tt = tile - 32; int ks = tt & 1; int po = tt >> 1; int ot = po & 7; int ph = po >> 3;
        src = f1w + layer * 14400 + ph * 7200; row = ot * 16 + l15; k0 = ks * 32 + l4 * 8;
        rmax = 120; kmax = 60; stride = 60; dst += 16384 + tt * 512;
        gam = g2v + layer * 60; bet = b2v + layer * 60;
        if (row < 120) bias = f1b[layer * 240 + ph * 120 + row];
    } else {
        int tt = tile - 64; int ks = tt & 3; int po = tt >> 2; int ot = po & 3; int ph = po >> 2;
        src = f2w + layer * 14400 + ph * 120; row = ot * 16 + l15; k0 = ks * 32 + l4 * 8;
        rmax = 60; kmax = 120; stride = 240; dst += 32768 + tt * 512;
        if (ph == 0 && row < 60) bias = f2b[layer * 60 + row];
    }
    unsigned short v[8];
    #pragma unroll
    for (int i = 0; i < 8; i++) {
        int k = k0 + i;
        float f = 0.f;
        if (row < rmax) {
            if (k < kmax) {
                f = src[row * stride + k];
                if (gam) f *= gam[k];
            } else if (k == kmax) {
                f = bias;
                if (bet) for (int kk = 0; kk < kmax; kk++) f += src[row * stride + kk] * bet[kk];
            }
        }
        v[i] = f2bf(f * rowscale);
    }
    unsigned a0 = (unsigned)v[0] | ((unsigned)v[1] << 16);
    unsigned a1 = (unsigned)v[2] | ((unsigned)v[3] << 16);
    unsigned a2 = (unsigned)v[4] | ((unsigned)v[5] << 16);
    unsigned a3 = (unsigned)v[6] | ((unsigned)v[7] << 16);
    *(uint4*)(dst + lane * 8) = make_uint4(a0, a1, a2, a3);
}

// ---------------------------------------------------------------- conv weight pre-pack
// tiles 0..35: conv_in A-frags (mt 0..3, g 0..8): row=c_out, k=g-tap ci (pad 18->32)
// tiles 36..53: conv_out A-frags (g 0..8, ks 0..1): row=co (3 valid), k=ci (pad 60->64)
__global__ __launch_bounds__(256) void prepc_k(
    const float* __restrict__ ciw, const float* __restrict__ cow,
    unsigned short* __restrict__ Wc)
{
    int t = blockIdx.x * 256 + threadIdx.x;
    if (t >= 3456) return;
    int lane = t & 63, tile = t >> 6;        // tile 0..53
    int l15 = lane & 15, l4 = lane >> 4;
    unsigned short v[8];
    if (tile < 36) {
        int mt = tile / 9, g = tile % 9;
        int ky = g / 3, kx = g % 3;
        int row = mt * 16 + l15;
        int ci0 = l4 * 8;
        #pragma unroll
        for (int i = 0; i < 8; i++) {
            int ci = ci0 + i;
            float f = (row < 60 && ci < 18) ? ciw[(row * 18 + ci) * 9 + ky * 3 + kx] : 0.f;
            v[i] = f2bf(f);
        }
    } else {
        int tt = tile - 36;
        int g = tt >> 1, ks = tt & 1;
        int row = l15;                        // co
        int ci0 = ks * 32 + l4 * 8;
        #pragma unroll
        for (int i = 0; i < 8; i++) {
            int ci = ci0 + i;
            float f = (row < 3 && ci < 60) ? cow[(row * 60 + ci) * 9 + g] : 0.f;
            v[i] = f2bf(f);
        }
    }
    unsigned a0 = (unsigned)v[0] | ((unsigned)v[1] << 16);
    unsigned a1 = (unsigned)v[2] | ((unsigned)v[3] << 16);
    unsigned a2 = (unsigned)v[4] | ((unsigned)v[5] << 16);
    unsigned a3 = (unsigned)v[6] | ((unsigned)v[7] << 16);
    *(uint4*)(Wc + tile * 512 + lane * 8) = make_uint4(a0, a1, a2, a3);
}

// ---------------------------------------------------------------- rpb pre-expansion
__global__ __launch_bounds__(256) void rpbexp_k(
    const float* __restrict__ rpb, unsigned* __restrict__ rpbE)
{
    int layer = blockIdx.x / 5, hp = blockIdx.x % 5;
    int tid = threadIdx.x;
    int q = tid >> 2, j0 = (tid & 3) * 16;
    const float* rsrc = rpb + layer * 2250 + hp * 2;
    unsigned* dst = rpbE + ((layer * 5 + hp) * 64 + q) * 64 + j0;
    int qr = q >> 3, qc = q & 7;
    #pragma unroll
    for (int jj = 0; jj < 16; jj++) {
        int j = j0 + jj;
        int jr = j >> 3, jc = j & 7;
        int ridx = ((qr - jr + 7) * 15 + (qc - jc + 7)) * 10;
        unsigned short lo = f2bf(rsrc[ridx] * 1.4426950409f);
        unsigned short hi = f2bf(rsrc[ridx + 1] * 1.4426950409f);
        dst[jj] = (unsigned)lo | ((unsigned)hi << 16);
    }
}

// ---------------------------------------------------------------- conv_in (implicit-GEMM MFMA)
__global__ __launch_bounds__(256) void conv_in_k(
    const float* __restrict__ x, const unsigned short* __restrict__ Wc,
    const float* __restrict__ bias, float* __restrict__ S)
{
    __shared__ __align__(16) unsigned short xt[10 * 42 * 32];  // 26880 B
    int b = blockIdx.x / 5, y0 = (blockIdx.x % 5) * 8;
    int tid = threadIdx.x;
    int lane = tid & 63, w = tid >> 6;
    int l15 = lane & 15, l4 = lane >> 4;

    uint4* xt4 = (uint4*)xt;
    for (int i = tid; i < 1680; i += 256) xt4[i] = make_uint4(0u, 0u, 0u, 0u);
    __syncthreads();

    const float* xb = x + (size_t)b * 28800;
    for (int idx = tid; idx < 10 * 18 * 40; idx += 256) {
        int xx = idx % 40;
        int rem = idx / 40;
        int ci = rem % 18;
        int ry = rem / 18;
        int yy = y0 + ry - 1;
        if (yy >= 0 && yy < 40) {
            float v = xb[ci * 1600 + yy * 40 + xx];
            int xs = xx + 1;
            int bo = (((ry * 42 + xs) * 32 + ci) * 2) ^ ((xs & 3) << 4);
            *(unsigned short*)((char*)xt + bo) = bfrn(v);
        }
    }
    __syncthreads();

    bf16x8 afr[9];
    #pragma unroll
    for (int g = 0; g < 9; g++)
        afr[g] = *(const bf16x8*)(Wc + (w * 9 + g) * 512 + lane * 8);

    int c0 = w * 16 + l4 * 4;
    bool valid = (c0 < 60);
    f4u bv = {0.f, 0.f, 0.f, 0.f};
    if (valid) bv = *(const f4u*)(bias + c0);
    const f32x4 zf = {0.f, 0.f, 0.f, 0.f};
    const char* xtb = (const char*)xt;

    for (int nt = 0; nt < 20; nt++) {
        int tok = nt * 16 + l15;
        int yl = tok / 40, xl = tok % 40;
        f32x4 acc = zf;
        #pragma unroll
        for (int g = 0; g < 9; g++) {
            int ky = g / 3, kx = g % 3;
            int xs = xl + kx;
            int ba = ((yl + ky) * 42 + xs) * 64 + ((l4 ^ (xs & 3)) << 4);
            bf16x8 bfrag = *(const bf16x8*)(xtb + ba);
            acc = MFMA16(afr[g], bfrag, acc);
        }
        if (valid) {
            float4 r;
            r.x = acc[0] + bv[0]; r.y = acc[1] + bv[1];
            r.z = acc[2] + bv[2]; r.w = acc[3] + bv[3];
            *(float4*)(S + ((size_t)b * 1600 + y0 * 40 + tok) * 60 + c0) = r;
        }
    }
}

// ---------------------------------------------------------------- fused Swin block
template<int SHIFT>
__global__ __launch_bounds__(256, 3) void block_k(
    float* __restrict__ S,
    const unsigned short* __restrict__ WpL,
    const unsigned* __restrict__ rpE)
{
    __shared__ __align__(16) unsigned char LDSA[53616];
    unsigned short* Pl  = (unsigned short*)(LDSA + 4608);
    float*          x1t = (float*)(LDSA + 0);
    unsigned short* xln = (unsigned short*)(LDSA + 15600);
    unsigned short* h1  = (unsigned short*)(LDSA + 15600);
    unsigned short* qn  = (unsigned short*)(LDSA + 24816);
    unsigned short* kn  = (unsigned short*)(LDSA + 34032);
    unsigned short* vt  = (unsigned short*)(LDSA + 43248);
    unsigned short* ln2 = (unsigned short*)(LDSA + 43248);

    const int tid = threadIdx.x;
    const int lane = tid & 63, w = tid >> 6;
    const int l15 = lane & 15, l4 = lane >> 4;
    const int wbase = w * 16;
    const int b = blockIdx.x / 25, wnd = blockIdx.x % 25;
    const int wh = wnd / 5, wc = wnd % 5;
    float* Sb = S + (size_t)b * 96000;
    const f32x4 zf = {0.f, 0.f, 0.f, 0.f};
    u32x4 zu = {0u, 0u, 0u, 0u};
    const bf16x8 zb = __builtin_bit_cast(bf16x8, zu);
    u32x4 ou = {0x3F803F80u, 0x3F803F80u, 0x3F803F80u, 0x3F803F80u};
    const bf16x8 ones = __builtin_bit_cast(bf16x8, ou);

    // ---- LN1 -> xln
    {
        int n = tid >> 2, p = tid & 3, cb = p * 16;
        int g = gidx(n, wh, wc, SHIFT);
        const float* xp = Sb + (size_t)g * 60 + cb;
        float xv[16];
        {
            float4 v0 = *(const float4*)xp;
            float4 v1 = *(const float4*)(xp + 4);
            float4 v2 = *(const float4*)(xp + 8);
            xv[0] = v0.x; xv[1] = v0.y; xv[2] = v0.z; xv[3] = v0.w;
            xv[4] = v1.x; xv[5] = v1.y; xv[6] = v1.z; xv[7] = v1.w;
            xv[8] = v2.x; xv[9] = v2.y; xv[10] = v2.z; xv[11] = v2.w;
            if (p < 3) {
                float4 v3 = *(const float4*)(xp + 12);
                xv[12] = v3.x; xv[13] = v3.y; xv[14] = v3.z; xv[15] = v3.w;
            } else { xv[12] = xv[13] = xv[14] = xv[15] = 0.f; }
        }
        float s = 0.f;
        #pragma unroll
        for (int ii = 0; ii < 16; ii++) s += xv[ii];
        s += __shfl_xor(s, 1); s += __shfl_xor(s, 2);
        float mean = s * (1.f / 60.f);
        float vv = 0.f;
        #pragma unroll
        for (int ii = 0; ii < 12; ii++) { float d = xv[ii] - mean; vv += d * d; }
        #pragma unroll
        for (int ii = 12; ii < 16; ii++) { float d = xv[ii] - mean; vv += (p < 3) ? d * d : 0.f; }
        vv += __shfl_xor(vv, 1); vv += __shfl_xor(vv, 2);
        float rs = rsqrtf(vv * (1.f / 60.f) + 1e-5f);
        float ov[16];
        #pragma unroll
        for (int ii = 0; ii < 12; ii++) ov[ii] = (xv[ii] - mean) * rs;
        #pragma unroll
        for (int ii = 12; ii < 16; ii++)
            ov[ii] = (p < 3) ? (xv[ii] - mean) * rs : ((ii == 12) ? 1.f : 0.f);
        unsigned short* xr = xln + n * 72 + cb;
        *(uint4*)xr = make_uint4(pk2rn(ov[0], ov[1]), pk2rn(ov[2], ov[3]),
                                 pk2rn(ov[4], ov[5]), pk2rn(ov[6], ov[7]));
        *(uint4*)(xr + 8) = make_uint4(pk2rn(ov[8], ov[9]), pk2rn(ov[10], ov[11]),
                                       pk2rn(ov[12], ov[13]), pk2rn(ov[14], ov[15]));
    }
    __syncthreads();  // B1

    // ---- QKV
    {
        bf16x8 bx[4][2];
        #pragma unroll
        for (int nt = 0; nt < 4; nt++)
            #pragma unroll
            for (int ks = 0; ks < 2; ks++)
                bx[nt][ks] = *(const bf16x8*)(xln + (nt * 16 + l15) * 72 + l4 * 8 + ks * 32);
        #pragma unroll
        for (int t = 0; t < 3; t++) {
            int ot = w * 3 + t;
            f32x4 acc[4];
            #pragma unroll
            for (int nt = 0; nt < 4; nt++) acc[nt] = zf;
            #pragma unroll
            for (int ks = 0; ks < 2; ks++) {
                bf16x8 a = *(const bf16x8*)(WpL + (ot * 2 + ks) * 512 + lane * 8);
                #pragma unroll
                for (int nt = 0; nt < 4; nt++) acc[nt] = MFMA16(a, bx[nt][ks], acc[nt]);
            }
            int o0 = ot * 16 + l4 * 4;
            #pragma unroll
            for (int nt = 0; nt < 4; nt++) {
                int n = nt * 16 + l15;
                if (o0 < 60) {
                    *(uint2*)(qn + n * 72 + o0) =
                        make_uint2(pk2rn(acc[nt][0], acc[nt][1]), pk2rn(acc[nt][2], acc[nt][3]));
                } else if (o0 < 120) {
                    *(uint2*)(kn + n * 72 + (o0 - 60)) =
                        make_uint2(pk2rn(acc[nt][0], acc[nt][1]), pk2rn(acc[nt][2], acc[nt][3]));
                } else {
                    int r = o0 - 120;
                    vt[(r + 0) * 72 + n] = bfrn(acc[nt][0]);
                    vt[(r + 1) * 72 + n] = bfrn(acc[nt][1]);
                    vt[(r + 2) * 72 + n] = bfrn(acc[nt][2]);
                    vt[(r + 3) * 72 + n] = bfrn(acc[nt][3]);
                }
            }
        }
    }
    __syncthreads();  // B2

    // ---- shift-mask bits
    unsigned maskbits = 0u;
    if (SHIFT) {
        int qtok = wbase + l15;
        int qr = qtok >> 3, qc = qtok & 7;
        int shp = wh * 8 + qr, swp = wc * 8 + qc;
        int qreg = (shp < 32 ? 0 : (shp < 36 ? 1 : 2)) * 3 + (swp < 32 ? 0 : (swp < 36 ? 1 : 2));
        #pragma unroll
        for (int e = 0; e < 16; e++) {
            int jt = e >> 2, r = e & 3;
            int j = jt * 16 + l4 * 4 + r;
            int jr = j >> 3, jc = j & 7;
            int shq = wh * 8 + jr, swq = wc * 8 + jc;
            int jreg = (shq < 32 ? 0 : (shq < 36 ? 1 : 2)) * 3 + (swq < 32 ? 0 : (swq < 36 ? 1 : 2));
            if (jreg != qreg) maskbits |= (1u << e);
        }
    }

    // ---- head loop
    f32x4 oacc[10];
    #pragma unroll
    for (int h = 0; h < 10; h++) oacc[h] = zf;
    unsigned short* prow = Pl + (wbase + l15) * 72;
    const unsigned* rpq = rpE + ((wbase + l15) << 6) + (l4 << 2);

    u32x4 rpc[4];
    #pragma unroll
    for (int jt = 0; jt < 4; jt++) rpc[jt] = *(const u32x4*)(rpq + jt * 16);

    #pragma unroll
    for (int hp = 0; hp < 5; hp++) {
        u32x4 rpn[4];
        if (hp < 4) {
            const unsigned* rq = rpq + (hp + 1) * 4096;
            #pragma unroll
            for (int jt = 0; jt < 4; jt++) rpn[jt] = *(const u32x4*)(rq + jt * 16);
        }
        #pragma unroll
        for (int hh2 = 0; hh2 < 2; hh2++) {
            const int h = hp * 2 + hh2;
            bf16x8 bq = zb, ak0 = zb, ak1 = zb, ak2 = zb, ak3 = zb;
            if (l4 == 0) {
                const unsigned* qp = (const unsigned*)(qn + (wbase + l15) * 72 + h * 6);
                u32x4 uq = {qp[0], qp[1], qp[2], 0u};
                bq = __builtin_bit_cast(bf16x8, uq);
                const unsigned* k0p = (const unsigned*)(kn + (0 * 16 + l15) * 72 + h * 6);
                const unsigned* k1p = (const unsigned*)(kn + (1 * 16 + l15) * 72 + h * 6);
                const unsigned* k2p = (const unsigned*)(kn + (2 * 16 + l15) * 72 + h * 6);
                const unsigned* k3p = (const unsigned*)(kn + (3 * 16 + l15) * 72 + h * 6);
                u32x4 u0 = {k0p[0], k0p[1], k0p[2], 0u}; ak0 = __builtin_bit_cast(bf16x8, u0);
                u32x4 u1 = {k1p[0], k1p[1], k1p[2], 0u}; ak1 = __builtin_bit_cast(bf16x8, u1);
                u32x4 u2 = {k2p[0], k2p[1], k2p[2], 0u}; ak2 = __builtin_bit_cast(bf16x8, u2);
                u32x4 u3 = {k3p[0], k3p[1], k3p[2], 0u}; ak3 = __builtin_bit_cast(bf16x8, u3);
            }
            f32x4 s0 = MFMA16(ak0, bq, zf);
            f32x4 s1 = MFMA16(ak1, bq, zf);
            f32x4 s2 = MFMA16(ak2, bq, zf);
            f32x4 s3 = MFMA16(ak3, bq, zf);
            float ee[16];
            #pragma unroll
            for (int r = 0; r < 4; r++) {
                ee[0 + r]  = __builtin_amdgcn_exp2f(s0[r] + bfsel(rpc[0][r], hh2));
                ee[4 + r]  = __builtin_amdgcn_exp2f(s1[r] + bfsel(rpc[1][r], hh2));
                ee[8 + r]  = __builtin_amdgcn_exp2f(s2[r] + bfsel(rpc[2][r], hh2));
                ee[12 + r] = __builtin_amdgcn_exp2f(s3[r] + bfsel(rpc[3][r], hh2));
            }
            if (SHIFT) {
                #pragma unroll
                for (int e = 0; e < 16; e++)
                    if (maskbits & (1u << e)) ee[e] = 0.f;
            }
            #pragma unroll
            for (int jt = 0; jt < 4; jt++)
                *(uint2*)(prow + jt * 16 + l4 * 4) =
                    make_uint2(pk2rn(ee[jt * 4 + 0], ee[jt * 4 + 1]),
                               pk2rn(ee[jt * 4 + 2], ee[jt * 4 + 3]));
            asm volatile("s_waitcnt lgkmcnt(0)" ::: "memory");
            bf16x8 ap0 = *(const bf16x8*)(prow + l4 * 8);
            bf16x8 ap1 = *(const bf16x8*)(prow + 32 + l4 * 8);
            bf16x8 bv0 = *(const bf16x8*)(vt + (h * 6 + l15) * 72 + l4 * 8);
            bf16x8 bv1 = *(const bf16x8*)(vt + (h * 6 + l15) * 72 + 32 + l4 * 8);
            f32x4 sm = MFMA16(ap0, ones, zf);
            sm = MFMA16(ap1, ones, sm);
            f32x4 pv = MFMA16(ap0, bv0, zf);
            pv = MFMA16(ap1, bv1, pv);
            #pragma unroll
            for (int r = 0; r < 4; r++)
                oacc[h][r] = pv[r] * __builtin_amdgcn_rcpf(sm[r]);
        }
        #pragma unroll
        for (int jt = 0; jt < 4; jt++) rpc[jt] = rpn[jt];
    }

    // ---- attention out -> olds (=qn slab)
    unsigned short* olds = qn;
    if (l15 < 6) {
        #pragma unroll
        for (int h = 0; h < 10; h++)
            #pragma unroll
            for (int j = 0; j < 4; j++)
                olds[(wbase + l4 * 4 + j) * 72 + h * 6 + l15] = bfrn(oacc[h][j]);
    } else if (l15 < 10) {
        unsigned short pv16 = (l15 == 6) ? (unsigned short)0x3F80 : (unsigned short)0;
        #pragma unroll
        for (int j = 0; j < 4; j++)
            olds[(wbase + l4 * 4 + j) * 72 + 60 + (l15 - 6)] = pv16;
    }
    __syncthreads();  // B2.5

    // ---- proj + residual -> x1t
    {
        bf16x8 bo0 = *(const bf16x8*)(olds + (wbase + l15) * 72 + l4 * 8);
        bf16x8 bo1 = *(const bf16x8*)(olds + (wbase + l15) * 72 + 32 + l4 * 8);
        f32x4 acc[4];
        #pragma unroll
        for (int ot = 0; ot < 4; ot++) acc[ot] = zf;
        #pragma unroll
        for (int ot = 0; ot < 4; ot++) {
            bf16x8 a0 = *(const bf16x8*)(WpL + 12288 + (ot * 2 + 0) * 512 + lane * 8);
            bf16x8 a1 = *(const bf16x8*)(WpL + 12288 + (ot * 2 + 1) * 512 + lane * 8);
            acc[ot] = MFMA16(a0, bo0, acc[ot]);
            acc[ot] = MFMA16(a1, bo1, acc[ot]);
        }
        int n = wbase + l15;
        int g = gidx(n, wh, wc, SHIFT);
        #pragma unroll
        for (int ot = 0; ot < 4; ot++) {
            int o0 = ot * 16 + l4 * 4;
            if (o0 < 60) {
                float4 xr = *(const float4*)(Sb + (size_t)g * 60 + o0);
                x1t[(o0 + 0) * 65 + n] = xr.x + acc[ot][0];
                x1t[(o0 + 1) * 65 + n] = xr.y + acc[ot][1];
                x1t[(o0 + 2) * 65 + n] = xr.z + acc[ot][2];
                x1t[(o0 + 3) * 65 + n] = xr.w + acc[ot][3];
            }
        }
    }
    asm volatile("s_waitcnt lgkmcnt(0)" ::: "memory");

    // ---- LN2 -> ln2
    {
        int n = wbase + (lane >> 2), p = lane & 3, cb = p * 16;
        float xv[16];
        #pragma unroll
        for (int ii = 0; ii < 12; ii++) xv[ii] = x1t[(cb + ii) * 65 + n];
        #pragma unroll
        for (int ii = 12; ii < 16; ii++) xv[ii] = (p < 3) ? x1t[(cb + ii) * 65 + n] : 0.f;
        float s = 0.f;
        #pragma unroll
        for (int ii = 0; ii < 16; ii++) s += xv[ii];
        s += __shfl_xor(s, 1); s += __shfl_xor(s, 2);
        float mean = s * (1.f / 60.f);
        float vv = 0.f;
        #pragma unroll
        for (int ii = 0; ii < 12; ii++) { float d = xv[ii] - mean; vv += d * d; }
        #pragma unroll
        for (int ii = 12; ii < 16; ii++) { float d = xv[ii] - mean; vv += (p < 3) ? d * d : 0.f; }
        vv += __shfl_xor(vv, 1); vv += __shfl_xor(vv, 2);
        float rs = rsqrtf(vv * (1.f / 60.f) + 1e-5f);
        float ov[16];
        #pragma unroll
        for (int ii = 0; ii < 12; ii++) ov[ii] = (xv[ii] - mean) * rs;
        #pragma unroll
        for (int ii = 12; ii < 16; ii++)
            ov[ii] = (p < 3) ? (xv[ii] - mean) * rs : ((ii == 12) ? 1.f : 0.f);
        unsigned short* lr = ln2 + n * 72 + cb;
        *(uint4*)lr = make_uint4(pk2rn(ov[0], ov[1]), pk2rn(ov[2], ov[3]),
                                 pk2rn(ov[4], ov[5]), pk2rn(ov[6], ov[7]));
        *(uint4*)(lr + 8) = make_uint4(pk2rn(ov[8], ov[9]), pk2rn(ov[10], ov[11]),
                                       pk2rn(ov[12], ov[13]), pk2rn(ov[14], ov[15]));
    }
    __syncthreads();  // B3

    // ---- MLP
    f32x4 acc2[4];
    #pragma unroll
    for (int ot = 0; ot < 4; ot++) acc2[ot] = zf;

    #pragma unroll
    for (int ph = 0; ph < 2; ph++) {
        {
            bf16x8 bl[4][2];
            #pragma unroll
            for (int nt = 0; nt < 4; nt++)
                #pragma unroll
                for (int ks = 0; ks < 2; ks++)
                    bl[nt][ks] = *(const bf16x8*)(ln2 + (nt * 16 + l15) * 72 + l4 * 8 + ks * 32);
            #pragma unroll
            for (int t = 0; t < 2; t++) {
                int ot = w + t * 4;
                f32x4 a1[4];
                #pragma unroll
                for (int nt = 0; nt < 4; nt++) a1[nt] = zf;
                #pragma unroll
                for (int ks = 0; ks < 2; ks++) {
                    bf16x8 a = *(const bf16x8*)(WpL + 16384 + ((ph * 8 + ot) * 2 + ks) * 512 + lane * 8);
                    #pragma unroll
                    for (int nt = 0; nt < 4; nt++) a1[nt] = MFMA16(a, bl[nt][ks], a1[nt]);
                }
                int o0 = ot * 16 + l4 * 4;
                if (o0 < 120) {
                    #pragma unroll
                    for (int nt = 0; nt < 4; nt++) {
                        int n = nt * 16 + l15;
                        *(uint2*)(h1 + n * 136 + o0) =
                            make_uint2(pk2rn(gelu_f(a1[nt][0]), gelu_f(a1[nt][1])),
                                       pk2rn(gelu_f(a1[nt][2]), gelu_f(a1[nt][3])));
                    }
                }
            }
            if (ph == 0 && tid < 64)
                *(uint4*)(h1 + tid * 136 + 120) = make_uint4(0x3F80u, 0u, 0u, 0u);
        }
        __syncthreads();
        {
            bf16x8 bh[4];
            #pragma unroll
            for (int ks = 0; ks < 4; ks++)
                bh[ks] = *(const bf16x8*)(h1 + (wbase + l15) * 136 + l4 * 8 + ks * 32);
            #pragma unroll
            for (int ot = 0; ot < 4; ot++)
                #pragma unroll
                for (int ks = 0; ks < 4; ks++) {
                    bf16x8 a = *(const bf16x8*)(WpL + 32768 + ((ph * 4 + ot) * 4 + ks) * 512 + lane * 8);
                    acc2[ot] = MFMA16(a, bh[ks], acc2[ot]);
                }
        }
        if (ph == 0) __syncthreads();
    }

    // ---- final: S[g] = x1 + fc2out
    {
        int n = wbase + l15;
        int g = gidx(n, wh, wc, SHIFT);
        #pragma unroll
        for (int ot = 0; ot < 4; ot++) {
            int o0 = ot * 16 + l4 * 4;
            if (o0 < 60) {
                float4 r;
                r.x = x1t[(o0 + 0) * 65 + n] + acc2[ot][0];
                r.y = x1t[(o0 + 1) * 65 + n] + acc2[ot][1];
                r.z = x1t[(o0 + 2) * 65 + n] + acc2[ot][2];
                r.w = x1t[(o0 + 3) * 65 + n] + acc2[ot][3];
                *(float4*)(Sb + (size_t)g * 60 + o0) = r;
            }
        }
    }
}

// ---------------------------------------------------------------- conv_out (implicit-GEMM MFMA)
// block = (image, 4-row band); stage 6 input rows bf16 [6][42][64], XOR-swizzled slots.
__global__ __launch_bounds__(256) void conv_out_k(
    const float* __restrict__ S, const unsigned short* __restrict__ Wc2,
    const float* __restrict__ bias, float* __restrict__ out)
{
    __shared__ __align__(16) unsigned short st[6 * 42 * 64];  // 32256 B
    int b = blockIdx.x / 10, y0 = (blockIdx.x % 10) * 4;
    int tid = threadIdx.x;
    int lane = tid & 63, w = tid >> 6;
    int l15 = lane & 15, l4 = lane >> 4;

    uint4* st4 = (uint4*)st;
    for (int i = tid; i < 2016; i += 256) st4[i] = make_uint4(0u, 0u, 0u, 0u);
    __syncthreads();

    const float* Sb = S + (size_t)b * 96000;
    for (int idx = tid; idx < 3600; idx += 256) {
        int cg = idx % 15;
        int xx = (idx / 15) % 40;
        int ry = idx / 600;
        int yy = y0 + ry - 1;
        if (yy >= 0 && yy < 40) {
            const float* sp = Sb + ((size_t)yy * 40 + xx) * 60 + cg * 4;
            float4 v = *(const float4*)sp;
            int xs = xx + 1;
            int bo = (ry * 42 + xs) * 128 + ((cg * 8) ^ ((xs & 7) << 4));
            *(uint2*)((char*)st + bo) = make_uint2(pk2rn(v.x, v.y), pk2rn(v.z, v.w));
        }
    }
    __syncthreads();

    bf16x8 afr[9][2];
    #pragma unroll
    for (int g = 0; g < 9; g++)
        #pragma unroll
        for (int ks = 0; ks < 2; ks++)
            afr[g][ks] = *(const bf16x8*)(Wc2 + (g * 2 + ks) * 512 + lane * 8);

    float b0 = bias[0], b1 = bias[1], b2 = bias[2];
    const f32x4 zf = {0.f, 0.f, 0.f, 0.f};
    const char* stb = (const char*)st;

    for (int nt = w; nt < 10; nt += 4) {
        int tok = nt * 16 + l15;
        int yl = tok / 40, xl = tok % 40;
        f32x4 acc = zf;
        #pragma unroll
        for (int g = 0; g < 9; g++) {
            int ky = g / 3, kx = g % 3;
            int xs = xl + kx;
            int base = ((yl + ky) * 42 + xs) * 128;
            #pragma unroll
            for (int ks = 0; ks < 2; ks++) {
                int bo = base + (((ks * 4 + l4) ^ (xs & 7)) << 4);
                bf16x8 bfrag = *(const bf16x8*)(stb + bo);
                acc = MFMA16(afr[g][ks], bfrag, acc);
            }
        }
        if (l4 == 0) {
            int y = y0 + yl;
            float* op = out + (size_t)b * 4800 + y * 40 + xl;
            op[0] = acc[0] + b0;
            op[1600] = acc[1] + b1;
            op[3200] = acc[2] + b2;
        }
    }
}

// ---------------------------------------------------------------- launch
extern "C" void kernel_launch(void* const* d_in, const int* in_sizes, int n_in,
                              void* d_out, int out_size, void* d_ws, size_t ws_size,
                              hipStream_t stream)
{
    const float* x   = (const float*)d_in[0];
    const float* ciw = (const float*)d_in[1];
    const float* cib = (const float*)d_in[2];
    const float* n1g = (const float*)d_in[3];
    const float* n1b = (const float*)d_in[4];
    const float* qw  = (const float*)d_in[5];
    const float* qb  = (const float*)d_in[6];
    const float* rpb = (const float*)d_in[7];
    const float* pw  = (const float*)d_in[8];
    const float* pb  = (const float*)d_in[9];
    const float* n2g = (const float*)d_in[10];
    const float* n2b = (const float*)d_in[11];
    const float* f1w = (const float*)d_in[12];
    const float* f1b = (const float*)d_in[13];
    const float* f2w = (const float*)d_in[14];
    const float* f2b = (const float*)d_in[15];
    const float* cow = (const float*)d_in[16];
    const float* cob = (const float*)d_in[17];
    float* out = (float*)d_out;
    float* S = (float*)d_ws;                                        // 49,152,000 B
    unsigned short* Wp = (unsigned short*)((char*)d_ws + 49152000); // 393,216 B packed weights
    unsigned* rpbE = (unsigned*)((char*)d_ws + 49545216);           // 327,680 B expanded rpb
    unsigned short* Wc = (unsigned short*)((char*)d_ws + 49872896); // 55,296 B conv A-frags

    prep_k<<<96, 256, 0, stream>>>(qw, pw, f1w, f2w, qb, pb, f1b, f2b,
                                   n1g, n1b, n2g, n2b, Wp);
    prepc_k<<<14, 256, 0, stream>>>(ciw, cow, Wc);
    rpbexp_k<<<20, 256, 0, stream>>>(rpb, rpbE);
    conv_in_k<<<128 * 5, 256, 0, stream>>>(x, Wc, cib, S);
    for (int i = 0; i < 4; i++) {
        const unsigned short* WpL = Wp + i * 49152;
        const unsigned* rpEL = rpbE + i * 5 * 4096;
        if (i & 1) block_k<4><<<128 * 25, 256, 0, stream>>>(S, WpL, rpEL);
        else       block_k<0><<<128 * 25, 256, 0, stream>>>(S, WpL, rpEL);
    }
    conv_out_k<<<128 * 10, 256, 0, stream>>>(S, Wc + 36 * 512, cob, out);
}

// Round 9
// 393.778 us; speedup vs baseline: 6.0998x; 1.0605x over previous
//
#include <hip/hip_runtime.h>
#include <math.h>

// B=128, H=W=40, C=60, L=1600, NH=10, HD=6, WS=8, N=64, NW=25, NB=4

typedef __bf16 bf16x8 __attribute__((ext_vector_type(8)));
typedef float f32x4 __attribute__((ext_vector_type(4)));
typedef unsigned int u32x4 __attribute__((ext_vector_type(4)));
typedef float f4u __attribute__((ext_vector_type(4), aligned(4)));

#define MFMA16(a, b, c) __builtin_amdgcn_mfma_f32_16x16x32_bf16(a, b, c, 0, 0, 0)

__device__ __forceinline__ unsigned short f2bf(float x) {  // RNE (prep only)
    unsigned u = __float_as_uint(x);
    return (unsigned short)((u + 0x7fffu + ((u >> 16) & 1u)) >> 16);
}
__device__ __forceinline__ unsigned short bfrn(float x) {  // 2 ops
    return (unsigned short)((__float_as_uint(x) + 0x8000u) >> 16);
}
__device__ __forceinline__ unsigned pk2rn(float a, float b) {  // 1 op
    unsigned r;
    asm("v_cvt_pk_bf16_f32 %0, %1, %2" : "=v"(r) : "v"(a), "v"(b));
    return r;
}
__device__ __forceinline__ float bfsel(unsigned u, int hi) {
    return __uint_as_float(hi ? (u & 0xffff0000u) : (u << 16));
}
__device__ __forceinline__ float gelu_f(float v) {
    float t2 = v * v;
    float e = __builtin_amdgcn_exp2f(v * fmaf(0.102943225f, t2, 2.302207877f));
    float r = __builtin_amdgcn_rcpf(e + 1.f);
    return fmaf(-v, r, v);
}
__device__ __forceinline__ int gidx(int n, int wh, int wc, int shift) {
    int hh = wh * 8 + (n >> 3) + shift; if (hh >= 40) hh -= 40;
    int ww = wc * 8 + (n & 7) + shift;  if (ww >= 40) ww -= 40;
    return hh * 40 + ww;
}

// ---------------------------------------------------------------- weight pre-pack (blocks)
__global__ __launch_bounds__(256) void prep_k(
    const float* __restrict__ qkvw, const float* __restrict__ pw,
    const float* __restrict__ f1w, const float* __restrict__ f2w,
    const float* __restrict__ qkvb, const float* __restrict__ pb,
    const float* __restrict__ f1b, const float* __restrict__ f2b,
    const float* __restrict__ g1v, const float* __restrict__ b1v,
    const float* __restrict__ g2v, const float* __restrict__ b2v,
    unsigned short* __restrict__ Wp)
{
    int t = blockIdx.x * 256 + threadIdx.x;  // 0..24575
    int lane = t & 63;
    int q6 = t >> 6;
    int layer = q6 / 96, tile = q6 % 96;
    int l15 = lane & 15, l4 = lane >> 4;
    const float* src; const float* gam = 0; const float* bet = 0;
    float bias = 0.f, rowscale = 1.f;
    int row, stride, rmax, kmax, k0;
    unsigned short* dst = Wp + layer * 49152;
    if (tile < 24) {
        int ot = tile >> 1, ks = tile & 1;
        src = qkvw + layer * 10800; row = ot * 16 + l15; k0 = ks * 32 + l4 * 8;
        rmax = 180; kmax = 60; stride = 60; dst += tile * 512;
        gam = g1v + layer * 60; bet = b1v + layer * 60;
        if (row < 180) bias = qkvb[layer * 180 + row];
        if (row < 60) rowscale = 0.58897780f;  // 6^-0.5 * log2(e)
    } else if (tile < 32) {
        int tt = tile - 24;
        src = pw + layer * 3600; row = (tt >> 1) * 16 + l15; k0 = (tt & 1) * 32 + l4 * 8;
        rmax = 60; kmax = 60; stride = 60; dst += 12288 + tt * 512;
        if (row < 60) bias = pb[layer * 60 + row];
    } else if (tile < 64) {
        int tt = tile - 32; int ks = tt & 1; int po = tt >> 1; int ot = po & 7; int ph = po >> 3;
        src = f1w + layer * 14400 + ph * 7200; row = ot * 16 + l15; k0 = ks * 32 + l4 * 8;
        rmax = 120; kmax = 60; stride = 60; dst += 16384 + tt * 512;
        gam = g2v + layer * 60; bet = b2v + layer * 60;
        if (row < 120) bias = f1b[layer * 240 + ph * 120 + row];
    } else {
        int tt = tile - 64; int ks = tt & 3; int po = tt >> 2; int ot = po & 3; int ph = po >> 2;
        src = f2w + layer * 14400 + ph * 120; row = ot * 16 + l15; k0 = ks * 32 + l4 * 8;
        rmax = 60; kmax = 120; stride = 240; dst += 32768 + tt * 512;
        if (ph == 0 && row < 60) bias = f2b[layer * 60 + row];
    }
    unsigned short v[8];
    #pragma unroll
    for (int i = 0; i < 8; i++) {
        int k = k0 + i;
        float f = 0.f;
        if (row < rmax) {
            if (k < kmax) {
                f = src[row * stride + k];
                if (gam) f *= gam[k];
            } else if (k == kmax) {
                f = bias;
                if (bet) for (int kk = 0; kk < kmax; kk++) f += src[row * stride + kk] * bet[kk];
            }
        }
        v[i] = f2bf(f * rowscale);
    }
    unsigned a0 = (unsigned)v[0] | ((unsigned)v[1] << 16);
    unsigned a1 = (unsigned)v[2] | ((unsigned)v[3] << 16);
    unsigned a2 = (unsigned)v[4] | ((unsigned)v[5] << 16);
    unsigned a3 = (unsigned)v[6] | ((unsigned)v[7] << 16);
    *(uint4*)(dst + lane * 8) = make_uint4(a0, a1, a2, a3);
}

// ---------------------------------------------------------------- conv weight pre-pack
__global__ __launch_bounds__(256) void prepc_k(
    const float* __restrict__ ciw, const float* __restrict__ cow,
    unsigned short* __restrict__ Wc)
{
    int t = blockIdx.x * 256 + threadIdx.x;
    if (t >= 3456) return;
    int lane = t & 63, tile = t >> 6;        // tile 0..53
    int l15 = lane & 15, l4 = lane >> 4;
    unsigned short v[8];
    if (tile < 36) {
        int mt = tile / 9, g = tile % 9;
        int ky = g / 3, kx = g % 3;
        int row = mt * 16 + l15;
        int ci0 = l4 * 8;
        #pragma unroll
        for (int i = 0; i < 8; i++) {
            int ci = ci0 + i;
            float f = (row < 60 && ci < 18) ? ciw[(row * 18 + ci) * 9 + ky * 3 + kx] : 0.f;
            v[i] = f2bf(f);
        }
    } else {
        int tt = tile - 36;
        int g = tt >> 1, ks = tt & 1;
        int row = l15;                        // co
        int ci0 = ks * 32 + l4 * 8;
        #pragma unroll
        for (int i = 0; i < 8; i++) {
            int ci = ci0 + i;
            float f = (row < 3 && ci < 60) ? cow[(row * 60 + ci) * 9 + g] : 0.f;
            v[i] = f2bf(f);
        }
    }
    unsigned a0 = (unsigned)v[0] | ((unsigned)v[1] << 16);
    unsigned a1 = (unsigned)v[2] | ((unsigned)v[3] << 16);
    unsigned a2 = (unsigned)v[4] | ((unsigned)v[5] << 16);
    unsigned a3 = (unsigned)v[6] | ((unsigned)v[7] << 16);
    *(uint4*)(Wc + tile * 512 + lane * 8) = make_uint4(a0, a1, a2, a3);
}

// ---------------------------------------------------------------- rpb pre-expansion
__global__ __launch_bounds__(256) void rpbexp_k(
    const float* __restrict__ rpb, unsigned* __restrict__ rpbE)
{
    int layer = blockIdx.x / 5, hp = blockIdx.x % 5;
    int tid = threadIdx.x;
    int q = tid >> 2, j0 = (tid & 3) * 16;
    const float* rsrc = rpb + layer * 2250 + hp * 2;
    unsigned* dst = rpbE + ((layer * 5 + hp) * 64 + q) * 64 + j0;
    int qr = q >> 3, qc = q & 7;
    #pragma unroll
    for (int jj = 0; jj < 16; jj++) {
        int j = j0 + jj;
        int jr = j >> 3, jc = j & 7;
        int ridx = ((qr - jr + 7) * 15 + (qc - jc + 7)) * 10;
        unsigned short lo = f2bf(rsrc[ridx] * 1.4426950409f);
        unsigned short hi = f2bf(rsrc[ridx + 1] * 1.4426950409f);
        dst[jj] = (unsigned)lo | ((unsigned)hi << 16);
    }
}

// ---------------------------------------------------------------- conv_in (implicit-GEMM MFMA)
__global__ __launch_bounds__(256) void conv_in_k(
    const float* __restrict__ x, const unsigned short* __restrict__ Wc,
    const float* __restrict__ bias, float* __restrict__ S)
{
    __shared__ __align__(16) unsigned short xt[10 * 42 * 32];  // 26880 B
    int b = blockIdx.x / 5, y0 = (blockIdx.x % 5) * 8;
    int tid = threadIdx.x;
    int lane = tid & 63, w = tid >> 6;
    int l15 = lane & 15, l4 = lane >> 4;

    uint4* xt4 = (uint4*)xt;
    for (int i = tid; i < 1680; i += 256) xt4[i] = make_uint4(0u, 0u, 0u, 0u);
    __syncthreads();

    const float* xb = x + (size_t)b * 28800;
    for (int idx = tid; idx < 10 * 18 * 40; idx += 256) {
        int xx = idx % 40;
        int rem = idx / 40;
        int ci = rem % 18;
        int ry = rem / 18;
        int yy = y0 + ry - 1;
        if (yy >= 0 && yy < 40) {
            float v = xb[ci * 1600 + yy * 40 + xx];
            int xs = xx + 1;
            int bo = (((ry * 42 + xs) * 32 + ci) * 2) ^ ((xs & 3) << 4);
            *(unsigned short*)((char*)xt + bo) = bfrn(v);
        }
    }
    __syncthreads();

    bf16x8 afr[9];
    #pragma unroll
    for (int g = 0; g < 9; g++)
        afr[g] = *(const bf16x8*)(Wc + (w * 9 + g) * 512 + lane * 8);

    int c0 = w * 16 + l4 * 4;
    bool valid = (c0 < 60);
    f4u bv = {0.f, 0.f, 0.f, 0.f};
    if (valid) bv = *(const f4u*)(bias + c0);
    const f32x4 zf = {0.f, 0.f, 0.f, 0.f};
    const char* xtb = (const char*)xt;

    for (int nt = 0; nt < 20; nt++) {
        int tok = nt * 16 + l15;
        int yl = tok / 40, xl = tok % 40;
        f32x4 acc = zf;
        #pragma unroll
        for (int g = 0; g < 9; g++) {
            int ky = g / 3, kx = g % 3;
            int xs = xl + kx;
            int ba = ((yl + ky) * 42 + xs) * 64 + ((l4 ^ (xs & 3)) << 4);
            bf16x8 bfrag = *(const bf16x8*)(xtb + ba);
            acc = MFMA16(afr[g], bfrag, acc);
        }
        if (valid) {
            float4 r;
            r.x = acc[0] + bv[0]; r.y = acc[1] + bv[1];
            r.z = acc[2] + bv[2]; r.w = acc[3] + bv[3];
            *(float4*)(S + ((size_t)b * 1600 + y0 * 40 + tok) * 60 + c0) = r;
        }
    }
}

// ---------------------------------------------------------------- fused Swin block
// LDS map (38016 B -> 4 blocks/CU):
//  A [0, 9216)      xln bf16[64][72] -> Pl (head loop, per-wave rows) -> h1 lower
//  B [9216, 18432)  qn/olds bf16[64][72] -> h1 upper (h1 = [64][136] @0, 17408 B)
//  C [18432, 27648) kn bf16[64][72]
//  D [27648, 38016) vt bf16[72][72] -> ln2 bf16[64][72]
// x1 (residual) lives in 16 VGPRs; LN2 is in-register via shfl_xor(16/32).
template<int SHIFT>
__global__ __launch_bounds__(256, 4) void block_k(
    float* __restrict__ S,
    const unsigned short* __restrict__ WpL,
    const unsigned* __restrict__ rpE)
{
    __shared__ __align__(16) unsigned char LDSA[38016];
    unsigned short* xln = (unsigned short*)(LDSA + 0);
    unsigned short* Pl  = (unsigned short*)(LDSA + 0);
    unsigned short* h1  = (unsigned short*)(LDSA + 0);
    unsigned short* qn  = (unsigned short*)(LDSA + 9216);
    unsigned short* kn  = (unsigned short*)(LDSA + 18432);
    unsigned short* vt  = (unsigned short*)(LDSA + 27648);
    unsigned short* ln2 = (unsigned short*)(LDSA + 27648);

    const int tid = threadIdx.x;
    const int lane = tid & 63, w = tid >> 6;
    const int l15 = lane & 15, l4 = lane >> 4;
    const int wbase = w * 16;
    const int b = blockIdx.x / 25, wnd = blockIdx.x % 25;
    const int wh = wnd / 5, wc = wnd % 5;
    float* Sb = S + (size_t)b * 96000;
    const f32x4 zf = {0.f, 0.f, 0.f, 0.f};
    u32x4 zu = {0u, 0u, 0u, 0u};
    const bf16x8 zb = __builtin_bit_cast(bf16x8, zu);
    u32x4 ou = {0x3F803F80u, 0x3F803F80u, 0x3F803F80u, 0x3F803F80u};
    const bf16x8 ones = __builtin_bit_cast(bf16x8, ou);

    // ---- LN1 -> xln (bf16 n-major; col60=1 bias slot)
    {
        int n = tid >> 2, p = tid & 3, cb = p * 16;
        int g = gidx(n, wh, wc, SHIFT);
        const float* xp = Sb + (size_t)g * 60 + cb;
        float xv[16];
        {
            float4 v0 = *(const float4*)xp;
            float4 v1 = *(const float4*)(xp + 4);
            float4 v2 = *(const float4*)(xp + 8);
            xv[0] = v0.x; xv[1] = v0.y; xv[2] = v0.z; xv[3] = v0.w;
            xv[4] = v1.x; xv[5] = v1.y; xv[6] = v1.z; xv[7] = v1.w;
            xv[8] = v2.x; xv[9] = v2.y; xv[10] = v2.z; xv[11] = v2.w;
            if (p < 3) {
                float4 v3 = *(const float4*)(xp + 12);
                xv[12] = v3.x; xv[13] = v3.y; xv[14] = v3.z; xv[15] = v3.w;
            } else { xv[12] = xv[13] = xv[14] = xv[15] = 0.f; }
        }
        float s = 0.f;
        #pragma unroll
        for (int ii = 0; ii < 16; ii++) s += xv[ii];
        s += __shfl_xor(s, 1); s += __shfl_xor(s, 2);
        float mean = s * (1.f / 60.f);
        float vv = 0.f;
        #pragma unroll
        for (int ii = 0; ii < 12; ii++) { float d = xv[ii] - mean; vv += d * d; }
        #pragma unroll
        for (int ii = 12; ii < 16; ii++) { float d = xv[ii] - mean; vv += (p < 3) ? d * d : 0.f; }
        vv += __shfl_xor(vv, 1); vv += __shfl_xor(vv, 2);
        float rs = rsqrtf(vv * (1.f / 60.f) + 1e-5f);
        float ov[16];
        #pragma unroll
        for (int ii = 0; ii < 12; ii++) ov[ii] = (xv[ii] - mean) * rs;
        #pragma unroll
        for (int ii = 12; ii < 16; ii++)
            ov[ii] = (p < 3) ? (xv[ii] - mean) * rs : ((ii == 12) ? 1.f : 0.f);
        unsigned short* xr = xln + n * 72 + cb;
        *(uint4*)xr = make_uint4(pk2rn(ov[0], ov[1]), pk2rn(ov[2], ov[3]),
                                 pk2rn(ov[4], ov[5]), pk2rn(ov[6], ov[7]));
        *(uint4*)(xr + 8) = make_uint4(pk2rn(ov[8], ov[9]), pk2rn(ov[10], ov[11]),
                                       pk2rn(ov[12], ov[13]), pk2rn(ov[14], ov[15]));
    }
    __syncthreads();  // B1

    // ---- QKV (bias in k=60 slot; q pre-scaled)
    {
        bf16x8 bx[4][2];
        #pragma unroll
        for (int nt = 0; nt < 4; nt++)
            #pragma unroll
            for (int ks = 0; ks < 2; ks++)
                bx[nt][ks] = *(const bf16x8*)(xln + (nt * 16 + l15) * 72 + l4 * 8 + ks * 32);
        #pragma unroll
        for (int t = 0; t < 3; t++) {
            int ot = w * 3 + t;
            f32x4 acc[4];
            #pragma unroll
            for (int nt = 0; nt < 4; nt++) acc[nt] = zf;
            #pragma unroll
            for (int ks = 0; ks < 2; ks++) {
                bf16x8 a = *(const bf16x8*)(WpL + (ot * 2 + ks) * 512 + lane * 8);
                #pragma unroll
                for (int nt = 0; nt < 4; nt++) acc[nt] = MFMA16(a, bx[nt][ks], acc[nt]);
            }
            int o0 = ot * 16 + l4 * 4;
            #pragma unroll
            for (int nt = 0; nt < 4; nt++) {
                int n = nt * 16 + l15;
                if (o0 < 60) {
                    *(uint2*)(qn + n * 72 + o0) =
                        make_uint2(pk2rn(acc[nt][0], acc[nt][1]), pk2rn(acc[nt][2], acc[nt][3]));
                } else if (o0 < 120) {
                    *(uint2*)(kn + n * 72 + (o0 - 60)) =
                        make_uint2(pk2rn(acc[nt][0], acc[nt][1]), pk2rn(acc[nt][2], acc[nt][3]));
                } else {
                    int r = o0 - 120;
                    vt[(r + 0) * 72 + n] = bfrn(acc[nt][0]);
                    vt[(r + 1) * 72 + n] = bfrn(acc[nt][1]);
                    vt[(r + 2) * 72 + n] = bfrn(acc[nt][2]);
                    vt[(r + 3) * 72 + n] = bfrn(acc[nt][3]);
                }
            }
        }
    }
    __syncthreads();  // B2 (xln dead -> Pl may be written)

    // ---- shift-mask bits
    unsigned maskbits = 0u;
    if (SHIFT) {
        int qtok = wbase + l15;
        int qr = qtok >> 3, qc = qtok & 7;
        int shp = wh * 8 + qr, swp = wc * 8 + qc;
        int qreg = (shp < 32 ? 0 : (shp < 36 ? 1 : 2)) * 3 + (swp < 32 ? 0 : (swp < 36 ? 1 : 2));
        #pragma unroll
        for (int e = 0; e < 16; e++) {
            int jt = e >> 2, r = e & 3;
            int j = jt * 16 + l4 * 4 + r;
            int jr = j >> 3, jc = j & 7;
            int shq = wh * 8 + jr, swq = wc * 8 + jc;
            int jreg = (shq < 32 ? 0 : (shq < 36 ? 1 : 2)) * 3 + (swq < 32 ? 0 : (swq < 36 ? 1 : 2));
            if (jreg != qreg) maskbits |= (1u << e);
        }
    }

    // ---- head loop (per-wave rows of Pl; kn/vt read-only)
    f32x4 oacc[10];
    #pragma unroll
    for (int h = 0; h < 10; h++) oacc[h] = zf;
    unsigned short* prow = Pl + (wbase + l15) * 72;
    const unsigned* rpq = rpE + ((wbase + l15) << 6) + (l4 << 2);

    u32x4 rpc[4];
    #pragma unroll
    for (int jt = 0; jt < 4; jt++) rpc[jt] = *(const u32x4*)(rpq + jt * 16);

    #pragma unroll
    for (int hp = 0; hp < 5; hp++) {
        u32x4 rpn[4];
        if (hp < 4) {
            const unsigned* rq = rpq + (hp + 1) * 4096;
            #pragma unroll
            for (int jt = 0; jt < 4; jt++) rpn[jt] = *(const u32x4*)(rq + jt * 16);
        }
        #pragma unroll
        for (int hh2 = 0; hh2 < 2; hh2++) {
            const int h = hp * 2 + hh2;
            bf16x8 bq = zb, ak0 = zb, ak1 = zb, ak2 = zb, ak3 = zb;
            if (l4 == 0) {
                const unsigned* qp = (const unsigned*)(qn + (wbase + l15) * 72 + h * 6);
                u32x4 uq = {qp[0], qp[1], qp[2], 0u};
                bq = __builtin_bit_cast(bf16x8, uq);
                const unsigned* k0p = (const unsigned*)(kn + (0 * 16 + l15) * 72 + h * 6);
                const unsigned* k1p = (const unsigned*)(kn + (1 * 16 + l15) * 72 + h * 6);
                const unsigned* k2p = (const unsigned*)(kn + (2 * 16 + l15) * 72 + h * 6);
                const unsigned* k3p = (const unsigned*)(kn + (3 * 16 + l15) * 72 + h * 6);
                u32x4 u0 = {k0p[0], k0p[1], k0p[2], 0u}; ak0 = __builtin_bit_cast(bf16x8, u0);
                u32x4 u1 = {k1p[0], k1p[1], k1p[2], 0u}; ak1 = __builtin_bit_cast(bf16x8, u1);
                u32x4 u2 = {k2p[0], k2p[1], k2p[2], 0u}; ak2 = __builtin_bit_cast(bf16x8, u2);
                u32x4 u3 = {k3p[0], k3p[1], k3p[2], 0u}; ak3 = __builtin_bit_cast(bf16x8, u3);
            }
            f32x4 s0 = MFMA16(ak0, bq, zf);
            f32x4 s1 = MFMA16(ak1, bq, zf);
            f32x4 s2 = MFMA16(ak2, bq, zf);
            f32x4 s3 = MFMA16(ak3, bq, zf);
            float ee[16];
            #pragma unroll
            for (int r = 0; r < 4; r++) {
                ee[0 + r]  = __builtin_amdgcn_exp2f(s0[r] + bfsel(rpc[0][r], hh2));
                ee[4 + r]  = __builtin_amdgcn_exp2f(s1[r] + bfsel(rpc[1][r], hh2));
                ee[8 + r]  = __builtin_amdgcn_exp2f(s2[r] + bfsel(rpc[2][r], hh2));
                ee[12 + r] = __builtin_amdgcn_exp2f(s3[r] + bfsel(rpc[3][r], hh2));
            }
            if (SHIFT) {
                #pragma unroll
                for (int e = 0; e < 16; e++)
                    if (maskbits & (1u << e)) ee[e] = 0.f;
            }
            #pragma unroll
            for (int jt = 0; jt < 4; jt++)
                *(uint2*)(prow + jt * 16 + l4 * 4) =
                    make_uint2(pk2rn(ee[jt * 4 + 0], ee[jt * 4 + 1]),
                               pk2rn(ee[jt * 4 + 2], ee[jt * 4 + 3]));
            asm volatile("s_waitcnt lgkmcnt(0)" ::: "memory");
            bf16x8 ap0 = *(const bf16x8*)(prow + l4 * 8);
            bf16x8 ap1 = *(const bf16x8*)(prow + 32 + l4 * 8);
            bf16x8 bv0 = *(const bf16x8*)(vt + (h * 6 + l15) * 72 + l4 * 8);
            bf16x8 bv1 = *(const bf16x8*)(vt + (h * 6 + l15) * 72 + 32 + l4 * 8);
            f32x4 sm = MFMA16(ap0, ones, zf);
            sm = MFMA16(ap1, ones, sm);
            f32x4 pv = MFMA16(ap0, bv0, zf);
            pv = MFMA16(ap1, bv1, pv);
            #pragma unroll
            for (int r = 0; r < 4; r++)
                oacc[h][r] = pv[r] * __builtin_amdgcn_rcpf(sm[r]);
        }
        #pragma unroll
        for (int jt = 0; jt < 4; jt++) rpc[jt] = rpn[jt];
    }

    // ---- attention out -> olds (=qn slab; own-wave rows only)
    unsigned short* olds = qn;
    if (l15 < 6) {
        #pragma unroll
        for (int h = 0; h < 10; h++)
            #pragma unroll
            for (int j = 0; j < 4; j++)
                olds[(wbase + l4 * 4 + j) * 72 + h * 6 + l15] = bfrn(oacc[h][j]);
    } else if (l15 < 10) {
        unsigned short pv16 = (l15 == 6) ? (unsigned short)0x3F80 : (unsigned short)0;
        #pragma unroll
        for (int j = 0; j < 4; j++)
            olds[(wbase + l4 * 4 + j) * 72 + 60 + (l15 - 6)] = pv16;
    }
    __syncthreads();  // B2.5: all waves past Pl/vt/kn reads -> ln2 overlay safe

    // ---- proj + residual -> x1 in REGISTERS (token n=wbase+l15, ch c=ot*16+l4*4+r)
    f32x4 x1v[4];
    {
        bf16x8 bo0 = *(const bf16x8*)(olds + (wbase + l15) * 72 + l4 * 8);
        bf16x8 bo1 = *(const bf16x8*)(olds + (wbase + l15) * 72 + 32 + l4 * 8);
        f32x4 acc[4];
        #pragma unroll
        for (int ot = 0; ot < 4; ot++) acc[ot] = zf;
        #pragma unroll
        for (int ot = 0; ot < 4; ot++) {
            bf16x8 a0 = *(const bf16x8*)(WpL + 12288 + (ot * 2 + 0) * 512 + lane * 8);
            bf16x8 a1 = *(const bf16x8*)(WpL + 12288 + (ot * 2 + 1) * 512 + lane * 8);
            acc[ot] = MFMA16(a0, bo0, acc[ot]);
            acc[ot] = MFMA16(a1, bo1, acc[ot]);
        }
        int n = wbase + l15;
        int g = gidx(n, wh, wc, SHIFT);
        #pragma unroll
        for (int ot = 0; ot < 4; ot++) {
            int o0 = ot * 16 + l4 * 4;
            if (o0 < 60) {
                float4 xr = *(const float4*)(Sb + (size_t)g * 60 + o0);
                x1v[ot][0] = xr.x + acc[ot][0];
                x1v[ot][1] = xr.y + acc[ot][1];
                x1v[ot][2] = xr.z + acc[ot][2];
                x1v[ot][3] = xr.w + acc[ot][3];
            } else {
                x1v[ot] = zf;
            }
        }
    }

    // ---- LN2 in registers (reduce across the 4 l4-lanes sharing token n)
    {
        float s = 0.f;
        #pragma unroll
        for (int ot = 0; ot < 4; ot++)
            #pragma unroll
            for (int r = 0; r < 4; r++) s += x1v[ot][r];
        s += __shfl_xor(s, 16); s += __shfl_xor(s, 32);
        float mean = s * (1.f / 60.f);
        float vv = 0.f;
        #pragma unroll
        for (int ot = 0; ot < 4; ot++) {
            int o0 = ot * 16 + l4 * 4;
            if (o0 < 60) {
                #pragma unroll
                for (int r = 0; r < 4; r++) { float d = x1v[ot][r] - mean; vv += d * d; }
            }
        }
        vv += __shfl_xor(vv, 16); vv += __shfl_xor(vv, 32);
        float rs = rsqrtf(vv * (1.f / 60.f) + 1e-5f);
        int n = wbase + l15;
        #pragma unroll
        for (int ot = 0; ot < 4; ot++) {
            int o0 = ot * 16 + l4 * 4;
            if (o0 < 60) {
                *(uint2*)(ln2 + n * 72 + o0) = make_uint2(
                    pk2rn((x1v[ot][0] - mean) * rs, (x1v[ot][1] - mean) * rs),
                    pk2rn((x1v[ot][2] - mean) * rs, (x1v[ot][3] - mean) * rs));
            } else {
                *(uint2*)(ln2 + n * 72 + 60) = make_uint2(0x00003F80u, 0u);  // bias=1, pad 0
            }
        }
    }
    __syncthreads();  // B3 (ln2 ready; Pl/olds dead -> h1 overlay safe)

    // ---- MLP (x1 stays in regs for the final residual)
    f32x4 acc2[4];
    #pragma unroll
    for (int ot = 0; ot < 4; ot++) acc2[ot] = zf;

    #pragma unroll
    for (int ph = 0; ph < 2; ph++) {
        {
            bf16x8 bl[4][2];
            #pragma unroll
            for (int nt = 0; nt < 4; nt++)
                #pragma unroll
                for (int ks = 0; ks < 2; ks++)
                    bl[nt][ks] = *(const bf16x8*)(ln2 + (nt * 16 + l15) * 72 + l4 * 8 + ks * 32);
            #pragma unroll
            for (int t = 0; t < 2; t++) {
                int ot = w + t * 4;
                f32x4 a1[4];
                #pragma unroll
                for (int nt = 0; nt < 4; nt++) a1[nt] = zf;
                #pragma unroll
                for (int ks = 0; ks < 2; ks++) {
                    bf16x8 a = *(const bf16x8*)(WpL + 16384 + ((ph * 8 + ot) * 2 + ks) * 512 + lane * 8);
                    #pragma unroll
                    for (int nt = 0; nt < 4; nt++) a1[nt] = MFMA16(a, bl[nt][ks], a1[nt]);
                }
                int o0 = ot * 16 + l4 * 4;
                if (o0 < 120) {
                    #pragma unroll
                    for (int nt = 0; nt < 4; nt++) {
                        int n = nt * 16 + l15;
                        *(uint2*)(h1 + n * 136 + o0) =
                            make_uint2(pk2rn(gelu_f(a1[nt][0]), gelu_f(a1[nt][1])),
                                       pk2rn(gelu_f(a1[nt][2]), gelu_f(a1[nt][3])));
                    }
                }
            }
            if (ph == 0 && tid < 64)
                *(uint4*)(h1 + tid * 136 + 120) = make_uint4(0x3F80u, 0u, 0u, 0u);
        }
        __syncthreads();
        {
            bf16x8 bh[4];
            #pragma unroll
            for (int ks = 0; ks < 4; ks++)
                bh[ks] = *(const bf16x8*)(h1 + (wbase + l15) * 136 + l4 * 8 + ks * 32);
            #pragma unroll
            for (int ot = 0; ot < 4; ot++)
                #pragma unroll
                for (int ks = 0; ks < 4; ks++) {
                    bf16x8 a = *(const bf16x8*)(WpL + 32768 + ((ph * 4 + ot) * 4 + ks) * 512 + lane * 8);
                    acc2[ot] = MFMA16(a, bh[ks], acc2[ot]);
                }
        }
        if (ph == 0) __syncthreads();
    }

    // ---- final: S[g] = x1(reg) + fc2out
    {
        int n = wbase + l15;
        int g = gidx(n, wh, wc, SHIFT);
        #pragma unroll
        for (int ot = 0; ot < 4; ot++) {
            int o0 = ot * 16 + l4 * 4;
            if (o0 < 60) {
                float4 r;
                r.x = x1v[ot][0] + acc2[ot][0];
                r.y = x1v[ot][1] + acc2[ot][1];
                r.z = x1v[ot][2] + acc2[ot][2];
                r.w = x1v[ot][3] + acc2[ot][3];
                *(float4*)(Sb + (size_t)g * 60 + o0) = r;
            }
        }
    }
}

// ---------------------------------------------------------------- conv_out (implicit-GEMM MFMA)
__global__ __launch_bounds__(256) void conv_out_k(
    const float* __restrict__ S, const unsigned short* __restrict__ Wc2,
    const float* __restrict__ bias, float* __restrict__ out)
{
    __shared__ __align__(16) unsigned short st[6 * 42 * 64];  // 32256 B
    int b = blockIdx.x / 10, y0 = (blockIdx.x % 10) * 4;
    int tid = threadIdx.x;
    int lane = tid & 63, w = tid >> 6;
    int l15 = lane & 15, l4 = lane >> 4;

    uint4* st4 = (uint4*)st;
    for (int i = tid; i < 2016; i += 256) st4[i] = make_uint4(0u, 0u, 0u, 0u);
    __syncthreads();

    const float* Sb = S + (size_t)b * 96000;
    for (int idx = tid; idx < 3600; idx += 256) {
        int cg = idx % 15;
        int xx = (idx / 15) % 40;
        int ry = idx / 600;
        int yy = y0 + ry - 1;
        if (yy >= 0 && yy < 40) {
            const float* sp = Sb + ((size_t)yy * 40 + xx) * 60 + cg * 4;
            float4 v = *(const float4*)sp;
            int xs = xx + 1;
            int bo = (ry * 42 + xs) * 128 + ((cg * 8) ^ ((xs & 7) << 4));
            *(uint2*)((char*)st + bo) = make_uint2(pk2rn(v.x, v.y), pk2rn(v.z, v.w));
        }
    }
    __syncthreads();

    bf16x8 afr[9][2];
    #pragma unroll
    for (int g = 0; g < 9; g++)
        #pragma unroll
        for (int ks = 0; ks < 2; ks++)
            afr[g][ks] = *(const bf16x8*)(Wc2 + (g * 2 + ks) * 512 + lane * 8);

    float b0 = bias[0], b1 = bias[1], b2 = bias[2];
    const f32x4 zf = {0.f, 0.f, 0.f, 0.f};
    const char* stb = (const char*)st;

    for (int nt = w; nt < 10; nt += 4) {
        int tok = nt * 16 + l15;
        int yl = tok / 40, xl = tok % 40;
        f32x4 acc = zf;
        #pragma unroll
        for (int g = 0; g < 9; g++) {
            int ky = g / 3, kx = g % 3;
            int xs = xl + kx;
            int base = ((yl + ky) * 42 + xs) * 128;
            #pragma unroll
            for (int ks = 0; ks < 2; ks++) {
                int bo = base + (((ks * 4 + l4) ^ (xs & 7)) << 4);
                bf16x8 bfrag = *(const bf16x8*)(stb + bo);
                acc = MFMA16(afr[g][ks], bfrag, acc);
            }
        }
        if (l4 == 0) {
            int y = y0 + yl;
            float* op = out + (size_t)b * 4800 + y * 40 + xl;
            op[0] = acc[0] + b0;
            op[1600] = acc[1] + b1;
            op[3200] = acc[2] + b2;
        }
    }
}

// ---------------------------------------------------------------- launch
extern "C" void kernel_launch(void* const* d_in, const int* in_sizes, int n_in,
                              void* d_out, int out_size, void* d_ws, size_t ws_size,
                              hipStream_t stream)
{
    const float* x   = (const float*)d_in[0];
    const float* ciw = (const float*)d_in[1];
    const float* cib = (const float*)d_in[2];
    const float* n1g = (const float*)d_in[3];
    const float* n1b = (const float*)d_in[4];
    const float* qw  = (const float*)d_in[5];
    const float* qb  = (const float*)d_in[6];
    const float* rpb = (const float*)d_in[7];
    const float* pw  = (const float*)d_in[8];
    const float* pb  = (const float*)d_in[9];
    const float* n2g = (const float*)d_in[10];
    const float* n2b = (const float*)d_in[11];
    const float* f1w = (const float*)d_in[12];
    const float* f1b = (const float*)d_in[13];
    const float* f2w = (const float*)d_in[14];
    const float* f2b = (const float*)d_in[15];
    const float* cow = (const float*)d_in[16];
    const float* cob = (const float*)d_in[17];
    float* out = (float*)d_out;
    float* S = (float*)d_ws;                                        // 49,152,000 B
    unsigned short* Wp = (unsigned short*)((char*)d_ws + 49152000); // packed weights
    unsigned* rpbE = (unsigned*)((char*)d_ws + 49545216);           // expanded rpb
    unsigned short* Wc = (unsigned short*)((char*)d_ws + 49872896); // conv A-frags

    prep_k<<<96, 256, 0, stream>>>(qw, pw, f1w, f2w, qb, pb, f1b, f2b,
                                   n1g, n1b, n2g, n2b, Wp);
    prepc_k<<<14, 256, 0, stream>>>(ciw, cow, Wc);
    rpbexp_k<<<20, 256, 0, stream>>>(rpb, rpbE);
    conv_in_k<<<128 * 5, 256, 0, stream>>>(x, Wc, cib, S);
    for (int i = 0; i < 4; i++) {
        const unsigned short* WpL = Wp + i * 49152;
        const unsigned* rpEL = rpbE + i * 5 * 4096;
        if (i & 1) block_k<4><<<128 * 25, 256, 0, stream>>>(S, WpL, rpEL);
        else       block_k<0><<<128 * 25, 256, 0, stream>>>(S, WpL, rpEL);
    }
    conv_out_k<<<128 * 10, 256, 0, stream>>>(S, Wc + 36 * 512, cob, out);
}